// Round 8
// baseline (625.635 us; speedup 1.0000x reference)
//
#include <hip/hip_runtime.h>

#define N_NODES 100000
#define N_EDGES 1600000
#define IN_F 128
#define HID 64
#define OUT_F 32
#define NB_SCAN ((N_NODES + 255) / 256)  // 391

#define BSHIFT 10
#define BUCK_N (1 << BSHIFT)                               // 1024 nodes/bucket
#define NBUCK ((N_NODES + BUCK_N - 1) >> BSHIFT)           // 98
#define EPB 8192
#define NBLK_A ((N_EDGES + EPB - 1) / EPB)                 // 196
#define ROW_MASK 0x1FFFF                                   // 17 bits, N < 131072

// ---------------- degree histogram (int) ----------------

__global__ __launch_bounds__(256) void hist_kernel(const int* __restrict__ col,
                                                   int* __restrict__ deg) {
    int e = blockIdx.x * 256 + threadIdx.x;
    if (e < N_EDGES) atomicAdd(&deg[col[e]], 1);
}

// ---------------- scan1 + dinv ----------------

__global__ __launch_bounds__(256) void scan1d_kernel(const int* __restrict__ deg,
                                                     int* __restrict__ excl,
                                                     int* __restrict__ bsum,
                                                     float* __restrict__ dinv) {
    __shared__ int s[256];
    int t = threadIdx.x, i = blockIdx.x * 256 + t;
    int v = (i < N_NODES) ? deg[i] : 0;
    if (i < N_NODES) dinv[i] = rsqrtf((float)v + 1.0f);  // +1 = self-loop
    s[t] = v; __syncthreads();
    for (int off = 1; off < 256; off <<= 1) {
        int x = (t >= off) ? s[t - off] : 0; __syncthreads();
        s[t] += x; __syncthreads();
    }
    if (i < N_NODES) excl[i] = s[t] - v;
    if (t == 255) bsum[blockIdx.x] = s[255];
}

__global__ __launch_bounds__(512) void scan2_kernel(int* __restrict__ bsum) {
    __shared__ int s[512];
    int t = threadIdx.x;
    int v = (t < NB_SCAN) ? bsum[t] : 0;
    s[t] = v; __syncthreads();
    for (int off = 1; off < 512; off <<= 1) {
        int x = (t >= off) ? s[t - off] : 0; __syncthreads();
        s[t] += x; __syncthreads();
    }
    if (t < NB_SCAN) bsum[t] = s[t] - v;  // exclusive block offsets
}

// scan3 + binit fused

__global__ __launch_bounds__(256) void scan3b_kernel(int* __restrict__ excl,
                                                     const int* __restrict__ bsum,
                                                     int* __restrict__ gcur) {
    int i = blockIdx.x * 256 + threadIdx.x;
    if (i < N_NODES) {
        int rp = excl[i] + bsum[blockIdx.x];
        excl[i] = rp;                                   // excl now holds rowptr
        if ((i & (BUCK_N - 1)) == 0) gcur[i >> BSHIFT] = rp;
    }
}

// ---------------- binned reorder (packed payload) ----------------
// pass A: group edges by bucket into tmp, packed (colin<<17)|row.

__global__ __launch_bounds__(256) void binA_kernel(const int* __restrict__ row,
                                                   const int* __restrict__ col,
                                                   int* __restrict__ gcur,
                                                   int* __restrict__ tmp) {
    __shared__ int cnt[NBUCK], base[NBUCK], lcur[NBUCK];
    int t = threadIdx.x;
    int e0 = blockIdx.x * EPB;
    int e1 = e0 + EPB < N_EDGES ? e0 + EPB : N_EDGES;
    for (int i = t; i < NBUCK; i += 256) cnt[i] = 0;
    __syncthreads();
    for (int e = e0 + t; e < e1; e += 256) atomicAdd(&cnt[col[e] >> BSHIFT], 1);
    __syncthreads();
    for (int i = t; i < NBUCK; i += 256) {
        int c = cnt[i];
        base[i] = c ? atomicAdd(&gcur[i], c) : 0;
        lcur[i] = 0;
    }
    __syncthreads();
    for (int e = e0 + t; e < e1; e += 256) {
        int c = col[e];
        int b = c >> BSHIFT;
        int rk = atomicAdd(&lcur[b], 1);
        tmp[base[b] + rk] = ((c & (BUCK_N - 1)) << 17) | row[e];
    }
}

// pass B: within a bucket, counting-sort into srt via LDS cursors.

__global__ __launch_bounds__(512) void binB_kernel(const int* __restrict__ rowp,
                                                   const int* __restrict__ tmp,
                                                   int* __restrict__ srt) {
    __shared__ int curs[BUCK_N];  // 4 KB
    int b = blockIdx.x, t = threadIdx.x;
    int nbase = b << BSHIFT;
    int nend = nbase + BUCK_N < N_NODES ? nbase + BUCK_N : N_NODES;
    for (int i = t; i < nend - nbase; i += 512) curs[i] = rowp[nbase + i];
    __syncthreads();
    int s  = rowp[nbase];
    int e1 = (nend < N_NODES) ? rowp[nend] : N_EDGES;
    for (int e = s + t; e < e1; e += 512) {
        int rc = tmp[e];
        int pos = atomicAdd(&curs[rc >> 17], 1);
        srt[pos] = rc & ROW_MASK;
    }
}

// ---------------- layer 1 dense: g1 = (x @ W1) * dinv ----------------
// register-tiled: tile 64 nodes x 64 f; thread = 4 nodes (stride 16) x 4 f.

__global__ __launch_bounds__(256) void gemm1_tiled(const float* __restrict__ x,
                                                   const float* __restrict__ W1,
                                                   const float* __restrict__ dinv,
                                                   float* __restrict__ g1) {
    __shared__ float w[IN_F * HID];       // 32 KB, [k][f]
    __shared__ float xs[64 * IN_F];       // 32 KB, swizzled
    float4* xs4 = (float4*)xs;            // row stride 32 float4

    int t = threadIdx.x;
    int base = blockIdx.x * 64;

    for (int i = t; i < IN_F * HID; i += 256) w[i] = W1[i];

#pragma unroll
    for (int j = 0; j < 8; ++j) {
        int idx = j * 1024 + t * 4;
        int n = idx >> 7;
        int k = idx & 127;
        float4 v = make_float4(0.f, 0.f, 0.f, 0.f);
        if (base + n < N_NODES) v = *(const float4*)&x[(size_t)(base + n) * IN_F + k];
        xs4[(n << 5) + ((k >> 2) ^ (n & 7))] = v;
    }
    __syncthreads();

    int m0 = t & 15;
    int f0 = (t >> 4) << 2;
    int sw = m0 & 7;

    float acc[4][4];
#pragma unroll
    for (int u = 0; u < 4; ++u)
#pragma unroll
        for (int j = 0; j < 4; ++j) acc[u][j] = 0.f;

    for (int k4 = 0; k4 < IN_F; k4 += 4) {
        int cb = (k4 >> 2) ^ sw;
        float4 xv[4], wv[4];
#pragma unroll
        for (int u = 0; u < 4; ++u) xv[u] = xs4[((m0 + 16 * u) << 5) + cb];
#pragma unroll
        for (int kk = 0; kk < 4; ++kk) wv[kk] = *(float4*)&w[(k4 + kk) * HID + f0];
#pragma unroll
        for (int u = 0; u < 4; ++u) {
            acc[u][0] += xv[u].x * wv[0].x + xv[u].y * wv[1].x + xv[u].z * wv[2].x + xv[u].w * wv[3].x;
            acc[u][1] += xv[u].x * wv[0].y + xv[u].y * wv[1].y + xv[u].z * wv[2].y + xv[u].w * wv[3].y;
            acc[u][2] += xv[u].x * wv[0].z + xv[u].y * wv[1].z + xv[u].z * wv[2].z + xv[u].w * wv[3].z;
            acc[u][3] += xv[u].x * wv[0].w + xv[u].y * wv[1].w + xv[u].z * wv[2].w + xv[u].w * wv[3].w;
        }
    }

#pragma unroll
    for (int u = 0; u < 4; ++u) {
        int n = base + m0 + 16 * u;
        if (n < N_NODES) {
            float dv = dinv[n];
            *(float4*)&g1[(size_t)n * HID + f0] =
                make_float4(acc[u][0] * dv, acc[u][1] * dv, acc[u][2] * dv, acc[u][3] * dv);
        }
    }
}

// ---------------- FUSED: gather1 + finalize1 + gemm2 ----------------
// Block = 128 nodes, 256 threads. Phase 1: 4 waves gather h rows into
// swizzled LDS (lane = feature). Phase 2: register-tiled gemm2 from LDS.
// g2 = (relu(dinv*(agg+self)+b1) @ W2) * dinv, no h round-trip to HBM.

__global__ __launch_bounds__(256) void g1g2_fused(const int* __restrict__ rowptr,
                                                  const int* __restrict__ deg,
                                                  const int* __restrict__ srt,
                                                  const float* __restrict__ g1,
                                                  const float* __restrict__ dinv,
                                                  const float* __restrict__ b1,
                                                  const float* __restrict__ W2,
                                                  float* __restrict__ g2) {
    __shared__ float w[HID * OUT_F];      // 8 KB
    __shared__ float hs[128 * HID];       // 32 KB, swizzled
    float4* hs4 = (float4*)hs;            // row stride 16 float4

    int t = threadIdx.x;
    int base = blockIdx.x * 128;

    for (int i = t; i < HID * OUT_F; i += 256) w[i] = W2[i];

    // -------- phase 1: gather --------
    int wv = t >> 6;       // wave 0..3
    int lane = t & 63;     // feature
    float bl = b1[lane];
    for (int q = 0; q < 32; ++q) {
        int rr = wv * 32 + q;
        int n = base + rr;
        if (n < N_NODES) {
            int s = rowptr[n], e = s + deg[n];
            float a0 = 0.f, a1 = 0.f, a2 = 0.f, a3 = 0.f;
            float a4 = 0.f, a5 = 0.f, a6 = 0.f, a7 = 0.f;
            int j = s;
            for (; j + 8 <= e; j += 8) {
                int r0 = srt[j],     r1 = srt[j + 1], r2 = srt[j + 2], r3 = srt[j + 3];
                int r4 = srt[j + 4], r5 = srt[j + 5], r6 = srt[j + 6], r7 = srt[j + 7];
                a0 += g1[(size_t)r0 * HID + lane];
                a1 += g1[(size_t)r1 * HID + lane];
                a2 += g1[(size_t)r2 * HID + lane];
                a3 += g1[(size_t)r3 * HID + lane];
                a4 += g1[(size_t)r4 * HID + lane];
                a5 += g1[(size_t)r5 * HID + lane];
                a6 += g1[(size_t)r6 * HID + lane];
                a7 += g1[(size_t)r7 * HID + lane];
            }
            for (; j < e; ++j) a0 += g1[(size_t)srt[j] * HID + lane];
            float sum = ((a0 + a1) + (a2 + a3)) + ((a4 + a5) + (a6 + a7))
                      + g1[(size_t)n * HID + lane];  // + self-loop
            float hval = dinv[n] * sum + bl;
            hval = hval > 0.f ? hval : 0.f;
            // swizzled scalar store (float4-block ^ (row&7))
            hs[rr * 64 + (((((unsigned)lane >> 2) ^ (rr & 7)) << 2) | (lane & 3))] = hval;
        }
    }
    __syncthreads();

    // -------- phase 2: gemm2 (register-tiled) --------
    int m0 = t & 31;
    int f0 = (t >> 5) << 2;
    int sw = m0 & 7;

    float acc[4][4];
#pragma unroll
    for (int u = 0; u < 4; ++u)
#pragma unroll
        for (int j = 0; j < 4; ++j) acc[u][j] = 0.f;

    for (int k4 = 0; k4 < HID; k4 += 4) {
        int cb = (k4 >> 2) ^ sw;
        float4 xv[4], wv4[4];
#pragma unroll
        for (int u = 0; u < 4; ++u) xv[u] = hs4[((m0 + 32 * u) << 4) + cb];
#pragma unroll
        for (int kk = 0; kk < 4; ++kk) wv4[kk] = *(float4*)&w[(k4 + kk) * OUT_F + f0];
#pragma unroll
        for (int u = 0; u < 4; ++u) {
            acc[u][0] += xv[u].x * wv4[0].x + xv[u].y * wv4[1].x + xv[u].z * wv4[2].x + xv[u].w * wv4[3].x;
            acc[u][1] += xv[u].x * wv4[0].y + xv[u].y * wv4[1].y + xv[u].z * wv4[2].y + xv[u].w * wv4[3].y;
            acc[u][2] += xv[u].x * wv4[0].z + xv[u].y * wv4[1].z + xv[u].z * wv4[2].z + xv[u].w * wv4[3].z;
            acc[u][3] += xv[u].x * wv4[0].w + xv[u].y * wv4[1].w + xv[u].z * wv4[2].w + xv[u].w * wv4[3].w;
        }
    }

#pragma unroll
    for (int u = 0; u < 4; ++u) {
        int n = base + m0 + 32 * u;
        if (n < N_NODES) {
            float dv = dinv[n];
            *(float4*)&g2[(size_t)n * OUT_F + f0] =
                make_float4(acc[u][0] * dv, acc[u][1] * dv, acc[u][2] * dv, acc[u][3] * dv);
        }
    }
}

// ---------------- layer 2 gather + finalize2 ----------------

__global__ __launch_bounds__(256) void gather2_kernel(const int* __restrict__ rowptr,
                                                      const int* __restrict__ deg,
                                                      const int* __restrict__ srt,
                                                      const float* __restrict__ g2,
                                                      const float* __restrict__ dinv,
                                                      const float* __restrict__ b2,
                                                      float* __restrict__ out) {
    int n = blockIdx.x * 8 + (threadIdx.x >> 5);
    int f = threadIdx.x & 31;
    if (n >= N_NODES) return;
    int s = rowptr[n], e = s + deg[n];
    float a0 = 0.f, a1 = 0.f, a2 = 0.f, a3 = 0.f;
    float a4 = 0.f, a5 = 0.f, a6 = 0.f, a7 = 0.f;
    int j = s;
    for (; j + 8 <= e; j += 8) {
        int r0 = srt[j],     r1 = srt[j + 1], r2 = srt[j + 2], r3 = srt[j + 3];
        int r4 = srt[j + 4], r5 = srt[j + 5], r6 = srt[j + 6], r7 = srt[j + 7];
        a0 += g2[(size_t)r0 * OUT_F + f];
        a1 += g2[(size_t)r1 * OUT_F + f];
        a2 += g2[(size_t)r2 * OUT_F + f];
        a3 += g2[(size_t)r3 * OUT_F + f];
        a4 += g2[(size_t)r4 * OUT_F + f];
        a5 += g2[(size_t)r5 * OUT_F + f];
        a6 += g2[(size_t)r6 * OUT_F + f];
        a7 += g2[(size_t)r7 * OUT_F + f];
    }
    for (; j < e; ++j) a0 += g2[(size_t)srt[j] * OUT_F + f];
    float sum = ((a0 + a1) + (a2 + a3)) + ((a4 + a5) + (a6 + a7))
              + g2[(size_t)n * OUT_F + f];  // + self-loop
    out[(size_t)n * OUT_F + f] = dinv[n] * sum + b2[f];
}

extern "C" void kernel_launch(void* const* d_in, const int* in_sizes, int n_in,
                              void* d_out, int out_size, void* d_ws, size_t ws_size,
                              hipStream_t stream) {
    const float* x   = (const float*)d_in[0];
    const int*   ei  = (const int*)d_in[1];
    const int*   row = ei;             // edge_index[0] = source
    const int*   col = ei + N_EDGES;   // edge_index[1] = target
    const float* W1  = (const float*)d_in[2];
    const float* b1  = (const float*)d_in[3];
    const float* W2  = (const float*)d_in[4];
    const float* b2  = (const float*)d_in[5];
    float* out = (float*)d_out;

    // workspace layout
    char* p = (char*)d_ws;
    float* dinv  = (float*)p; p += (size_t)N_NODES * 4;          // 0.4 MB
    float* g1    = (float*)p; p += (size_t)N_NODES * HID * 4;    // 25.6 MB
    float* g2    = (float*)p; p += (size_t)N_NODES * OUT_F * 4;  // 12.8 MB
    int*   deg   = (int*)p;   p += (size_t)N_NODES * 4;          // 0.4 MB
    int*   rowp  = (int*)p;   p += (size_t)(N_NODES + 1) * 4;    // 0.4 MB
    int*   bsum  = (int*)p;   p += 512 * 4;
    int*   gcur  = (int*)p;   p += ((NBUCK + 63) & ~63) * 4;
    int*   srt   = (int*)p;   p += (size_t)N_EDGES * 4;          // 6.4 MB
    int*   tmp   = (int*)p;   p += (size_t)N_EDGES * 4;          // 6.4 MB (packed)

    hipMemsetAsync(deg, 0, (size_t)N_NODES * sizeof(int), stream);

    hist_kernel  <<<(N_EDGES + 255) / 256, 256, 0, stream>>>(col, deg);
    scan1d_kernel<<<NB_SCAN, 256, 0, stream>>>(deg, rowp, bsum, dinv);
    scan2_kernel <<<1, 512, 0, stream>>>(bsum);
    scan3b_kernel<<<NB_SCAN, 256, 0, stream>>>(rowp, bsum, gcur);
    binA_kernel  <<<NBLK_A, 256, 0, stream>>>(row, col, gcur, tmp);
    binB_kernel  <<<NBUCK, 512, 0, stream>>>(rowp, tmp, srt);

    gemm1_tiled  <<<(N_NODES + 63) / 64, 256, 0, stream>>>(x, W1, dinv, g1);
    g1g2_fused   <<<(N_NODES + 127) / 128, 256, 0, stream>>>(rowp, deg, srt, g1, dinv, b1, W2, g2);
    gather2_kernel<<<(N_NODES + 7) / 8, 256, 0, stream>>>(rowp, deg, srt, g2, dinv, b2, out);
}

// Round 9
// 322.635 us; speedup vs baseline: 1.9391x; 1.9391x over previous
//
#include <hip/hip_runtime.h>

#define N_NODES 100000
#define N_EDGES 1600000
#define IN_F 128
#define HID 64
#define OUT_F 32
#define NB_SCAN ((N_NODES + 255) / 256)  // 391

#define BSHIFT 10
#define BUCK_N (1 << BSHIFT)                               // 1024 nodes/bucket
#define NBUCK ((N_NODES + BUCK_N - 1) >> BSHIFT)           // 98
#define EPB 8192
#define NBLK_A ((N_EDGES + EPB - 1) / EPB)                 // 196
#define ROW_MASK 0x1FFFF                                   // 17 bits, N < 131072

// bf16 helpers (RNE pack, exact unpack)
__device__ __forceinline__ float bf2f(unsigned short u) {
    return __uint_as_float(((unsigned)u) << 16);
}
__device__ __forceinline__ unsigned short f2bf(float f) {
    unsigned u = __float_as_uint(f);
    u += 0x7FFF + ((u >> 16) & 1);   // round-to-nearest-even
    return (unsigned short)(u >> 16);
}

// ---------------- degree histogram (int) ----------------

__global__ __launch_bounds__(256) void hist_kernel(const int* __restrict__ col,
                                                   int* __restrict__ deg) {
    int e = blockIdx.x * 256 + threadIdx.x;
    if (e < N_EDGES) atomicAdd(&deg[col[e]], 1);
}

// ---------------- scan1 + dinv ----------------

__global__ __launch_bounds__(256) void scan1d_kernel(const int* __restrict__ deg,
                                                     int* __restrict__ excl,
                                                     int* __restrict__ bsum,
                                                     float* __restrict__ dinv) {
    __shared__ int s[256];
    int t = threadIdx.x, i = blockIdx.x * 256 + t;
    int v = (i < N_NODES) ? deg[i] : 0;
    if (i < N_NODES) dinv[i] = rsqrtf((float)v + 1.0f);  // +1 = self-loop
    s[t] = v; __syncthreads();
    for (int off = 1; off < 256; off <<= 1) {
        int x = (t >= off) ? s[t - off] : 0; __syncthreads();
        s[t] += x; __syncthreads();
    }
    if (i < N_NODES) excl[i] = s[t] - v;
    if (t == 255) bsum[blockIdx.x] = s[255];
}

__global__ __launch_bounds__(512) void scan2_kernel(int* __restrict__ bsum) {
    __shared__ int s[512];
    int t = threadIdx.x;
    int v = (t < NB_SCAN) ? bsum[t] : 0;
    s[t] = v; __syncthreads();
    for (int off = 1; off < 512; off <<= 1) {
        int x = (t >= off) ? s[t - off] : 0; __syncthreads();
        s[t] += x; __syncthreads();
    }
    if (t < NB_SCAN) bsum[t] = s[t] - v;  // exclusive block offsets
}

// scan3 + binit fused

__global__ __launch_bounds__(256) void scan3b_kernel(int* __restrict__ excl,
                                                     const int* __restrict__ bsum,
                                                     int* __restrict__ gcur) {
    int i = blockIdx.x * 256 + threadIdx.x;
    if (i < N_NODES) {
        int rp = excl[i] + bsum[blockIdx.x];
        excl[i] = rp;                                   // excl now holds rowptr
        if ((i & (BUCK_N - 1)) == 0) gcur[i >> BSHIFT] = rp;
    }
}

// ---------------- binned reorder (packed payload) ----------------

__global__ __launch_bounds__(256) void binA_kernel(const int* __restrict__ row,
                                                   const int* __restrict__ col,
                                                   int* __restrict__ gcur,
                                                   int* __restrict__ tmp) {
    __shared__ int cnt[NBUCK], base[NBUCK], lcur[NBUCK];
    int t = threadIdx.x;
    int e0 = blockIdx.x * EPB;
    int e1 = e0 + EPB < N_EDGES ? e0 + EPB : N_EDGES;
    for (int i = t; i < NBUCK; i += 256) cnt[i] = 0;
    __syncthreads();
    for (int e = e0 + t; e < e1; e += 256) atomicAdd(&cnt[col[e] >> BSHIFT], 1);
    __syncthreads();
    for (int i = t; i < NBUCK; i += 256) {
        int c = cnt[i];
        base[i] = c ? atomicAdd(&gcur[i], c) : 0;
        lcur[i] = 0;
    }
    __syncthreads();
    for (int e = e0 + t; e < e1; e += 256) {
        int c = col[e];
        int b = c >> BSHIFT;
        int rk = atomicAdd(&lcur[b], 1);
        tmp[base[b] + rk] = ((c & (BUCK_N - 1)) << 17) | row[e];
    }
}

__global__ __launch_bounds__(512) void binB_kernel(const int* __restrict__ rowp,
                                                   const int* __restrict__ tmp,
                                                   int* __restrict__ srt) {
    __shared__ int curs[BUCK_N];  // 4 KB
    int b = blockIdx.x, t = threadIdx.x;
    int nbase = b << BSHIFT;
    int nend = nbase + BUCK_N < N_NODES ? nbase + BUCK_N : N_NODES;
    for (int i = t; i < nend - nbase; i += 512) curs[i] = rowp[nbase + i];
    __syncthreads();
    int s  = rowp[nbase];
    int e1 = (nend < N_NODES) ? rowp[nend] : N_EDGES;
    for (int e = s + t; e < e1; e += 512) {
        int rc = tmp[e];
        int pos = atomicAdd(&curs[rc >> 17], 1);
        srt[pos] = rc & ROW_MASK;
    }
}

// ---------------- layer 1 dense: g1b = bf16((x @ W1) * dinv) ----------------
// register-tiled: tile 64 nodes x 64 f; thread = 4 nodes (stride 16) x 4 f.

__global__ __launch_bounds__(256) void gemm1_tiled(const float* __restrict__ x,
                                                   const float* __restrict__ W1,
                                                   const float* __restrict__ dinv,
                                                   unsigned short* __restrict__ g1b) {
    __shared__ float w[IN_F * HID];       // 32 KB, [k][f]
    __shared__ float xs[64 * IN_F];       // 32 KB, swizzled
    float4* xs4 = (float4*)xs;            // row stride 32 float4

    int t = threadIdx.x;
    int base = blockIdx.x * 64;

    for (int i = t; i < IN_F * HID; i += 256) w[i] = W1[i];

#pragma unroll
    for (int j = 0; j < 8; ++j) {
        int idx = j * 1024 + t * 4;
        int n = idx >> 7;
        int k = idx & 127;
        float4 v = make_float4(0.f, 0.f, 0.f, 0.f);
        if (base + n < N_NODES) v = *(const float4*)&x[(size_t)(base + n) * IN_F + k];
        xs4[(n << 5) + ((k >> 2) ^ (n & 7))] = v;
    }
    __syncthreads();

    int m0 = t & 15;
    int f0 = (t >> 4) << 2;
    int sw = m0 & 7;

    float acc[4][4];
#pragma unroll
    for (int u = 0; u < 4; ++u)
#pragma unroll
        for (int j = 0; j < 4; ++j) acc[u][j] = 0.f;

    for (int k4 = 0; k4 < IN_F; k4 += 4) {
        int cb = (k4 >> 2) ^ sw;
        float4 xv[4], wv[4];
#pragma unroll
        for (int u = 0; u < 4; ++u) xv[u] = xs4[((m0 + 16 * u) << 5) + cb];
#pragma unroll
        for (int kk = 0; kk < 4; ++kk) wv[kk] = *(float4*)&w[(k4 + kk) * HID + f0];
#pragma unroll
        for (int u = 0; u < 4; ++u) {
            acc[u][0] += xv[u].x * wv[0].x + xv[u].y * wv[1].x + xv[u].z * wv[2].x + xv[u].w * wv[3].x;
            acc[u][1] += xv[u].x * wv[0].y + xv[u].y * wv[1].y + xv[u].z * wv[2].y + xv[u].w * wv[3].y;
            acc[u][2] += xv[u].x * wv[0].z + xv[u].y * wv[1].z + xv[u].z * wv[2].z + xv[u].w * wv[3].z;
            acc[u][3] += xv[u].x * wv[0].w + xv[u].y * wv[1].w + xv[u].z * wv[2].w + xv[u].w * wv[3].w;
        }
    }

#pragma unroll
    for (int u = 0; u < 4; ++u) {
        int n = base + m0 + 16 * u;
        if (n < N_NODES) {
            float dv = dinv[n];
            ushort4 o;
            o.x = f2bf(acc[u][0] * dv);
            o.y = f2bf(acc[u][1] * dv);
            o.z = f2bf(acc[u][2] * dv);
            o.w = f2bf(acc[u][3] * dv);
            *(ushort4*)&g1b[(size_t)n * HID + f0] = o;
        }
    }
}

// ---------------- layer 1 gather + finalize1 (bf16 reads, fp32 accum) -------
// one 64-lane wave per node, lane = feature, 8-edge unroll.

__global__ __launch_bounds__(256) void gather1_kernel(const int* __restrict__ rowptr,
                                                      const int* __restrict__ deg,
                                                      const int* __restrict__ srt,
                                                      const unsigned short* __restrict__ g1b,
                                                      const float* __restrict__ dinv,
                                                      const float* __restrict__ b1,
                                                      float* __restrict__ h) {
    int n = blockIdx.x * 4 + (threadIdx.x >> 6);
    int lane = threadIdx.x & 63;
    if (n >= N_NODES) return;
    int s = rowptr[n], e = s + deg[n];
    float a0 = 0.f, a1 = 0.f, a2 = 0.f, a3 = 0.f;
    float a4 = 0.f, a5 = 0.f, a6 = 0.f, a7 = 0.f;
    int j = s;
    for (; j + 8 <= e; j += 8) {
        int r0 = srt[j],     r1 = srt[j + 1], r2 = srt[j + 2], r3 = srt[j + 3];
        int r4 = srt[j + 4], r5 = srt[j + 5], r6 = srt[j + 6], r7 = srt[j + 7];
        a0 += bf2f(g1b[(size_t)r0 * HID + lane]);
        a1 += bf2f(g1b[(size_t)r1 * HID + lane]);
        a2 += bf2f(g1b[(size_t)r2 * HID + lane]);
        a3 += bf2f(g1b[(size_t)r3 * HID + lane]);
        a4 += bf2f(g1b[(size_t)r4 * HID + lane]);
        a5 += bf2f(g1b[(size_t)r5 * HID + lane]);
        a6 += bf2f(g1b[(size_t)r6 * HID + lane]);
        a7 += bf2f(g1b[(size_t)r7 * HID + lane]);
    }
    for (; j < e; ++j) a0 += bf2f(g1b[(size_t)srt[j] * HID + lane]);
    float sum = ((a0 + a1) + (a2 + a3)) + ((a4 + a5) + (a6 + a7))
              + bf2f(g1b[(size_t)n * HID + lane]);  // + self-loop
    float t = dinv[n] * sum + b1[lane];
    h[(size_t)n * HID + lane] = t > 0.f ? t : 0.f;
}

// ---------------- layer 2 dense: g2b = bf16((h @ W2) * dinv) ----------------
// register-tiled: tile 128 nodes x 32 f; thread = 4 nodes (stride 32) x 4 f.

__global__ __launch_bounds__(256) void gemm2_tiled(const float* __restrict__ h,
                                                   const float* __restrict__ W2,
                                                   const float* __restrict__ dinv,
                                                   unsigned short* __restrict__ g2b) {
    __shared__ float w[HID * OUT_F];      // 8 KB
    __shared__ float hs[128 * HID];       // 32 KB, swizzled
    float4* hs4 = (float4*)hs;            // row stride 16 float4

    int t = threadIdx.x;
    int base = blockIdx.x * 128;

    for (int i = t; i < HID * OUT_F; i += 256) w[i] = W2[i];

#pragma unroll
    for (int j = 0; j < 8; ++j) {
        int idx = j * 1024 + t * 4;
        int n = idx >> 6;
        int k = idx & 63;
        float4 v = make_float4(0.f, 0.f, 0.f, 0.f);
        if (base + n < N_NODES) v = *(const float4*)&h[(size_t)(base + n) * HID + k];
        hs4[(n << 4) + ((k >> 2) ^ (n & 7))] = v;
    }
    __syncthreads();

    int m0 = t & 31;
    int f0 = (t >> 5) << 2;
    int sw = m0 & 7;

    float acc[4][4];
#pragma unroll
    for (int u = 0; u < 4; ++u)
#pragma unroll
        for (int j = 0; j < 4; ++j) acc[u][j] = 0.f;

    for (int k4 = 0; k4 < HID; k4 += 4) {
        int cb = (k4 >> 2) ^ sw;
        float4 xv[4], wv4[4];
#pragma unroll
        for (int u = 0; u < 4; ++u) xv[u] = hs4[((m0 + 32 * u) << 4) + cb];
#pragma unroll
        for (int kk = 0; kk < 4; ++kk) wv4[kk] = *(float4*)&w[(k4 + kk) * OUT_F + f0];
#pragma unroll
        for (int u = 0; u < 4; ++u) {
            acc[u][0] += xv[u].x * wv4[0].x + xv[u].y * wv4[1].x + xv[u].z * wv4[2].x + xv[u].w * wv4[3].x;
            acc[u][1] += xv[u].x * wv4[0].y + xv[u].y * wv4[1].y + xv[u].z * wv4[2].y + xv[u].w * wv4[3].y;
            acc[u][2] += xv[u].x * wv4[0].z + xv[u].y * wv4[1].z + xv[u].z * wv4[2].z + xv[u].w * wv4[3].z;
            acc[u][3] += xv[u].x * wv4[0].w + xv[u].y * wv4[1].w + xv[u].z * wv4[2].w + xv[u].w * wv4[3].w;
        }
    }

#pragma unroll
    for (int u = 0; u < 4; ++u) {
        int n = base + m0 + 32 * u;
        if (n < N_NODES) {
            float dv = dinv[n];
            ushort4 o;
            o.x = f2bf(acc[u][0] * dv);
            o.y = f2bf(acc[u][1] * dv);
            o.z = f2bf(acc[u][2] * dv);
            o.w = f2bf(acc[u][3] * dv);
            *(ushort4*)&g2b[(size_t)n * OUT_F + f0] = o;
        }
    }
}

// ---------------- layer 2 gather + finalize2 (bf16 reads) ----------------
// half-wave (32 lanes) per node, 8-edge unroll.

__global__ __launch_bounds__(256) void gather2_kernel(const int* __restrict__ rowptr,
                                                      const int* __restrict__ deg,
                                                      const int* __restrict__ srt,
                                                      const unsigned short* __restrict__ g2b,
                                                      const float* __restrict__ dinv,
                                                      const float* __restrict__ b2,
                                                      float* __restrict__ out) {
    int n = blockIdx.x * 8 + (threadIdx.x >> 5);
    int f = threadIdx.x & 31;
    if (n >= N_NODES) return;
    int s = rowptr[n], e = s + deg[n];
    float a0 = 0.f, a1 = 0.f, a2 = 0.f, a3 = 0.f;
    float a4 = 0.f, a5 = 0.f, a6 = 0.f, a7 = 0.f;
    int j = s;
    for (; j + 8 <= e; j += 8) {
        int r0 = srt[j],     r1 = srt[j + 1], r2 = srt[j + 2], r3 = srt[j + 3];
        int r4 = srt[j + 4], r5 = srt[j + 5], r6 = srt[j + 6], r7 = srt[j + 7];
        a0 += bf2f(g2b[(size_t)r0 * OUT_F + f]);
        a1 += bf2f(g2b[(size_t)r1 * OUT_F + f]);
        a2 += bf2f(g2b[(size_t)r2 * OUT_F + f]);
        a3 += bf2f(g2b[(size_t)r3 * OUT_F + f]);
        a4 += bf2f(g2b[(size_t)r4 * OUT_F + f]);
        a5 += bf2f(g2b[(size_t)r5 * OUT_F + f]);
        a6 += bf2f(g2b[(size_t)r6 * OUT_F + f]);
        a7 += bf2f(g2b[(size_t)r7 * OUT_F + f]);
    }
    for (; j < e; ++j) a0 += bf2f(g2b[(size_t)srt[j] * OUT_F + f]);
    float sum = ((a0 + a1) + (a2 + a3)) + ((a4 + a5) + (a6 + a7))
              + bf2f(g2b[(size_t)n * OUT_F + f]);  // + self-loop
    out[(size_t)n * OUT_F + f] = dinv[n] * sum + b2[f];
}

extern "C" void kernel_launch(void* const* d_in, const int* in_sizes, int n_in,
                              void* d_out, int out_size, void* d_ws, size_t ws_size,
                              hipStream_t stream) {
    const float* x   = (const float*)d_in[0];
    const int*   ei  = (const int*)d_in[1];
    const int*   row = ei;             // edge_index[0] = source
    const int*   col = ei + N_EDGES;   // edge_index[1] = target
    const float* W1  = (const float*)d_in[2];
    const float* b1  = (const float*)d_in[3];
    const float* W2  = (const float*)d_in[4];
    const float* b2  = (const float*)d_in[5];
    float* out = (float*)d_out;

    // workspace layout
    char* p = (char*)d_ws;
    float*          dinv = (float*)p;          p += (size_t)N_NODES * 4;        // 0.4 MB
    unsigned short* g1b  = (unsigned short*)p; p += (size_t)N_NODES * HID * 2;  // 12.8 MB
    float*          h    = (float*)p;          p += (size_t)N_NODES * HID * 4;  // 25.6 MB
    unsigned short* g2b  = (unsigned short*)p; p += (size_t)N_NODES * OUT_F * 2;// 6.4 MB
    int*   deg   = (int*)p;   p += (size_t)N_NODES * 4;          // 0.4 MB
    int*   rowp  = (int*)p;   p += (size_t)(N_NODES + 1) * 4;    // 0.4 MB
    int*   bsum  = (int*)p;   p += 512 * 4;
    int*   gcur  = (int*)p;   p += ((NBUCK + 63) & ~63) * 4;
    int*   srt   = (int*)p;   p += (size_t)N_EDGES * 4;          // 6.4 MB
    int*   tmp   = (int*)p;   p += (size_t)N_EDGES * 4;          // 6.4 MB (packed)

    hipMemsetAsync(deg, 0, (size_t)N_NODES * sizeof(int), stream);

    hist_kernel  <<<(N_EDGES + 255) / 256, 256, 0, stream>>>(col, deg);
    scan1d_kernel<<<NB_SCAN, 256, 0, stream>>>(deg, rowp, bsum, dinv);
    scan2_kernel <<<1, 512, 0, stream>>>(bsum);
    scan3b_kernel<<<NB_SCAN, 256, 0, stream>>>(rowp, bsum, gcur);
    binA_kernel  <<<NBLK_A, 256, 0, stream>>>(row, col, gcur, tmp);
    binB_kernel  <<<NBUCK, 512, 0, stream>>>(rowp, tmp, srt);

    gemm1_tiled  <<<(N_NODES + 63) / 64, 256, 0, stream>>>(x, W1, dinv, g1b);
    gather1_kernel<<<(N_NODES + 3) / 4, 256, 0, stream>>>(rowp, deg, srt, g1b, dinv, b1, h);
    gemm2_tiled  <<<(N_NODES + 127) / 128, 256, 0, stream>>>(h, W2, dinv, g2b);
    gather2_kernel<<<(N_NODES + 7) / 8, 256, 0, stream>>>(rowp, deg, srt, g2b, dinv, b2, out);
}

// Round 10
// 293.058 us; speedup vs baseline: 2.1348x; 1.1009x over previous
//
#include <hip/hip_runtime.h>

#define N_NODES 100000
#define N_EDGES 1600000
#define IN_F 128
#define HID 64
#define OUT_F 32
#define NB_SCAN ((N_NODES + 255) / 256)  // 391

#define BSHIFT 10
#define BUCK_N (1 << BSHIFT)                               // 1024 nodes/bucket
#define NBUCK ((N_NODES + BUCK_N - 1) >> BSHIFT)           // 98
#define EPB 8192
#define NBLK_A ((N_EDGES + EPB - 1) / EPB)                 // 196
#define ROW_MASK 0x1FFFF                                   // 17 bits, N < 131072

// bf16 helpers (RNE pack, exact unpack)
__device__ __forceinline__ float bf2f(unsigned short u) {
    return __uint_as_float(((unsigned)u) << 16);
}
__device__ __forceinline__ unsigned short f2bf(float f) {
    unsigned u = __float_as_uint(f);
    u += 0x7FFF + ((u >> 16) & 1);   // round-to-nearest-even
    return (unsigned short)(u >> 16);
}

// ---------------- degree histogram (int) ----------------

__global__ __launch_bounds__(256) void hist_kernel(const int* __restrict__ col,
                                                   int* __restrict__ deg) {
    int e = blockIdx.x * 256 + threadIdx.x;
    if (e < N_EDGES) atomicAdd(&deg[col[e]], 1);
}

// ---------------- scan1 + dinv ----------------

__global__ __launch_bounds__(256) void scan1d_kernel(const int* __restrict__ deg,
                                                     int* __restrict__ excl,
                                                     int* __restrict__ bsum,
                                                     float* __restrict__ dinv) {
    __shared__ int s[256];
    int t = threadIdx.x, i = blockIdx.x * 256 + t;
    int v = (i < N_NODES) ? deg[i] : 0;
    if (i < N_NODES) dinv[i] = rsqrtf((float)v + 1.0f);  // +1 = self-loop
    s[t] = v; __syncthreads();
    for (int off = 1; off < 256; off <<= 1) {
        int x = (t >= off) ? s[t - off] : 0; __syncthreads();
        s[t] += x; __syncthreads();
    }
    if (i < N_NODES) excl[i] = s[t] - v;
    if (t == 255) bsum[blockIdx.x] = s[255];
}

__global__ __launch_bounds__(512) void scan2_kernel(int* __restrict__ bsum) {
    __shared__ int s[512];
    int t = threadIdx.x;
    int v = (t < NB_SCAN) ? bsum[t] : 0;
    s[t] = v; __syncthreads();
    for (int off = 1; off < 512; off <<= 1) {
        int x = (t >= off) ? s[t - off] : 0; __syncthreads();
        s[t] += x; __syncthreads();
    }
    if (t < NB_SCAN) bsum[t] = s[t] - v;  // exclusive block offsets
}

// scan3 + binit fused

__global__ __launch_bounds__(256) void scan3b_kernel(int* __restrict__ excl,
                                                     const int* __restrict__ bsum,
                                                     int* __restrict__ gcur) {
    int i = blockIdx.x * 256 + threadIdx.x;
    if (i < N_NODES) {
        int rp = excl[i] + bsum[blockIdx.x];
        excl[i] = rp;                                   // excl now holds rowptr
        if ((i & (BUCK_N - 1)) == 0) gcur[i >> BSHIFT] = rp;
    }
}

// ---------------- binned reorder (packed payload) ----------------

__global__ __launch_bounds__(256) void binA_kernel(const int* __restrict__ row,
                                                   const int* __restrict__ col,
                                                   int* __restrict__ gcur,
                                                   int* __restrict__ tmp) {
    __shared__ int cnt[NBUCK], base[NBUCK], lcur[NBUCK];
    int t = threadIdx.x;
    int e0 = blockIdx.x * EPB;
    int e1 = e0 + EPB < N_EDGES ? e0 + EPB : N_EDGES;
    for (int i = t; i < NBUCK; i += 256) cnt[i] = 0;
    __syncthreads();
    for (int e = e0 + t; e < e1; e += 256) atomicAdd(&cnt[col[e] >> BSHIFT], 1);
    __syncthreads();
    for (int i = t; i < NBUCK; i += 256) {
        int c = cnt[i];
        base[i] = c ? atomicAdd(&gcur[i], c) : 0;
        lcur[i] = 0;
    }
    __syncthreads();
    for (int e = e0 + t; e < e1; e += 256) {
        int c = col[e];
        int b = c >> BSHIFT;
        int rk = atomicAdd(&lcur[b], 1);
        tmp[base[b] + rk] = ((c & (BUCK_N - 1)) << 17) | row[e];
    }
}

__global__ __launch_bounds__(512) void binB_kernel(const int* __restrict__ rowp,
                                                   const int* __restrict__ tmp,
                                                   int* __restrict__ srt) {
    __shared__ int curs[BUCK_N];  // 4 KB
    int b = blockIdx.x, t = threadIdx.x;
    int nbase = b << BSHIFT;
    int nend = nbase + BUCK_N < N_NODES ? nbase + BUCK_N : N_NODES;
    for (int i = t; i < nend - nbase; i += 512) curs[i] = rowp[nbase + i];
    __syncthreads();
    int s  = rowp[nbase];
    int e1 = (nend < N_NODES) ? rowp[nend] : N_EDGES;
    for (int e = s + t; e < e1; e += 512) {
        int rc = tmp[e];
        int pos = atomicAdd(&curs[rc >> 17], 1);
        srt[pos] = rc & ROW_MASK;
    }
}

// ---------------- layer 1 dense: g1b = bf16((x @ W1) * dinv) ----------------
// register-tiled: tile 64 nodes x 64 f; thread = 4 nodes (stride 16) x 4 f.
// k4 loop unroll capped at 2 to keep VGPR pressure down (256-VGPR bloat seen
// with full unroll -> 9% occupancy).

__global__ __launch_bounds__(256) void gemm1_tiled(const float* __restrict__ x,
                                                   const float* __restrict__ W1,
                                                   const float* __restrict__ dinv,
                                                   unsigned short* __restrict__ g1b) {
    __shared__ float w[IN_F * HID];       // 32 KB, [k][f]
    __shared__ float xs[64 * IN_F];       // 32 KB, swizzled
    float4* xs4 = (float4*)xs;            // row stride 32 float4

    int t = threadIdx.x;
    int base = blockIdx.x * 64;

    for (int i = t; i < IN_F * HID; i += 256) w[i] = W1[i];

#pragma unroll
    for (int j = 0; j < 8; ++j) {
        int idx = j * 1024 + t * 4;
        int n = idx >> 7;
        int k = idx & 127;
        float4 v = make_float4(0.f, 0.f, 0.f, 0.f);
        if (base + n < N_NODES) v = *(const float4*)&x[(size_t)(base + n) * IN_F + k];
        xs4[(n << 5) + ((k >> 2) ^ (n & 7))] = v;
    }
    __syncthreads();

    int m0 = t & 15;
    int f0 = (t >> 4) << 2;
    int sw = m0 & 7;

    float acc[4][4];
#pragma unroll
    for (int u = 0; u < 4; ++u)
#pragma unroll
        for (int j = 0; j < 4; ++j) acc[u][j] = 0.f;

#pragma unroll 2
    for (int k4 = 0; k4 < IN_F; k4 += 4) {
        int cb = (k4 >> 2) ^ sw;
        float4 xv[4], wv[4];
#pragma unroll
        for (int u = 0; u < 4; ++u) xv[u] = xs4[((m0 + 16 * u) << 5) + cb];
#pragma unroll
        for (int kk = 0; kk < 4; ++kk) wv[kk] = *(float4*)&w[(k4 + kk) * HID + f0];
#pragma unroll
        for (int u = 0; u < 4; ++u) {
            acc[u][0] += xv[u].x * wv[0].x + xv[u].y * wv[1].x + xv[u].z * wv[2].x + xv[u].w * wv[3].x;
            acc[u][1] += xv[u].x * wv[0].y + xv[u].y * wv[1].y + xv[u].z * wv[2].y + xv[u].w * wv[3].y;
            acc[u][2] += xv[u].x * wv[0].z + xv[u].y * wv[1].z + xv[u].z * wv[2].z + xv[u].w * wv[3].z;
            acc[u][3] += xv[u].x * wv[0].w + xv[u].y * wv[1].w + xv[u].z * wv[2].w + xv[u].w * wv[3].w;
        }
    }

#pragma unroll
    for (int u = 0; u < 4; ++u) {
        int n = base + m0 + 16 * u;
        if (n < N_NODES) {
            float dv = dinv[n];
            ushort4 o;
            o.x = f2bf(acc[u][0] * dv);
            o.y = f2bf(acc[u][1] * dv);
            o.z = f2bf(acc[u][2] * dv);
            o.w = f2bf(acc[u][3] * dv);
            *(ushort4*)&g1b[(size_t)n * HID + f0] = o;
        }
    }
}

// ---------------- layer 1 gather + finalize1 (bf16 reads, fp32 accum) -------

__global__ __launch_bounds__(256) void gather1_kernel(const int* __restrict__ rowptr,
                                                      const int* __restrict__ deg,
                                                      const int* __restrict__ srt,
                                                      const unsigned short* __restrict__ g1b,
                                                      const float* __restrict__ dinv,
                                                      const float* __restrict__ b1,
                                                      float* __restrict__ h) {
    int n = blockIdx.x * 4 + (threadIdx.x >> 6);
    int lane = threadIdx.x & 63;
    if (n >= N_NODES) return;
    int s = rowptr[n], e = s + deg[n];
    float a0 = 0.f, a1 = 0.f, a2 = 0.f, a3 = 0.f;
    float a4 = 0.f, a5 = 0.f, a6 = 0.f, a7 = 0.f;
    int j = s;
    for (; j + 8 <= e; j += 8) {
        int r0 = srt[j],     r1 = srt[j + 1], r2 = srt[j + 2], r3 = srt[j + 3];
        int r4 = srt[j + 4], r5 = srt[j + 5], r6 = srt[j + 6], r7 = srt[j + 7];
        a0 += bf2f(g1b[(size_t)r0 * HID + lane]);
        a1 += bf2f(g1b[(size_t)r1 * HID + lane]);
        a2 += bf2f(g1b[(size_t)r2 * HID + lane]);
        a3 += bf2f(g1b[(size_t)r3 * HID + lane]);
        a4 += bf2f(g1b[(size_t)r4 * HID + lane]);
        a5 += bf2f(g1b[(size_t)r5 * HID + lane]);
        a6 += bf2f(g1b[(size_t)r6 * HID + lane]);
        a7 += bf2f(g1b[(size_t)r7 * HID + lane]);
    }
    for (; j < e; ++j) a0 += bf2f(g1b[(size_t)srt[j] * HID + lane]);
    float sum = ((a0 + a1) + (a2 + a3)) + ((a4 + a5) + (a6 + a7))
              + bf2f(g1b[(size_t)n * HID + lane]);  // + self-loop
    float t = dinv[n] * sum + b1[lane];
    h[(size_t)n * HID + lane] = t > 0.f ? t : 0.f;
}

// ---------------- layer 2 dense: g2b = bf16((h @ W2) * dinv) ----------------
// REWRITTEN for occupancy: tile 64 nodes x 32 f; thread = 2 nodes (m0, m0+32)
// x 4 f; acc[2][4]; LDS 24 KB; unroll capped.  (Old version: 256 VGPR, 9% occ.)

__global__ __launch_bounds__(256) void gemm2_tiled(const float* __restrict__ h,
                                                   const float* __restrict__ W2,
                                                   const float* __restrict__ dinv,
                                                   unsigned short* __restrict__ g2b) {
    __shared__ float w[HID * OUT_F];      // 8 KB, [k][f]
    __shared__ float hs[64 * HID];        // 16 KB, swizzled
    float4* hs4 = (float4*)hs;            // row stride 16 float4

    int t = threadIdx.x;
    int base = blockIdx.x * 64;

    for (int i = t; i < HID * OUT_F; i += 256) w[i] = W2[i];

#pragma unroll
    for (int j = 0; j < 4; ++j) {         // 64 rows x 64 k = 4096 floats
        int idx = j * 1024 + t * 4;
        int n = idx >> 6;                 // 0..63
        int k = idx & 63;
        float4 v = make_float4(0.f, 0.f, 0.f, 0.f);
        if (base + n < N_NODES) v = *(const float4*)&h[(size_t)(base + n) * HID + k];
        hs4[(n << 4) + ((k >> 2) ^ (n & 7))] = v;
    }
    __syncthreads();

    int m0 = t & 31;           // rows m0, m0+32  ((m0+32)&7 == m0&7, same swizzle)
    int f0 = (t >> 5) << 2;    // 4 features
    int sw = m0 & 7;

    float acc[2][4];
#pragma unroll
    for (int u = 0; u < 2; ++u)
#pragma unroll
        for (int j = 0; j < 4; ++j) acc[u][j] = 0.f;

#pragma unroll 2
    for (int k4 = 0; k4 < HID; k4 += 4) {
        int cb = (k4 >> 2) ^ sw;
        float4 xv[2], wv4[4];
        xv[0] = hs4[(m0 << 4) + cb];
        xv[1] = hs4[((m0 + 32) << 4) + cb];
#pragma unroll
        for (int kk = 0; kk < 4; ++kk) wv4[kk] = *(float4*)&w[(k4 + kk) * OUT_F + f0];
#pragma unroll
        for (int u = 0; u < 2; ++u) {
            acc[u][0] += xv[u].x * wv4[0].x + xv[u].y * wv4[1].x + xv[u].z * wv4[2].x + xv[u].w * wv4[3].x;
            acc[u][1] += xv[u].x * wv4[0].y + xv[u].y * wv4[1].y + xv[u].z * wv4[2].y + xv[u].w * wv4[3].y;
            acc[u][2] += xv[u].x * wv4[0].z + xv[u].y * wv4[1].z + xv[u].z * wv4[2].z + xv[u].w * wv4[3].z;
            acc[u][3] += xv[u].x * wv4[0].w + xv[u].y * wv4[1].w + xv[u].z * wv4[2].w + xv[u].w * wv4[3].w;
        }
    }

#pragma unroll
    for (int u = 0; u < 2; ++u) {
        int n = base + m0 + 32 * u;
        if (n < N_NODES) {
            float dv = dinv[n];
            ushort4 o;
            o.x = f2bf(acc[u][0] * dv);
            o.y = f2bf(acc[u][1] * dv);
            o.z = f2bf(acc[u][2] * dv);
            o.w = f2bf(acc[u][3] * dv);
            *(ushort4*)&g2b[(size_t)n * OUT_F + f0] = o;
        }
    }
}

// ---------------- layer 2 gather + finalize2 (bf16 reads) ----------------

__global__ __launch_bounds__(256) void gather2_kernel(const int* __restrict__ rowptr,
                                                      const int* __restrict__ deg,
                                                      const int* __restrict__ srt,
                                                      const unsigned short* __restrict__ g2b,
                                                      const float* __restrict__ dinv,
                                                      const float* __restrict__ b2,
                                                      float* __restrict__ out) {
    int n = blockIdx.x * 8 + (threadIdx.x >> 5);
    int f = threadIdx.x & 31;
    if (n >= N_NODES) return;
    int s = rowptr[n], e = s + deg[n];
    float a0 = 0.f, a1 = 0.f, a2 = 0.f, a3 = 0.f;
    float a4 = 0.f, a5 = 0.f, a6 = 0.f, a7 = 0.f;
    int j = s;
    for (; j + 8 <= e; j += 8) {
        int r0 = srt[j],     r1 = srt[j + 1], r2 = srt[j + 2], r3 = srt[j + 3];
        int r4 = srt[j + 4], r5 = srt[j + 5], r6 = srt[j + 6], r7 = srt[j + 7];
        a0 += bf2f(g2b[(size_t)r0 * OUT_F + f]);
        a1 += bf2f(g2b[(size_t)r1 * OUT_F + f]);
        a2 += bf2f(g2b[(size_t)r2 * OUT_F + f]);
        a3 += bf2f(g2b[(size_t)r3 * OUT_F + f]);
        a4 += bf2f(g2b[(size_t)r4 * OUT_F + f]);
        a5 += bf2f(g2b[(size_t)r5 * OUT_F + f]);
        a6 += bf2f(g2b[(size_t)r6 * OUT_F + f]);
        a7 += bf2f(g2b[(size_t)r7 * OUT_F + f]);
    }
    for (; j < e; ++j) a0 += bf2f(g2b[(size_t)srt[j] * OUT_F + f]);
    float sum = ((a0 + a1) + (a2 + a3)) + ((a4 + a5) + (a6 + a7))
              + bf2f(g2b[(size_t)n * OUT_F + f]);  // + self-loop
    out[(size_t)n * OUT_F + f] = dinv[n] * sum + b2[f];
}

extern "C" void kernel_launch(void* const* d_in, const int* in_sizes, int n_in,
                              void* d_out, int out_size, void* d_ws, size_t ws_size,
                              hipStream_t stream) {
    const float* x   = (const float*)d_in[0];
    const int*   ei  = (const int*)d_in[1];
    const int*   row = ei;             // edge_index[0] = source
    const int*   col = ei + N_EDGES;   // edge_index[1] = target
    const float* W1  = (const float*)d_in[2];
    const float* b1  = (const float*)d_in[3];
    const float* W2  = (const float*)d_in[4];
    const float* b2  = (const float*)d_in[5];
    float* out = (float*)d_out;

    // workspace layout
    char* p = (char*)d_ws;
    float*          dinv = (float*)p;          p += (size_t)N_NODES * 4;        // 0.4 MB
    unsigned short* g1b  = (unsigned short*)p; p += (size_t)N_NODES * HID * 2;  // 12.8 MB
    float*          h    = (float*)p;          p += (size_t)N_NODES * HID * 4;  // 25.6 MB
    unsigned short* g2b  = (unsigned short*)p; p += (size_t)N_NODES * OUT_F * 2;// 6.4 MB
    int*   deg   = (int*)p;   p += (size_t)N_NODES * 4;          // 0.4 MB
    int*   rowp  = (int*)p;   p += (size_t)(N_NODES + 1) * 4;    // 0.4 MB
    int*   bsum  = (int*)p;   p += 512 * 4;
    int*   gcur  = (int*)p;   p += ((NBUCK + 63) & ~63) * 4;
    int*   srt   = (int*)p;   p += (size_t)N_EDGES * 4;          // 6.4 MB
    int*   tmp   = (int*)p;   p += (size_t)N_EDGES * 4;          // 6.4 MB (packed)

    hipMemsetAsync(deg, 0, (size_t)N_NODES * sizeof(int), stream);

    hist_kernel  <<<(N_EDGES + 255) / 256, 256, 0, stream>>>(col, deg);
    scan1d_kernel<<<NB_SCAN, 256, 0, stream>>>(deg, rowp, bsum, dinv);
    scan2_kernel <<<1, 512, 0, stream>>>(bsum);
    scan3b_kernel<<<NB_SCAN, 256, 0, stream>>>(rowp, bsum, gcur);
    binA_kernel  <<<NBLK_A, 256, 0, stream>>>(row, col, gcur, tmp);
    binB_kernel  <<<NBUCK, 512, 0, stream>>>(rowp, tmp, srt);

    gemm1_tiled  <<<(N_NODES + 63) / 64, 256, 0, stream>>>(x, W1, dinv, g1b);
    gather1_kernel<<<(N_NODES + 3) / 4, 256, 0, stream>>>(rowp, deg, srt, g1b, dinv, b1, h);
    gemm2_tiled  <<<(N_NODES + 63) / 64, 256, 0, stream>>>(h, W2, dinv, g2b);
    gather2_kernel<<<(N_NODES + 7) / 8, 256, 0, stream>>>(rowp, deg, srt, g2b, dinv, b2, out);
}

// Round 11
// 263.820 us; speedup vs baseline: 2.3714x; 1.1108x over previous
//
#include <hip/hip_runtime.h>

#define N_NODES 100000
#define N_EDGES 1600000
#define IN_F 128
#define HID 64
#define OUT_F 32
#define NB_SCAN ((N_NODES + 255) / 256)  // 391

#define BSHIFT 10
#define BUCK_N (1 << BSHIFT)                               // 1024 nodes/bucket
#define NBUCK ((N_NODES + BUCK_N - 1) >> BSHIFT)           // 98
#define EPB 8192
#define NBLK_A ((N_EDGES + EPB - 1) / EPB)                 // 196
#define ROW_MASK 0x1FFFF                                   // 17 bits, N < 131072

// bf16 helpers
__device__ __forceinline__ float bf2f(unsigned short u) {
    return __uint_as_float(((unsigned)u) << 16);
}
__device__ __forceinline__ float bflo(unsigned u) { return __uint_as_float(u << 16); }
__device__ __forceinline__ float bfhi(unsigned u) { return __uint_as_float(u & 0xffff0000u); }
__device__ __forceinline__ unsigned short f2bf(float f) {
    unsigned u = __float_as_uint(f);
    u += 0x7FFF + ((u >> 16) & 1);   // round-to-nearest-even
    return (unsigned short)(u >> 16);
}

// ---------------- degree histogram (int) ----------------

__global__ __launch_bounds__(256) void hist_kernel(const int* __restrict__ col,
                                                   int* __restrict__ deg) {
    int e = blockIdx.x * 256 + threadIdx.x;
    if (e < N_EDGES) atomicAdd(&deg[col[e]], 1);
}

// ---------------- scan1 + dinv ----------------

__global__ __launch_bounds__(256) void scan1d_kernel(const int* __restrict__ deg,
                                                     int* __restrict__ excl,
                                                     int* __restrict__ bsum,
                                                     float* __restrict__ dinv) {
    __shared__ int s[256];
    int t = threadIdx.x, i = blockIdx.x * 256 + t;
    int v = (i < N_NODES) ? deg[i] : 0;
    if (i < N_NODES) dinv[i] = rsqrtf((float)v + 1.0f);  // +1 = self-loop
    s[t] = v; __syncthreads();
    for (int off = 1; off < 256; off <<= 1) {
        int x = (t >= off) ? s[t - off] : 0; __syncthreads();
        s[t] += x; __syncthreads();
    }
    if (i < N_NODES) excl[i] = s[t] - v;
    if (t == 255) bsum[blockIdx.x] = s[255];
}

__global__ __launch_bounds__(512) void scan2_kernel(int* __restrict__ bsum) {
    __shared__ int s[512];
    int t = threadIdx.x;
    int v = (t < NB_SCAN) ? bsum[t] : 0;
    s[t] = v; __syncthreads();
    for (int off = 1; off < 512; off <<= 1) {
        int x = (t >= off) ? s[t - off] : 0; __syncthreads();
        s[t] += x; __syncthreads();
    }
    if (t < NB_SCAN) bsum[t] = s[t] - v;  // exclusive block offsets
}

// scan3 + binit fused

__global__ __launch_bounds__(256) void scan3b_kernel(int* __restrict__ excl,
                                                     const int* __restrict__ bsum,
                                                     int* __restrict__ gcur) {
    int i = blockIdx.x * 256 + threadIdx.x;
    if (i < N_NODES) {
        int rp = excl[i] + bsum[blockIdx.x];
        excl[i] = rp;                                   // excl now holds rowptr
        if ((i & (BUCK_N - 1)) == 0) gcur[i >> BSHIFT] = rp;
    }
}

// ---------------- binned reorder (packed payload) ----------------

__global__ __launch_bounds__(256) void binA_kernel(const int* __restrict__ row,
                                                   const int* __restrict__ col,
                                                   int* __restrict__ gcur,
                                                   int* __restrict__ tmp) {
    __shared__ int cnt[NBUCK], base[NBUCK], lcur[NBUCK];
    int t = threadIdx.x;
    int e0 = blockIdx.x * EPB;
    int e1 = e0 + EPB < N_EDGES ? e0 + EPB : N_EDGES;
    for (int i = t; i < NBUCK; i += 256) cnt[i] = 0;
    __syncthreads();
    for (int e = e0 + t; e < e1; e += 256) atomicAdd(&cnt[col[e] >> BSHIFT], 1);
    __syncthreads();
    for (int i = t; i < NBUCK; i += 256) {
        int c = cnt[i];
        base[i] = c ? atomicAdd(&gcur[i], c) : 0;
        lcur[i] = 0;
    }
    __syncthreads();
    for (int e = e0 + t; e < e1; e += 256) {
        int c = col[e];
        int b = c >> BSHIFT;
        int rk = atomicAdd(&lcur[b], 1);
        tmp[base[b] + rk] = ((c & (BUCK_N - 1)) << 17) | row[e];
    }
}

__global__ __launch_bounds__(512) void binB_kernel(const int* __restrict__ rowp,
                                                   const int* __restrict__ tmp,
                                                   int* __restrict__ srt) {
    __shared__ int curs[BUCK_N];  // 4 KB
    int b = blockIdx.x, t = threadIdx.x;
    int nbase = b << BSHIFT;
    int nend = nbase + BUCK_N < N_NODES ? nbase + BUCK_N : N_NODES;
    for (int i = t; i < nend - nbase; i += 512) curs[i] = rowp[nbase + i];
    __syncthreads();
    int s  = rowp[nbase];
    int e1 = (nend < N_NODES) ? rowp[nend] : N_EDGES;
    for (int e = s + t; e < e1; e += 512) {
        int rc = tmp[e];
        int pos = atomicAdd(&curs[rc >> 17], 1);
        srt[pos] = rc & ROW_MASK;
    }
}

// ---------------- layer 1 dense: g1b = bf16((x @ W1) * dinv) ----------------

__global__ __launch_bounds__(256) void gemm1_tiled(const float* __restrict__ x,
                                                   const float* __restrict__ W1,
                                                   const float* __restrict__ dinv,
                                                   unsigned short* __restrict__ g1b) {
    __shared__ float w[IN_F * HID];       // 32 KB, [k][f]
    __shared__ float xs[64 * IN_F];       // 32 KB, swizzled
    float4* xs4 = (float4*)xs;            // row stride 32 float4

    int t = threadIdx.x;
    int base = blockIdx.x * 64;

    for (int i = t; i < IN_F * HID; i += 256) w[i] = W1[i];

#pragma unroll
    for (int j = 0; j < 8; ++j) {
        int idx = j * 1024 + t * 4;
        int n = idx >> 7;
        int k = idx & 127;
        float4 v = make_float4(0.f, 0.f, 0.f, 0.f);
        if (base + n < N_NODES) v = *(const float4*)&x[(size_t)(base + n) * IN_F + k];
        xs4[(n << 5) + ((k >> 2) ^ (n & 7))] = v;
    }
    __syncthreads();

    int m0 = t & 15;
    int f0 = (t >> 4) << 2;
    int sw = m0 & 7;

    float acc[4][4];
#pragma unroll
    for (int u = 0; u < 4; ++u)
#pragma unroll
        for (int j = 0; j < 4; ++j) acc[u][j] = 0.f;

#pragma unroll 2
    for (int k4 = 0; k4 < IN_F; k4 += 4) {
        int cb = (k4 >> 2) ^ sw;
        float4 xv[4], wv[4];
#pragma unroll
        for (int u = 0; u < 4; ++u) xv[u] = xs4[((m0 + 16 * u) << 5) + cb];
#pragma unroll
        for (int kk = 0; kk < 4; ++kk) wv[kk] = *(float4*)&w[(k4 + kk) * HID + f0];
#pragma unroll
        for (int u = 0; u < 4; ++u) {
            acc[u][0] += xv[u].x * wv[0].x + xv[u].y * wv[1].x + xv[u].z * wv[2].x + xv[u].w * wv[3].x;
            acc[u][1] += xv[u].x * wv[0].y + xv[u].y * wv[1].y + xv[u].z * wv[2].y + xv[u].w * wv[3].y;
            acc[u][2] += xv[u].x * wv[0].z + xv[u].y * wv[1].z + xv[u].z * wv[2].z + xv[u].w * wv[3].z;
            acc[u][3] += xv[u].x * wv[0].w + xv[u].y * wv[1].w + xv[u].z * wv[2].w + xv[u].w * wv[3].w;
        }
    }

#pragma unroll
    for (int u = 0; u < 4; ++u) {
        int n = base + m0 + 16 * u;
        if (n < N_NODES) {
            float dv = dinv[n];
            ushort4 o;
            o.x = f2bf(acc[u][0] * dv);
            o.y = f2bf(acc[u][1] * dv);
            o.z = f2bf(acc[u][2] * dv);
            o.w = f2bf(acc[u][3] * dv);
            *(ushort4*)&g1b[(size_t)n * HID + f0] = o;
        }
    }
}

// ---------------- layer 1 gather + finalize1 ----------------
// 4 nodes per wave: 16 lanes/node, lane holds 4 features (uint2 = 4 bf16).
// 32-bit offsets -> saddr-form loads; every loop instr retires 4 edges.

__global__ __launch_bounds__(256) void gather1_kernel(const int* __restrict__ rowptr,
                                                      const int* __restrict__ deg,
                                                      const int* __restrict__ srt,
                                                      const unsigned short* __restrict__ g1b,
                                                      const float* __restrict__ dinv,
                                                      const float* __restrict__ b1,
                                                      float* __restrict__ h) {
    int t = threadIdx.x;
    int n = blockIdx.x * 16 + (t >> 4);   // 16 nodes per block
    int lane16 = t & 15;
    if (n >= N_NODES) return;
    int s = rowptr[n];
    int e = s + deg[n];
    unsigned fo = lane16 << 2;            // feature offset 0..60

    float a0 = 0.f, a1 = 0.f, a2 = 0.f, a3 = 0.f;
    float c0 = 0.f, c1 = 0.f, c2 = 0.f, c3 = 0.f;
    int j = s;
    for (; j + 2 <= e; j += 2) {
        int r0 = srt[j], r1 = srt[j + 1];
        uint2 v0 = *(const uint2*)&g1b[(unsigned)(r0 << 6) + fo];
        uint2 v1 = *(const uint2*)&g1b[(unsigned)(r1 << 6) + fo];
        a0 += bflo(v0.x); a1 += bfhi(v0.x); a2 += bflo(v0.y); a3 += bfhi(v0.y);
        c0 += bflo(v1.x); c1 += bfhi(v1.x); c2 += bflo(v1.y); c3 += bfhi(v1.y);
    }
    if (j < e) {
        int r0 = srt[j];
        uint2 v0 = *(const uint2*)&g1b[(unsigned)(r0 << 6) + fo];
        a0 += bflo(v0.x); a1 += bfhi(v0.x); a2 += bflo(v0.y); a3 += bfhi(v0.y);
    }
    // self-loop
    uint2 vs = *(const uint2*)&g1b[(unsigned)(n << 6) + fo];
    a0 += c0 + bflo(vs.x); a1 += c1 + bfhi(vs.x);
    a2 += c2 + bflo(vs.y); a3 += c3 + bfhi(vs.y);

    float dv = dinv[n];
    float4 bb = *(const float4*)&b1[fo];
    float4 o;
    o.x = dv * a0 + bb.x; o.y = dv * a1 + bb.y;
    o.z = dv * a2 + bb.z; o.w = dv * a3 + bb.w;
    o.x = o.x > 0.f ? o.x : 0.f;
    o.y = o.y > 0.f ? o.y : 0.f;
    o.z = o.z > 0.f ? o.z : 0.f;
    o.w = o.w > 0.f ? o.w : 0.f;
    *(float4*)&h[(unsigned)(n << 6) + fo] = o;
}

// ---------------- layer 2 dense: g2b = bf16((h @ W2) * dinv) ----------------
// tile 64 nodes x 32 f; thread = 2 nodes (m0, m0+32) x 4 f; acc[2][4].

__global__ __launch_bounds__(256) void gemm2_tiled(const float* __restrict__ h,
                                                   const float* __restrict__ W2,
                                                   const float* __restrict__ dinv,
                                                   unsigned short* __restrict__ g2b) {
    __shared__ float w[HID * OUT_F];      // 8 KB, [k][f]
    __shared__ float hs[64 * HID];        // 16 KB, swizzled
    float4* hs4 = (float4*)hs;            // row stride 16 float4

    int t = threadIdx.x;
    int base = blockIdx.x * 64;

    for (int i = t; i < HID * OUT_F; i += 256) w[i] = W2[i];

#pragma unroll
    for (int j = 0; j < 4; ++j) {         // 64 rows x 64 k = 4096 floats
        int idx = j * 1024 + t * 4;
        int n = idx >> 6;                 // 0..63
        int k = idx & 63;
        float4 v = make_float4(0.f, 0.f, 0.f, 0.f);
        if (base + n < N_NODES) v = *(const float4*)&h[(size_t)(base + n) * HID + k];
        hs4[(n << 4) + ((k >> 2) ^ (n & 7))] = v;
    }
    __syncthreads();

    int m0 = t & 31;
    int f0 = (t >> 5) << 2;
    int sw = m0 & 7;

    float acc[2][4];
#pragma unroll
    for (int u = 0; u < 2; ++u)
#pragma unroll
        for (int j = 0; j < 4; ++j) acc[u][j] = 0.f;

#pragma unroll 2
    for (int k4 = 0; k4 < HID; k4 += 4) {
        int cb = (k4 >> 2) ^ sw;
        float4 xv[2], wv4[4];
        xv[0] = hs4[(m0 << 4) + cb];
        xv[1] = hs4[((m0 + 32) << 4) + cb];
#pragma unroll
        for (int kk = 0; kk < 4; ++kk) wv4[kk] = *(float4*)&w[(k4 + kk) * OUT_F + f0];
#pragma unroll
        for (int u = 0; u < 2; ++u) {
            acc[u][0] += xv[u].x * wv4[0].x + xv[u].y * wv4[1].x + xv[u].z * wv4[2].x + xv[u].w * wv4[3].x;
            acc[u][1] += xv[u].x * wv4[0].y + xv[u].y * wv4[1].y + xv[u].z * wv4[2].y + xv[u].w * wv4[3].y;
            acc[u][2] += xv[u].x * wv4[0].z + xv[u].y * wv4[1].z + xv[u].z * wv4[2].z + xv[u].w * wv4[3].z;
            acc[u][3] += xv[u].x * wv4[0].w + xv[u].y * wv4[1].w + xv[u].z * wv4[2].w + xv[u].w * wv4[3].w;
        }
    }

#pragma unroll
    for (int u = 0; u < 2; ++u) {
        int n = base + m0 + 32 * u;
        if (n < N_NODES) {
            float dv = dinv[n];
            ushort4 o;
            o.x = f2bf(acc[u][0] * dv);
            o.y = f2bf(acc[u][1] * dv);
            o.z = f2bf(acc[u][2] * dv);
            o.w = f2bf(acc[u][3] * dv);
            *(ushort4*)&g2b[(size_t)n * OUT_F + f0] = o;
        }
    }
}

// ---------------- layer 2 gather + finalize2 ----------------
// 4 nodes per wave: 16 lanes/node, lane holds 2 features (uint = 2 bf16).

__global__ __launch_bounds__(256) void gather2_kernel(const int* __restrict__ rowptr,
                                                      const int* __restrict__ deg,
                                                      const int* __restrict__ srt,
                                                      const unsigned short* __restrict__ g2b,
                                                      const float* __restrict__ dinv,
                                                      const float* __restrict__ b2,
                                                      float* __restrict__ out) {
    int t = threadIdx.x;
    int n = blockIdx.x * 16 + (t >> 4);   // 16 nodes per block
    int lane16 = t & 15;
    if (n >= N_NODES) return;
    int s = rowptr[n];
    int e = s + deg[n];
    unsigned fo = lane16 << 1;            // feature offset 0..30

    float a0 = 0.f, a1 = 0.f, c0 = 0.f, c1 = 0.f;
    int j = s;
    for (; j + 2 <= e; j += 2) {
        int r0 = srt[j], r1 = srt[j + 1];
        unsigned v0 = *(const unsigned*)&g2b[(unsigned)(r0 << 5) + fo];
        unsigned v1 = *(const unsigned*)&g2b[(unsigned)(r1 << 5) + fo];
        a0 += bflo(v0); a1 += bfhi(v0);
        c0 += bflo(v1); c1 += bfhi(v1);
    }
    if (j < e) {
        unsigned v0 = *(const unsigned*)&g2b[(unsigned)(srt[j] << 5) + fo];
        a0 += bflo(v0); a1 += bfhi(v0);
    }
    unsigned vs = *(const unsigned*)&g2b[(unsigned)(n << 5) + fo];
    a0 += c0 + bflo(vs); a1 += c1 + bfhi(vs);

    float dv = dinv[n];
    float2 o;
    o.x = dv * a0 + b2[fo];
    o.y = dv * a1 + b2[fo + 1];
    *(float2*)&out[(unsigned)(n << 5) + fo] = o;
}

extern "C" void kernel_launch(void* const* d_in, const int* in_sizes, int n_in,
                              void* d_out, int out_size, void* d_ws, size_t ws_size,
                              hipStream_t stream) {
    const float* x   = (const float*)d_in[0];
    const int*   ei  = (const int*)d_in[1];
    const int*   row = ei;             // edge_index[0] = source
    const int*   col = ei + N_EDGES;   // edge_index[1] = target
    const float* W1  = (const float*)d_in[2];
    const float* b1  = (const float*)d_in[3];
    const float* W2  = (const float*)d_in[4];
    const float* b2  = (const float*)d_in[5];
    float* out = (float*)d_out;

    // workspace layout
    char* p = (char*)d_ws;
    float*          dinv = (float*)p;          p += (size_t)N_NODES * 4;        // 0.4 MB
    unsigned short* g1b  = (unsigned short*)p; p += (size_t)N_NODES * HID * 2;  // 12.8 MB
    float*          h    = (float*)p;          p += (size_t)N_NODES * HID * 4;  // 25.6 MB
    unsigned short* g2b  = (unsigned short*)p; p += (size_t)N_NODES * OUT_F * 2;// 6.4 MB
    int*   deg   = (int*)p;   p += (size_t)N_NODES * 4;          // 0.4 MB
    int*   rowp  = (int*)p;   p += (size_t)(N_NODES + 1) * 4;    // 0.4 MB
    int*   bsum  = (int*)p;   p += 512 * 4;
    int*   gcur  = (int*)p;   p += ((NBUCK + 63) & ~63) * 4;
    int*   srt   = (int*)p;   p += (size_t)N_EDGES * 4;          // 6.4 MB
    int*   tmp   = (int*)p;   p += (size_t)N_EDGES * 4;          // 6.4 MB (packed)

    hipMemsetAsync(deg, 0, (size_t)N_NODES * sizeof(int), stream);

    hist_kernel  <<<(N_EDGES + 255) / 256, 256, 0, stream>>>(col, deg);
    scan1d_kernel<<<NB_SCAN, 256, 0, stream>>>(deg, rowp, bsum, dinv);
    scan2_kernel <<<1, 512, 0, stream>>>(bsum);
    scan3b_kernel<<<NB_SCAN, 256, 0, stream>>>(rowp, bsum, gcur);
    binA_kernel  <<<NBLK_A, 256, 0, stream>>>(row, col, gcur, tmp);
    binB_kernel  <<<NBUCK, 512, 0, stream>>>(rowp, tmp, srt);

    gemm1_tiled  <<<(N_NODES + 63) / 64, 256, 0, stream>>>(x, W1, dinv, g1b);
    gather1_kernel<<<(N_NODES + 15) / 16, 256, 0, stream>>>(rowp, deg, srt, g1b, dinv, b1, h);
    gemm2_tiled  <<<(N_NODES + 63) / 64, 256, 0, stream>>>(h, W2, dinv, g2b);
    gather2_kernel<<<(N_NODES + 15) / 16, 256, 0, stream>>>(rowp, deg, srt, g2b, dinv, b2, out);
}

// Round 12
// 204.205 us; speedup vs baseline: 3.0638x; 1.2919x over previous
//
#include <hip/hip_runtime.h>

#define N_NODES 100000
#define N_EDGES 1600000
#define IN_F 128
#define HID 64
#define OUT_F 32

#define BSHIFT 9
#define BUCK_N (1 << BSHIFT)                               // 512 nodes/bucket
#define NBUCK ((N_NODES + BUCK_N - 1) >> BSHIFT)           // 196
#define EPB 8192
#define NBLK_A ((N_EDGES + EPB - 1) / EPB)                 // 196
#define ROW_MASK 0x1FFFF                                   // 17 bits, N < 131072

// bf16 helpers
__device__ __forceinline__ float bflo(unsigned u) { return __uint_as_float(u << 16); }
__device__ __forceinline__ float bfhi(unsigned u) { return __uint_as_float(u & 0xffff0000u); }
__device__ __forceinline__ unsigned short f2bf(float f) {
    unsigned u = __float_as_uint(f);
    u += 0x7FFF + ((u >> 16) & 1);   // round-to-nearest-even
    return (unsigned short)(u >> 16);
}

// ---------------- bucket histogram (LDS-privatized) ----------------

__global__ __launch_bounds__(256) void bhist_kernel(const int* __restrict__ col,
                                                    int* __restrict__ gbcnt) {
    __shared__ int cnt[NBUCK];
    int t = threadIdx.x;
    int e0 = blockIdx.x * EPB;
    int e1 = e0 + EPB < N_EDGES ? e0 + EPB : N_EDGES;
    for (int i = t; i < NBUCK; i += 256) cnt[i] = 0;
    __syncthreads();
    for (int e = e0 + t; e < e1; e += 256) atomicAdd(&cnt[col[e] >> BSHIFT], 1);
    __syncthreads();
    for (int i = t; i < NBUCK; i += 256)
        if (cnt[i]) atomicAdd(&gbcnt[i], cnt[i]);
}

// ---------------- bucket scan: boff (exclusive) + gcur seed ----------------

__global__ __launch_bounds__(256) void bscan_kernel(const int* __restrict__ gbcnt,
                                                    int* __restrict__ boff,
                                                    int* __restrict__ gcur) {
    __shared__ int s[256];
    int t = threadIdx.x;
    int v = (t < NBUCK) ? gbcnt[t] : 0;
    s[t] = v; __syncthreads();
    for (int off = 1; off < 256; off <<= 1) {
        int x = (t >= off) ? s[t - off] : 0; __syncthreads();
        s[t] += x; __syncthreads();
    }
    if (t < NBUCK) {
        int o = s[t] - v;
        boff[t] = o;
        gcur[t] = o;
    }
    if (t == 0) boff[NBUCK] = N_EDGES;
}

// ---------------- binA: group edges by bucket into tmp (packed) ----------------

__global__ __launch_bounds__(256) void binA_kernel(const int* __restrict__ row,
                                                   const int* __restrict__ col,
                                                   int* __restrict__ gcur,
                                                   int* __restrict__ tmp) {
    __shared__ int cnt[NBUCK], base[NBUCK], lcur[NBUCK];
    int t = threadIdx.x;
    int e0 = blockIdx.x * EPB;
    int e1 = e0 + EPB < N_EDGES ? e0 + EPB : N_EDGES;
    for (int i = t; i < NBUCK; i += 256) cnt[i] = 0;
    __syncthreads();
    for (int e = e0 + t; e < e1; e += 256) atomicAdd(&cnt[col[e] >> BSHIFT], 1);
    __syncthreads();
    for (int i = t; i < NBUCK; i += 256) {
        int c = cnt[i];
        base[i] = c ? atomicAdd(&gcur[i], c) : 0;
        lcur[i] = 0;
    }
    __syncthreads();
    for (int e = e0 + t; e < e1; e += 256) {
        int c = col[e];
        int b = c >> BSHIFT;
        int rk = atomicAdd(&lcur[b], 1);
        tmp[base[b] + rk] = ((c & (BUCK_N - 1)) << 17) | row[e];
    }
}

// ---------------- binB2: per-bucket hist + scan + rowp/deg/dinv + sort -------
// 196 blocks x 512 threads; all per-node counter work in LDS.

__global__ __launch_bounds__(512) void binB2_kernel(const int* __restrict__ boff,
                                                    const int* __restrict__ tmp,
                                                    int* __restrict__ srt,
                                                    int* __restrict__ rowp,
                                                    int* __restrict__ deg,
                                                    float* __restrict__ dinv) {
    __shared__ int cnt[BUCK_N];   // 2 KB: hist -> inclusive scan -> cursors
    int b = blockIdx.x, t = threadIdx.x;
    int nbase = b << BSHIFT;
    int s  = boff[b];
    int e1 = boff[b + 1];

    cnt[t] = 0;
    __syncthreads();
    for (int e = s + t; e < e1; e += 512) atomicAdd(&cnt[tmp[e] >> 17], 1);
    __syncthreads();

    int v = cnt[t];               // this node's degree
    // in-place inclusive scan over 512
    for (int off = 1; off < 512; off <<= 1) {
        int x = (t >= off) ? cnt[t - off] : 0; __syncthreads();
        cnt[t] += x; __syncthreads();
    }
    int rowpos = s + cnt[t] - v;  // global exclusive position
    int n = nbase + t;
    if (n < N_NODES) {
        rowp[n] = rowpos;
        deg[n]  = v;
        dinv[n] = rsqrtf((float)v + 1.0f);  // +1 = self-loop
    }
    __syncthreads();
    cnt[t] = rowpos;              // now cursors
    __syncthreads();
    for (int e = s + t; e < e1; e += 512) {
        int rc = tmp[e];
        int pos = atomicAdd(&cnt[rc >> 17], 1);
        srt[pos] = rc & ROW_MASK;
    }
}

// ---------------- layer 1 dense: g1b = bf16((x @ W1) * dinv) ----------------

__global__ __launch_bounds__(256) void gemm1_tiled(const float* __restrict__ x,
                                                   const float* __restrict__ W1,
                                                   const float* __restrict__ dinv,
                                                   unsigned short* __restrict__ g1b) {
    __shared__ float w[IN_F * HID];       // 32 KB, [k][f]
    __shared__ float xs[64 * IN_F];       // 32 KB, swizzled
    float4* xs4 = (float4*)xs;            // row stride 32 float4

    int t = threadIdx.x;
    int base = blockIdx.x * 64;

    for (int i = t; i < IN_F * HID; i += 256) w[i] = W1[i];

#pragma unroll
    for (int j = 0; j < 8; ++j) {
        int idx = j * 1024 + t * 4;
        int n = idx >> 7;
        int k = idx & 127;
        float4 v = make_float4(0.f, 0.f, 0.f, 0.f);
        if (base + n < N_NODES) v = *(const float4*)&x[(size_t)(base + n) * IN_F + k];
        xs4[(n << 5) + ((k >> 2) ^ (n & 7))] = v;
    }
    __syncthreads();

    int m0 = t & 15;
    int f0 = (t >> 4) << 2;
    int sw = m0 & 7;

    float acc[4][4];
#pragma unroll
    for (int u = 0; u < 4; ++u)
#pragma unroll
        for (int j = 0; j < 4; ++j) acc[u][j] = 0.f;

#pragma unroll 2
    for (int k4 = 0; k4 < IN_F; k4 += 4) {
        int cb = (k4 >> 2) ^ sw;
        float4 xv[4], wv[4];
#pragma unroll
        for (int u = 0; u < 4; ++u) xv[u] = xs4[((m0 + 16 * u) << 5) + cb];
#pragma unroll
        for (int kk = 0; kk < 4; ++kk) wv[kk] = *(float4*)&w[(k4 + kk) * HID + f0];
#pragma unroll
        for (int u = 0; u < 4; ++u) {
            acc[u][0] += xv[u].x * wv[0].x + xv[u].y * wv[1].x + xv[u].z * wv[2].x + xv[u].w * wv[3].x;
            acc[u][1] += xv[u].x * wv[0].y + xv[u].y * wv[1].y + xv[u].z * wv[2].y + xv[u].w * wv[3].y;
            acc[u][2] += xv[u].x * wv[0].z + xv[u].y * wv[1].z + xv[u].z * wv[2].z + xv[u].w * wv[3].z;
            acc[u][3] += xv[u].x * wv[0].w + xv[u].y * wv[1].w + xv[u].z * wv[2].w + xv[u].w * wv[3].w;
        }
    }

#pragma unroll
    for (int u = 0; u < 4; ++u) {
        int n = base + m0 + 16 * u;
        if (n < N_NODES) {
            float dv = dinv[n];
            ushort4 o;
            o.x = f2bf(acc[u][0] * dv);
            o.y = f2bf(acc[u][1] * dv);
            o.z = f2bf(acc[u][2] * dv);
            o.w = f2bf(acc[u][3] * dv);
            *(ushort4*)&g1b[(size_t)n * HID + f0] = o;
        }
    }
}

// ---------------- layer 1 gather + finalize1 ----------------
// 4 nodes per wave: 16 lanes/node, lane holds 4 features (uint2 = 4 bf16).

__global__ __launch_bounds__(256) void gather1_kernel(const int* __restrict__ rowptr,
                                                      const int* __restrict__ deg,
                                                      const int* __restrict__ srt,
                                                      const unsigned short* __restrict__ g1b,
                                                      const float* __restrict__ dinv,
                                                      const float* __restrict__ b1,
                                                      float* __restrict__ h) {
    int t = threadIdx.x;
    int n = blockIdx.x * 16 + (t >> 4);   // 16 nodes per block
    int lane16 = t & 15;
    if (n >= N_NODES) return;
    int s = rowptr[n];
    int e = s + deg[n];
    unsigned fo = lane16 << 2;            // feature offset 0..60

    float a0 = 0.f, a1 = 0.f, a2 = 0.f, a3 = 0.f;
    float c0 = 0.f, c1 = 0.f, c2 = 0.f, c3 = 0.f;
    int j = s;
    for (; j + 2 <= e; j += 2) {
        int r0 = srt[j], r1 = srt[j + 1];
        uint2 v0 = *(const uint2*)&g1b[(unsigned)(r0 << 6) + fo];
        uint2 v1 = *(const uint2*)&g1b[(unsigned)(r1 << 6) + fo];
        a0 += bflo(v0.x); a1 += bfhi(v0.x); a2 += bflo(v0.y); a3 += bfhi(v0.y);
        c0 += bflo(v1.x); c1 += bfhi(v1.x); c2 += bflo(v1.y); c3 += bfhi(v1.y);
    }
    if (j < e) {
        int r0 = srt[j];
        uint2 v0 = *(const uint2*)&g1b[(unsigned)(r0 << 6) + fo];
        a0 += bflo(v0.x); a1 += bfhi(v0.x); a2 += bflo(v0.y); a3 += bfhi(v0.y);
    }
    // self-loop
    uint2 vs = *(const uint2*)&g1b[(unsigned)(n << 6) + fo];
    a0 += c0 + bflo(vs.x); a1 += c1 + bfhi(vs.x);
    a2 += c2 + bflo(vs.y); a3 += c3 + bfhi(vs.y);

    float dv = dinv[n];
    float4 bb = *(const float4*)&b1[fo];
    float4 o;
    o.x = dv * a0 + bb.x; o.y = dv * a1 + bb.y;
    o.z = dv * a2 + bb.z; o.w = dv * a3 + bb.w;
    o.x = o.x > 0.f ? o.x : 0.f;
    o.y = o.y > 0.f ? o.y : 0.f;
    o.z = o.z > 0.f ? o.z : 0.f;
    o.w = o.w > 0.f ? o.w : 0.f;
    *(float4*)&h[(unsigned)(n << 6) + fo] = o;
}

// ---------------- layer 2 dense: g2b = bf16((h @ W2) * dinv) ----------------

__global__ __launch_bounds__(256) void gemm2_tiled(const float* __restrict__ h,
                                                   const float* __restrict__ W2,
                                                   const float* __restrict__ dinv,
                                                   unsigned short* __restrict__ g2b) {
    __shared__ float w[HID * OUT_F];      // 8 KB, [k][f]
    __shared__ float hs[64 * HID];        // 16 KB, swizzled
    float4* hs4 = (float4*)hs;            // row stride 16 float4

    int t = threadIdx.x;
    int base = blockIdx.x * 64;

    for (int i = t; i < HID * OUT_F; i += 256) w[i] = W2[i];

#pragma unroll
    for (int j = 0; j < 4; ++j) {         // 64 rows x 64 k = 4096 floats
        int idx = j * 1024 + t * 4;
        int n = idx >> 6;                 // 0..63
        int k = idx & 63;
        float4 v = make_float4(0.f, 0.f, 0.f, 0.f);
        if (base + n < N_NODES) v = *(const float4*)&h[(size_t)(base + n) * HID + k];
        hs4[(n << 4) + ((k >> 2) ^ (n & 7))] = v;
    }
    __syncthreads();

    int m0 = t & 31;
    int f0 = (t >> 5) << 2;
    int sw = m0 & 7;

    float acc[2][4];
#pragma unroll
    for (int u = 0; u < 2; ++u)
#pragma unroll
        for (int j = 0; j < 4; ++j) acc[u][j] = 0.f;

#pragma unroll 2
    for (int k4 = 0; k4 < HID; k4 += 4) {
        int cb = (k4 >> 2) ^ sw;
        float4 xv[2], wv4[4];
        xv[0] = hs4[(m0 << 4) + cb];
        xv[1] = hs4[((m0 + 32) << 4) + cb];
#pragma unroll
        for (int kk = 0; kk < 4; ++kk) wv4[kk] = *(float4*)&w[(k4 + kk) * OUT_F + f0];
#pragma unroll
        for (int u = 0; u < 2; ++u) {
            acc[u][0] += xv[u].x * wv4[0].x + xv[u].y * wv4[1].x + xv[u].z * wv4[2].x + xv[u].w * wv4[3].x;
            acc[u][1] += xv[u].x * wv4[0].y + xv[u].y * wv4[1].y + xv[u].z * wv4[2].y + xv[u].w * wv4[3].y;
            acc[u][2] += xv[u].x * wv4[0].z + xv[u].y * wv4[1].z + xv[u].z * wv4[2].z + xv[u].w * wv4[3].z;
            acc[u][3] += xv[u].x * wv4[0].w + xv[u].y * wv4[1].w + xv[u].z * wv4[2].w + xv[u].w * wv4[3].w;
        }
    }

#pragma unroll
    for (int u = 0; u < 2; ++u) {
        int n = base + m0 + 32 * u;
        if (n < N_NODES) {
            float dv = dinv[n];
            ushort4 o;
            o.x = f2bf(acc[u][0] * dv);
            o.y = f2bf(acc[u][1] * dv);
            o.z = f2bf(acc[u][2] * dv);
            o.w = f2bf(acc[u][3] * dv);
            *(ushort4*)&g2b[(size_t)n * OUT_F + f0] = o;
        }
    }
}

// ---------------- layer 2 gather + finalize2 ----------------
// 4 nodes per wave: 16 lanes/node, lane holds 2 features (uint = 2 bf16).

__global__ __launch_bounds__(256) void gather2_kernel(const int* __restrict__ rowptr,
                                                      const int* __restrict__ deg,
                                                      const int* __restrict__ srt,
                                                      const unsigned short* __restrict__ g2b,
                                                      const float* __restrict__ dinv,
                                                      const float* __restrict__ b2,
                                                      float* __restrict__ out) {
    int t = threadIdx.x;
    int n = blockIdx.x * 16 + (t >> 4);   // 16 nodes per block
    int lane16 = t & 15;
    if (n >= N_NODES) return;
    int s = rowptr[n];
    int e = s + deg[n];
    unsigned fo = lane16 << 1;            // feature offset 0..30

    float a0 = 0.f, a1 = 0.f, c0 = 0.f, c1 = 0.f;
    int j = s;
    for (; j + 2 <= e; j += 2) {
        int r0 = srt[j], r1 = srt[j + 1];
        unsigned v0 = *(const unsigned*)&g2b[(unsigned)(r0 << 5) + fo];
        unsigned v1 = *(const unsigned*)&g2b[(unsigned)(r1 << 5) + fo];
        a0 += bflo(v0); a1 += bfhi(v0);
        c0 += bflo(v1); c1 += bfhi(v1);
    }
    if (j < e) {
        unsigned v0 = *(const unsigned*)&g2b[(unsigned)(srt[j] << 5) + fo];
        a0 += bflo(v0); a1 += bfhi(v0);
    }
    unsigned vs = *(const unsigned*)&g2b[(unsigned)(n << 5) + fo];
    a0 += c0 + bflo(vs); a1 += c1 + bfhi(vs);

    float dv = dinv[n];
    float2 o;
    o.x = dv * a0 + b2[fo];
    o.y = dv * a1 + b2[fo + 1];
    *(float2*)&out[(unsigned)(n << 5) + fo] = o;
}

extern "C" void kernel_launch(void* const* d_in, const int* in_sizes, int n_in,
                              void* d_out, int out_size, void* d_ws, size_t ws_size,
                              hipStream_t stream) {
    const float* x   = (const float*)d_in[0];
    const int*   ei  = (const int*)d_in[1];
    const int*   row = ei;             // edge_index[0] = source
    const int*   col = ei + N_EDGES;   // edge_index[1] = target
    const float* W1  = (const float*)d_in[2];
    const float* b1  = (const float*)d_in[3];
    const float* W2  = (const float*)d_in[4];
    const float* b2  = (const float*)d_in[5];
    float* out = (float*)d_out;

    // workspace layout
    char* p = (char*)d_ws;
    float*          dinv = (float*)p;          p += (size_t)N_NODES * 4;        // 0.4 MB
    unsigned short* g1b  = (unsigned short*)p; p += (size_t)N_NODES * HID * 2;  // 12.8 MB
    float*          h    = (float*)p;          p += (size_t)N_NODES * HID * 4;  // 25.6 MB
    unsigned short* g2b  = (unsigned short*)p; p += (size_t)N_NODES * OUT_F * 2;// 6.4 MB
    int*   deg   = (int*)p;   p += (size_t)N_NODES * 4;          // 0.4 MB
    int*   rowp  = (int*)p;   p += (size_t)(N_NODES + 1) * 4;    // 0.4 MB
    int*   gbcnt = (int*)p;   p += ((NBUCK + 63) & ~63) * 4;
    int*   boff  = (int*)p;   p += ((NBUCK + 64) & ~63) * 4;
    int*   gcur  = (int*)p;   p += ((NBUCK + 63) & ~63) * 4;
    int*   srt   = (int*)p;   p += (size_t)N_EDGES * 4;          // 6.4 MB
    int*   tmp   = (int*)p;   p += (size_t)N_EDGES * 4;          // 6.4 MB (packed)

    hipMemsetAsync(gbcnt, 0, NBUCK * sizeof(int), stream);

    bhist_kernel <<<NBLK_A, 256, 0, stream>>>(col, gbcnt);
    bscan_kernel <<<1, 256, 0, stream>>>(gbcnt, boff, gcur);
    binA_kernel  <<<NBLK_A, 256, 0, stream>>>(row, col, gcur, tmp);
    binB2_kernel <<<NBUCK, 512, 0, stream>>>(boff, tmp, srt, rowp, deg, dinv);

    gemm1_tiled  <<<(N_NODES + 63) / 64, 256, 0, stream>>>(x, W1, dinv, g1b);
    gather1_kernel<<<(N_NODES + 15) / 16, 256, 0, stream>>>(rowp, deg, srt, g1b, dinv, b1, h);
    gemm2_tiled  <<<(N_NODES + 63) / 64, 256, 0, stream>>>(h, W2, dinv, g2b);
    gather2_kernel<<<(N_NODES + 15) / 16, 256, 0, stream>>>(rowp, deg, srt, g2b, dinv, b2, out);
}

// Round 14
// 185.048 us; speedup vs baseline: 3.3809x; 1.1035x over previous
//
#include <hip/hip_runtime.h>

#define N_NODES 100000
#define N_EDGES 1600000
#define IN_F 128
#define HID 64
#define OUT_F 32

#define BSHIFT 9
#define BUCK_N (1 << BSHIFT)                               // 512 nodes/bucket
#define NBUCK ((N_NODES + BUCK_N - 1) >> BSHIFT)           // 196
#define EPB 8192
#define NBLK_A ((N_EDGES + EPB - 1) / EPB)                 // 196
#define ROW_MASK 0x1FFFF                                   // 17 bits, N < 131072

// bf16 helpers
__device__ __forceinline__ float bflo(unsigned u) { return __uint_as_float(u << 16); }
__device__ __forceinline__ float bfhi(unsigned u) { return __uint_as_float(u & 0xffff0000u); }
__device__ __forceinline__ unsigned short f2bf(float f) {
    unsigned u = __float_as_uint(f);
    u += 0x7FFF + ((u >> 16) & 1);   // round-to-nearest-even
    return (unsigned short)(u >> 16);
}

// ---------------- bucket histogram (LDS-privatized) ----------------

__global__ __launch_bounds__(256) void bhist_kernel(const int* __restrict__ col,
                                                    int* __restrict__ gbcnt) {
    __shared__ int cnt[NBUCK];
    int t = threadIdx.x;
    int e0 = blockIdx.x * EPB;
    int e1 = e0 + EPB < N_EDGES ? e0 + EPB : N_EDGES;
    for (int i = t; i < NBUCK; i += 256) cnt[i] = 0;
    __syncthreads();
    for (int e = e0 + t; e < e1; e += 256) atomicAdd(&cnt[col[e] >> BSHIFT], 1);
    __syncthreads();
    for (int i = t; i < NBUCK; i += 256)
        if (cnt[i]) atomicAdd(&gbcnt[i], cnt[i]);
}

// ---------------- bucket scan: boff (exclusive) + gcur seed ----------------

__global__ __launch_bounds__(256) void bscan_kernel(const int* __restrict__ gbcnt,
                                                    int* __restrict__ boff,
                                                    int* __restrict__ gcur) {
    __shared__ int s[256];
    int t = threadIdx.x;
    int v = (t < NBUCK) ? gbcnt[t] : 0;
    s[t] = v; __syncthreads();
    for (int off = 1; off < 256; off <<= 1) {
        int x = (t >= off) ? s[t - off] : 0; __syncthreads();
        s[t] += x; __syncthreads();
    }
    if (t < NBUCK) {
        int o = s[t] - v;
        boff[t] = o;
        gcur[t] = o;
    }
    if (t == 0) boff[NBUCK] = N_EDGES;
}

// ---------------- binA: group edges by bucket into tmp (packed) ----------------

__global__ __launch_bounds__(256) void binA_kernel(const int* __restrict__ row,
                                                   const int* __restrict__ col,
                                                   int* __restrict__ gcur,
                                                   int* __restrict__ tmp) {
    __shared__ int cnt[NBUCK], base[NBUCK], lcur[NBUCK];
    int t = threadIdx.x;
    int e0 = blockIdx.x * EPB;
    int e1 = e0 + EPB < N_EDGES ? e0 + EPB : N_EDGES;
    for (int i = t; i < NBUCK; i += 256) cnt[i] = 0;
    __syncthreads();
    for (int e = e0 + t; e < e1; e += 256) atomicAdd(&cnt[col[e] >> BSHIFT], 1);
    __syncthreads();
    for (int i = t; i < NBUCK; i += 256) {
        int c = cnt[i];
        base[i] = c ? atomicAdd(&gcur[i], c) : 0;
        lcur[i] = 0;
    }
    __syncthreads();
    for (int e = e0 + t; e < e1; e += 256) {
        int c = col[e];
        int b = c >> BSHIFT;
        int rk = atomicAdd(&lcur[b], 1);
        tmp[base[b] + rk] = ((c & (BUCK_N - 1)) << 17) | row[e];
    }
}

// ---------------- binB2: per-bucket hist + scan + rowp/deg/dinv + sort -------

__global__ __launch_bounds__(512) void binB2_kernel(const int* __restrict__ boff,
                                                    const int* __restrict__ tmp,
                                                    int* __restrict__ srt,
                                                    int* __restrict__ rowp,
                                                    int* __restrict__ deg,
                                                    float* __restrict__ dinv) {
    __shared__ int cnt[BUCK_N];   // 2 KB: hist -> inclusive scan -> cursors
    int b = blockIdx.x, t = threadIdx.x;
    int nbase = b << BSHIFT;
    int s  = boff[b];
    int e1 = boff[b + 1];

    cnt[t] = 0;
    __syncthreads();
    for (int e = s + t; e < e1; e += 512) atomicAdd(&cnt[tmp[e] >> 17], 1);
    __syncthreads();

    int v = cnt[t];               // this node's degree
    for (int off = 1; off < 512; off <<= 1) {
        int x = (t >= off) ? cnt[t - off] : 0; __syncthreads();
        cnt[t] += x; __syncthreads();
    }
    int rowpos = s + cnt[t] - v;  // global exclusive position
    int n = nbase + t;
    if (n < N_NODES) {
        rowp[n] = rowpos;
        deg[n]  = v;
        dinv[n] = rsqrtf((float)v + 1.0f);  // +1 = self-loop
    }
    __syncthreads();
    cnt[t] = rowpos;              // now cursors
    __syncthreads();
    for (int e = s + t; e < e1; e += 512) {
        int rc = tmp[e];
        int pos = atomicAdd(&cnt[rc >> 17], 1);
        srt[pos] = rc & ROW_MASK;
    }
}

// ---------------- layer 1 dense: g1b = bf16((x @ W1) * dinv) ----------------
// K-split staging: xs = 64n x 64k half-slab (16 KB) -> LDS 48 KB -> 3 blocks/CU.

__global__ __launch_bounds__(256) void gemm1_tiled(const float* __restrict__ x,
                                                   const float* __restrict__ W1,
                                                   const float* __restrict__ dinv,
                                                   unsigned short* __restrict__ g1b) {
    __shared__ float w[IN_F * HID];       // 32 KB, [k][f]
    __shared__ float xs[64 * 64];         // 16 KB half-K slab, swizzled
    float4* xs4 = (float4*)xs;            // row stride 16 float4

    int t = threadIdx.x;
    int base = blockIdx.x * 64;

    for (int i = t; i < IN_F * HID; i += 256) w[i] = W1[i];

    int m0 = t & 15;
    int f0 = (t >> 4) << 2;
    int sw = m0 & 7;

    float acc[4][4];
#pragma unroll
    for (int u = 0; u < 4; ++u)
#pragma unroll
        for (int j = 0; j < 4; ++j) acc[u][j] = 0.f;

    for (int half = 0; half < 2; ++half) {
        __syncthreads();   // also covers w-load before first use
#pragma unroll
        for (int j = 0; j < 4; ++j) {     // 64 rows x 64 k = 4096 floats
            int idx = j * 1024 + t * 4;
            int n = idx >> 6;             // 0..63
            int k = idx & 63;
            float4 v = make_float4(0.f, 0.f, 0.f, 0.f);
            if (base + n < N_NODES)
                v = *(const float4*)&x[(size_t)(base + n) * IN_F + half * 64 + k];
            xs4[(n << 4) + ((k >> 2) ^ (n & 7))] = v;
        }
        __syncthreads();

#pragma unroll 2
        for (int k4 = 0; k4 < 64; k4 += 4) {
            int cb = (k4 >> 2) ^ sw;
            float4 xv[4], wv[4];
#pragma unroll
            for (int u = 0; u < 4; ++u) xv[u] = xs4[((m0 + 16 * u) << 4) + cb];
#pragma unroll
            for (int kk = 0; kk < 4; ++kk)
                wv[kk] = *(float4*)&w[(half * 64 + k4 + kk) * HID + f0];
#pragma unroll
            for (int u = 0; u < 4; ++u) {
                acc[u][0] += xv[u].x * wv[0].x + xv[u].y * wv[1].x + xv[u].z * wv[2].x + xv[u].w * wv[3].x;
                acc[u][1] += xv[u].x * wv[0].y + xv[u].y * wv[1].y + xv[u].z * wv[2].y + xv[u].w * wv[3].y;
                acc[u][2] += xv[u].x * wv[0].z + xv[u].y * wv[1].z + xv[u].z * wv[2].z + xv[u].w * wv[3].z;
                acc[u][3] += xv[u].x * wv[0].w + xv[u].y * wv[1].w + xv[u].z * wv[2].w + xv[u].w * wv[3].w;
            }
        }
    }

#pragma unroll
    for (int u = 0; u < 4; ++u) {
        int n = base + m0 + 16 * u;
        if (n < N_NODES) {
            float dv = dinv[n];
            ushort4 o;
            o.x = f2bf(acc[u][0] * dv);
            o.y = f2bf(acc[u][1] * dv);
            o.z = f2bf(acc[u][2] * dv);
            o.w = f2bf(acc[u][3] * dv);
            *(ushort4*)&g1b[(size_t)n * HID + f0] = o;
        }
    }
}

// ---------------- layer 1 gather + finalize1 ----------------
// 8 nodes per wave: 8 lanes/node, lane holds 8 features (uint4 = 8 bf16).

__global__ __launch_bounds__(256) void gather1_kernel(const int* __restrict__ rowptr,
                                                      const int* __restrict__ deg,
                                                      const int* __restrict__ srt,
                                                      const unsigned short* __restrict__ g1b,
                                                      const float* __restrict__ dinv,
                                                      const float* __restrict__ b1,
                                                      float* __restrict__ h) {
    int t = threadIdx.x;
    int n = blockIdx.x * 32 + (t >> 3);   // 32 nodes per block
    int lane8 = t & 7;
    if (n >= N_NODES) return;
    int s = rowptr[n];
    int e = s + deg[n];
    unsigned fo = lane8 << 3;             // feature offset 0..56 (16B)

    float a0 = 0.f, a1 = 0.f, a2 = 0.f, a3 = 0.f;
    float a4 = 0.f, a5 = 0.f, a6 = 0.f, a7 = 0.f;
    float c0 = 0.f, c1 = 0.f, c2 = 0.f, c3 = 0.f;
    float c4 = 0.f, c5 = 0.f, c6 = 0.f, c7 = 0.f;
    int j = s;
    for (; j + 2 <= e; j += 2) {
        int r0 = srt[j], r1 = srt[j + 1];
        uint4 v0 = *(const uint4*)&g1b[(unsigned)(r0 << 6) + fo];
        uint4 v1 = *(const uint4*)&g1b[(unsigned)(r1 << 6) + fo];
        a0 += bflo(v0.x); a1 += bfhi(v0.x); a2 += bflo(v0.y); a3 += bfhi(v0.y);
        a4 += bflo(v0.z); a5 += bfhi(v0.z); a6 += bflo(v0.w); a7 += bfhi(v0.w);
        c0 += bflo(v1.x); c1 += bfhi(v1.x); c2 += bflo(v1.y); c3 += bfhi(v1.y);
        c4 += bflo(v1.z); c5 += bfhi(v1.z); c6 += bflo(v1.w); c7 += bfhi(v1.w);
    }
    if (j < e) {
        int r0 = srt[j];
        uint4 v0 = *(const uint4*)&g1b[(unsigned)(r0 << 6) + fo];
        a0 += bflo(v0.x); a1 += bfhi(v0.x); a2 += bflo(v0.y); a3 += bfhi(v0.y);
        a4 += bflo(v0.z); a5 += bfhi(v0.z); a6 += bflo(v0.w); a7 += bfhi(v0.w);
    }
    // self-loop
    uint4 vs = *(const uint4*)&g1b[(unsigned)(n << 6) + fo];
    a0 += c0 + bflo(vs.x); a1 += c1 + bfhi(vs.x);
    a2 += c2 + bflo(vs.y); a3 += c3 + bfhi(vs.y);
    a4 += c4 + bflo(vs.z); a5 += c5 + bfhi(vs.z);
    a6 += c6 + bflo(vs.w); a7 += c7 + bfhi(vs.w);

    float dv = dinv[n];
    float4 bb0 = *(const float4*)&b1[fo];
    float4 bb1 = *(const float4*)&b1[fo + 4];
    float4 o0, o1;
    o0.x = dv * a0 + bb0.x; o0.y = dv * a1 + bb0.y;
    o0.z = dv * a2 + bb0.z; o0.w = dv * a3 + bb0.w;
    o1.x = dv * a4 + bb1.x; o1.y = dv * a5 + bb1.y;
    o1.z = dv * a6 + bb1.z; o1.w = dv * a7 + bb1.w;
    o0.x = o0.x > 0.f ? o0.x : 0.f; o0.y = o0.y > 0.f ? o0.y : 0.f;
    o0.z = o0.z > 0.f ? o0.z : 0.f; o0.w = o0.w > 0.f ? o0.w : 0.f;
    o1.x = o1.x > 0.f ? o1.x : 0.f; o1.y = o1.y > 0.f ? o1.y : 0.f;
    o1.z = o1.z > 0.f ? o1.z : 0.f; o1.w = o1.w > 0.f ? o1.w : 0.f;
    *(float4*)&h[(unsigned)(n << 6) + fo] = o0;
    *(float4*)&h[(unsigned)(n << 6) + fo + 4] = o1;
}

// ---------------- layer 2 dense: g2b = bf16((h @ W2) * dinv) ----------------

__global__ __launch_bounds__(256) void gemm2_tiled(const float* __restrict__ h,
                                                   const float* __restrict__ W2,
                                                   const float* __restrict__ dinv,
                                                   unsigned short* __restrict__ g2b) {
    __shared__ float w[HID * OUT_F];      // 8 KB, [k][f]
    __shared__ float hs[64 * HID];        // 16 KB, swizzled
    float4* hs4 = (float4*)hs;            // row stride 16 float4

    int t = threadIdx.x;
    int base = blockIdx.x * 64;

    for (int i = t; i < HID * OUT_F; i += 256) w[i] = W2[i];

#pragma unroll
    for (int j = 0; j < 4; ++j) {         // 64 rows x 64 k = 4096 floats
        int idx = j * 1024 + t * 4;
        int n = idx >> 6;                 // 0..63
        int k = idx & 63;
        float4 v = make_float4(0.f, 0.f, 0.f, 0.f);
        if (base + n < N_NODES) v = *(const float4*)&h[(size_t)(base + n) * HID + k];
        hs4[(n << 4) + ((k >> 2) ^ (n & 7))] = v;
    }
    __syncthreads();

    int m0 = t & 31;
    int f0 = (t >> 5) << 2;
    int sw = m0 & 7;

    float acc[2][4];
#pragma unroll
    for (int u = 0; u < 2; ++u)
#pragma unroll
        for (int j = 0; j < 4; ++j) acc[u][j] = 0.f;

#pragma unroll 2
    for (int k4 = 0; k4 < HID; k4 += 4) {
        int cb = (k4 >> 2) ^ sw;
        float4 xv[2], wv4[4];
        xv[0] = hs4[(m0 << 4) + cb];
        xv[1] = hs4[((m0 + 32) << 4) + cb];
#pragma unroll
        for (int kk = 0; kk < 4; ++kk) wv4[kk] = *(float4*)&w[(k4 + kk) * OUT_F + f0];
#pragma unroll
        for (int u = 0; u < 2; ++u) {
            acc[u][0] += xv[u].x * wv4[0].x + xv[u].y * wv4[1].x + xv[u].z * wv4[2].x + xv[u].w * wv4[3].x;
            acc[u][1] += xv[u].x * wv4[0].y + xv[u].y * wv4[1].y + xv[u].z * wv4[2].y + xv[u].w * wv4[3].y;
            acc[u][2] += xv[u].x * wv4[0].z + xv[u].y * wv4[1].z + xv[u].z * wv4[2].z + xv[u].w * wv4[3].z;
            acc[u][3] += xv[u].x * wv4[0].w + xv[u].y * wv4[1].w + xv[u].z * wv4[2].w + xv[u].w * wv4[3].w;
        }
    }

#pragma unroll
    for (int u = 0; u < 2; ++u) {
        int n = base + m0 + 32 * u;
        if (n < N_NODES) {
            float dv = dinv[n];
            ushort4 o;
            o.x = f2bf(acc[u][0] * dv);
            o.y = f2bf(acc[u][1] * dv);
            o.z = f2bf(acc[u][2] * dv);
            o.w = f2bf(acc[u][3] * dv);
            *(ushort4*)&g2b[(size_t)n * OUT_F + f0] = o;
        }
    }
}

// ---------------- layer 2 gather + finalize2 ----------------
// 8 nodes per wave: 8 lanes/node, lane holds 4 features (uint2 = 4 bf16).

__global__ __launch_bounds__(256) void gather2_kernel(const int* __restrict__ rowptr,
                                                      const int* __restrict__ deg,
                                                      const int* __restrict__ srt,
                                                      const unsigned short* __restrict__ g2b,
                                                      const float* __restrict__ dinv,
                                                      const float* __restrict__ b2,
                                                      float* __restrict__ out) {
    int t = threadIdx.x;
    int n = blockIdx.x * 32 + (t >> 3);   // 32 nodes per block
    int lane8 = t & 7;
    if (n >= N_NODES) return;
    int s = rowptr[n];
    int e = s + deg[n];
    unsigned fo = lane8 << 2;             // feature offset 0..28 (8B)

    float a0 = 0.f, a1 = 0.f, a2 = 0.f, a3 = 0.f;
    float c0 = 0.f, c1 = 0.f, c2 = 0.f, c3 = 0.f;
    int j = s;
    for (; j + 2 <= e; j += 2) {
        int r0 = srt[j], r1 = srt[j + 1];
        uint2 v0 = *(const uint2*)&g2b[(unsigned)(r0 << 5) + fo];
        uint2 v1 = *(const uint2*)&g2b[(unsigned)(r1 << 5) + fo];
        a0 += bflo(v0.x); a1 += bfhi(v0.x); a2 += bflo(v0.y); a3 += bfhi(v0.y);
        c0 += bflo(v1.x); c1 += bfhi(v1.x); c2 += bflo(v1.y); c3 += bfhi(v1.y);
    }
    if (j < e) {
        uint2 v0 = *(const uint2*)&g2b[(unsigned)(srt[j] << 5) + fo];
        a0 += bflo(v0.x); a1 += bfhi(v0.x); a2 += bflo(v0.y); a3 += bfhi(v0.y);
    }
    uint2 vs = *(const uint2*)&g2b[(unsigned)(n << 5) + fo];
    a0 += c0 + bflo(vs.x); a1 += c1 + bfhi(vs.x);
    a2 += c2 + bflo(vs.y); a3 += c3 + bfhi(vs.y);

    float dv = dinv[n];
    float4 bb = *(const float4*)&b2[fo];
    float4 o;
    o.x = dv * a0 + bb.x; o.y = dv * a1 + bb.y;
    o.z = dv * a2 + bb.z; o.w = dv * a3 + bb.w;
    *(float4*)&out[(unsigned)(n << 5) + fo] = o;
}

extern "C" void kernel_launch(void* const* d_in, const int* in_sizes, int n_in,
                              void* d_out, int out_size, void* d_ws, size_t ws_size,
                              hipStream_t stream) {
    const float* x   = (const float*)d_in[0];
    const int*   ei  = (const int*)d_in[1];
    const int*   row = ei;             // edge_index[0] = source
    const int*   col = ei + N_EDGES;   // edge_index[1] = target
    const float* W1  = (const float*)d_in[2];
    const float* b1  = (const float*)d_in[3];
    const float* W2  = (const float*)d_in[4];
    const float* b2  = (const float*)d_in[5];
    float* out = (float*)d_out;

    // workspace layout
    char* p = (char*)d_ws;
    float*          dinv = (float*)p;          p += (size_t)N_NODES * 4;        // 0.4 MB
    unsigned short* g1b  = (unsigned short*)p; p += (size_t)N_NODES * HID * 2;  // 12.8 MB
    float*          h    = (float*)p;          p += (size_t)N_NODES * HID * 4;  // 25.6 MB
    unsigned short* g2b  = (unsigned short*)p; p += (size_t)N_NODES * OUT_F * 2;// 6.4 MB
    int*   deg   = (int*)p;   p += (size_t)N_NODES * 4;          // 0.4 MB
    int*   rowp  = (int*)p;   p += (size_t)(N_NODES + 1) * 4;    // 0.4 MB
    int*   gbcnt = (int*)p;   p += ((NBUCK + 63) & ~63) * 4;
    int*   boff  = (int*)p;   p += ((NBUCK + 64) & ~63) * 4;
    int*   gcur  = (int*)p;   p += ((NBUCK + 63) & ~63) * 4;
    int*   srt   = (int*)p;   p += (size_t)N_EDGES * 4;          // 6.4 MB
    int*   tmp   = (int*)p;   p += (size_t)N_EDGES * 4;          // 6.4 MB (packed)

    hipMemsetAsync(gbcnt, 0, NBUCK * sizeof(int), stream);

    bhist_kernel <<<NBLK_A, 256, 0, stream>>>(col, gbcnt);
    bscan_kernel <<<1, 256, 0, stream>>>(gbcnt, boff, gcur);
    binA_kernel  <<<NBLK_A, 256, 0, stream>>>(row, col, gcur, tmp);
    binB2_kernel <<<NBUCK, 512, 0, stream>>>(boff, tmp, srt, rowp, deg, dinv);

    gemm1_tiled  <<<(N_NODES + 63) / 64, 256, 0, stream>>>(x, W1, dinv, g1b);
    gather1_kernel<<<(N_NODES + 31) / 32, 256, 0, stream>>>(rowp, deg, srt, g1b, dinv, b1, h);
    gemm2_tiled  <<<(N_NODES + 63) / 64, 256, 0, stream>>>(h, W2, dinv, g2b);
    gather2_kernel<<<(N_NODES + 31) / 32, 256, 0, stream>>>(rowp, deg, srt, g2b, dinv, b2, out);
}

// Round 16
// 166.464 us; speedup vs baseline: 3.7584x; 1.1116x over previous
//
#include <hip/hip_runtime.h>

#define N_NODES 100000
#define N_EDGES 1600000
#define IN_F 128
#define HID 64
#define OUT_F 32

#define BSHIFT 9
#define BUCK_N (1 << BSHIFT)                               // 512 nodes/bucket
#define NBUCK ((N_NODES + BUCK_N - 1) >> BSHIFT)           // 196
#define EPB 8192
#define NBLK_A ((N_EDGES + EPB - 1) / EPB)                 // 196
#define ROW_MASK 0x1FFFF                                   // 17 bits, N < 131072

typedef __attribute__((ext_vector_type(8))) short bf16x8;
typedef __attribute__((ext_vector_type(4))) float f32x4;

// bf16 helpers
__device__ __forceinline__ float bflo(unsigned u) { return __uint_as_float(u << 16); }
__device__ __forceinline__ float bfhi(unsigned u) { return __uint_as_float(u & 0xffff0000u); }
__device__ __forceinline__ unsigned short f2bf(float f) {
    unsigned u = __float_as_uint(f);
    u += 0x7FFF + ((u >> 16) & 1);   // round-to-nearest-even
    return (unsigned short)(u >> 16);
}
__device__ __forceinline__ unsigned pack2(float lo, float hi) {
    return (unsigned)f2bf(lo) | ((unsigned)f2bf(hi) << 16);
}

// ---------------- bucket histogram (LDS-privatized) ----------------

__global__ __launch_bounds__(256) void bhist_kernel(const int* __restrict__ col,
                                                    int* __restrict__ gbcnt) {
    __shared__ int cnt[NBUCK];
    int t = threadIdx.x;
    int e0 = blockIdx.x * EPB;
    int e1 = e0 + EPB < N_EDGES ? e0 + EPB : N_EDGES;
    for (int i = t; i < NBUCK; i += 256) cnt[i] = 0;
    __syncthreads();
    for (int e = e0 + t; e < e1; e += 256) atomicAdd(&cnt[col[e] >> BSHIFT], 1);
    __syncthreads();
    for (int i = t; i < NBUCK; i += 256)
        if (cnt[i]) atomicAdd(&gbcnt[i], cnt[i]);
}

// ---------------- bucket scan: boff (exclusive) + gcur seed ----------------

__global__ __launch_bounds__(256) void bscan_kernel(const int* __restrict__ gbcnt,
                                                    int* __restrict__ boff,
                                                    int* __restrict__ gcur) {
    __shared__ int s[256];
    int t = threadIdx.x;
    int v = (t < NBUCK) ? gbcnt[t] : 0;
    s[t] = v; __syncthreads();
    for (int off = 1; off < 256; off <<= 1) {
        int x = (t >= off) ? s[t - off] : 0; __syncthreads();
        s[t] += x; __syncthreads();
    }
    if (t < NBUCK) {
        int o = s[t] - v;
        boff[t] = o;
        gcur[t] = o;
    }
    if (t == 0) boff[NBUCK] = N_EDGES;
}

// ---------------- binA: group edges by bucket into tmp (packed) ----------------

__global__ __launch_bounds__(256) void binA_kernel(const int* __restrict__ row,
                                                   const int* __restrict__ col,
                                                   int* __restrict__ gcur,
                                                   int* __restrict__ tmp) {
    __shared__ int cnt[NBUCK], base[NBUCK], lcur[NBUCK];
    int t = threadIdx.x;
    int e0 = blockIdx.x * EPB;
    int e1 = e0 + EPB < N_EDGES ? e0 + EPB : N_EDGES;
    for (int i = t; i < NBUCK; i += 256) cnt[i] = 0;
    __syncthreads();
    for (int e = e0 + t; e < e1; e += 256) atomicAdd(&cnt[col[e] >> BSHIFT], 1);
    __syncthreads();
    for (int i = t; i < NBUCK; i += 256) {
        int c = cnt[i];
        base[i] = c ? atomicAdd(&gcur[i], c) : 0;
        lcur[i] = 0;
    }
    __syncthreads();
    for (int e = e0 + t; e < e1; e += 256) {
        int c = col[e];
        int b = c >> BSHIFT;
        int rk = atomicAdd(&lcur[b], 1);
        tmp[base[b] + rk] = ((c & (BUCK_N - 1)) << 17) | row[e];
    }
}

// ---------------- binB2: per-bucket hist + scan + rowp/deg/dinv + sort -------

__global__ __launch_bounds__(512) void binB2_kernel(const int* __restrict__ boff,
                                                    const int* __restrict__ tmp,
                                                    int* __restrict__ srt,
                                                    int* __restrict__ rowp,
                                                    int* __restrict__ deg,
                                                    float* __restrict__ dinv) {
    __shared__ int cnt[BUCK_N];   // 2 KB: hist -> inclusive scan -> cursors
    int b = blockIdx.x, t = threadIdx.x;
    int nbase = b << BSHIFT;
    int s  = boff[b];
    int e1 = boff[b + 1];

    cnt[t] = 0;
    __syncthreads();
    for (int e = s + t; e < e1; e += 512) atomicAdd(&cnt[tmp[e] >> 17], 1);
    __syncthreads();

    int v = cnt[t];               // this node's degree
    for (int off = 1; off < 512; off <<= 1) {
        int x = (t >= off) ? cnt[t - off] : 0; __syncthreads();
        cnt[t] += x; __syncthreads();
    }
    int rowpos = s + cnt[t] - v;  // global exclusive position
    int n = nbase + t;
    if (n < N_NODES) {
        rowp[n] = rowpos;
        deg[n]  = v;
        dinv[n] = rsqrtf((float)v + 1.0f);  // +1 = self-loop
    }
    __syncthreads();
    cnt[t] = rowpos;              // now cursors
    __syncthreads();
    for (int e = s + t; e < e1; e += 512) {
        int rc = tmp[e];
        int pos = atomicAdd(&cnt[rc >> 17], 1);
        srt[pos] = rc & ROW_MASK;
    }
}

// ---------------- W1^T -> bf16 (one-time, tiny) ----------------
// wTg[c][k] = bf16(W1[k][c]),  64 x 128 bf16 = 16 KB.

__global__ __launch_bounds__(256) void wcvt_kernel(const float* __restrict__ W1,
                                                   unsigned short* __restrict__ wTg) {
    int i = blockIdx.x * 256 + threadIdx.x;   // 8192
    if (i < IN_F * HID) {
        int k = i >> 6, c = i & 63;
        wTg[c * IN_F + k] = f2bf(W1[i]);
    }
}

// ---------------- layer 1 dense via MFMA: g1b = bf16((x @ W1) * dinv) -------
// Block = 64 nodes, 256 thr (4 waves). LDS: x-tile bf16 [64][128] + W1^T bf16
// [64][128], both XOR-swizzled in 16B chunks (chunk ^ (row&7)).
// Wave w computes rows w*16..w*16+15; 4 col-tiles x 4 K-chunks = 16 MFMA.
// A-frag: row=lane&15, k=kchunk*32+(lane>>4)*8+j (contiguous b128).
// C/D: col=lane&15, row=(lane>>4)*4+reg (m89-verified).

__global__ __launch_bounds__(256) void gemm1_mfma(const float* __restrict__ x,
                                                  const unsigned short* __restrict__ wTg,
                                                  const float* __restrict__ dinv,
                                                  unsigned short* __restrict__ g1b) {
    __shared__ unsigned short xs[64 * IN_F];   // 16 KB
    __shared__ unsigned short wT[64 * IN_F];   // 16 KB

    int t = threadIdx.x;
    int base = blockIdx.x * 64;

    // stage W1^T (bf16, pre-converted): 1024 16B chunks
    {
        const int4* src = (const int4*)wTg;
        int4* dst = (int4*)wT;
#pragma unroll
        for (int j = 0; j < 4; ++j) {
            int c = j * 256 + t;          // chunk id
            int colr = c >> 4, kc = c & 15;
            dst[colr * 16 + (kc ^ (colr & 7))] = src[c];
        }
    }
    // stage x tile -> bf16 swizzled
#pragma unroll
    for (int j = 0; j < 4; ++j) {
        int fidx = j * 2048 + t * 8;
        int r = fidx >> 7;                // 0..63
        int k = fidx & 127;
        float4 v0 = make_float4(0.f, 0.f, 0.f, 0.f), v1 = v0;
        if (base + r < N_NODES) {
            const float* xp = &x[(size_t)(base + r) * IN_F + k];
            v0 = *(const float4*)xp;
            v1 = *(const float4*)(xp + 4);
        }
        int4 pk;
        pk.x = pack2(v0.x, v0.y); pk.y = pack2(v0.z, v0.w);
        pk.z = pack2(v1.x, v1.y); pk.w = pack2(v1.z, v1.w);
        ((int4*)xs)[r * 16 + ((k >> 3) ^ (r & 7))] = pk;
    }
    __syncthreads();

    int l = t & 63;
    int w = t >> 6;
    int lr = l & 15;          // A-row / B-col / D-col component
    int lg = l >> 4;          // k-subgroup

    f32x4 acc[4];
#pragma unroll
    for (int ct = 0; ct < 4; ++ct) acc[ct] = (f32x4){0.f, 0.f, 0.f, 0.f};

#pragma unroll
    for (int kk = 0; kk < 4; ++kk) {
        int chunk = kk * 4 + lg;
        int arow = w * 16 + lr;
        bf16x8 a = *(bf16x8*)&xs[arow * IN_F + ((chunk ^ (arow & 7)) << 3)];
#pragma unroll
        for (int ct = 0; ct < 4; ++ct) {
            int bcol = ct * 16 + lr;
            bf16x8 b = *(bf16x8*)&wT[bcol * IN_F + ((chunk ^ (bcol & 7)) << 3)];
            acc[ct] = __builtin_amdgcn_mfma_f32_16x16x32_bf16(a, b, acc[ct], 0, 0, 0);
        }
    }

    // epilogue: D row = w*16 + lg*4 + i, col = ct*16 + lr
    float dv[4];
    int rbase = base + w * 16 + lg * 4;
#pragma unroll
    for (int i = 0; i < 4; ++i)
        dv[i] = (rbase + i < N_NODES) ? dinv[rbase + i] : 0.f;
#pragma unroll
    for (int i = 0; i < 4; ++i) {
        int n = rbase + i;
        if (n < N_NODES) {
#pragma unroll
            for (int ct = 0; ct < 4; ++ct)
                g1b[(unsigned)(n << 6) + ct * 16 + lr] = f2bf(acc[ct][i] * dv[i]);
        }
    }
}

// ---------------- layer 1 gather + finalize1 ----------------
// 8 nodes per wave: 8 lanes/node, lane holds 8 features (uint4 = 8 bf16).

__global__ __launch_bounds__(256) void gather1_kernel(const int* __restrict__ rowptr,
                                                      const int* __restrict__ deg,
                                                      const int* __restrict__ srt,
                                                      const unsigned short* __restrict__ g1b,
                                                      const float* __restrict__ dinv,
                                                      const float* __restrict__ b1,
                                                      float* __restrict__ h) {
    int t = threadIdx.x;
    int n = blockIdx.x * 32 + (t >> 3);   // 32 nodes per block
    int lane8 = t & 7;
    if (n >= N_NODES) return;
    int s = rowptr[n];
    int e = s + deg[n];
    unsigned fo = lane8 << 3;             // feature offset 0..56 (16B)

    float a0 = 0.f, a1 = 0.f, a2 = 0.f, a3 = 0.f;
    float a4 = 0.f, a5 = 0.f, a6 = 0.f, a7 = 0.f;
    float c0 = 0.f, c1 = 0.f, c2 = 0.f, c3 = 0.f;
    float c4 = 0.f, c5 = 0.f, c6 = 0.f, c7 = 0.f;
    int j = s;
    for (; j + 2 <= e; j += 2) {
        int r0 = srt[j], r1 = srt[j + 1];
        uint4 v0 = *(const uint4*)&g1b[(unsigned)(r0 << 6) + fo];
        uint4 v1 = *(const uint4*)&g1b[(unsigned)(r1 << 6) + fo];
        a0 += bflo(v0.x); a1 += bfhi(v0.x); a2 += bflo(v0.y); a3 += bfhi(v0.y);
        a4 += bflo(v0.z); a5 += bfhi(v0.z); a6 += bflo(v0.w); a7 += bfhi(v0.w);
        c0 += bflo(v1.x); c1 += bfhi(v1.x); c2 += bflo(v1.y); c3 += bfhi(v1.y);
        c4 += bflo(v1.z); c5 += bfhi(v1.z); c6 += bflo(v1.w); c7 += bfhi(v1.w);
    }
    if (j < e) {
        int r0 = srt[j];
        uint4 v0 = *(const uint4*)&g1b[(unsigned)(r0 << 6) + fo];
        a0 += bflo(v0.x); a1 += bfhi(v0.x); a2 += bflo(v0.y); a3 += bfhi(v0.y);
        a4 += bflo(v0.z); a5 += bfhi(v0.z); a6 += bflo(v0.w); a7 += bfhi(v0.w);
    }
    // self-loop
    uint4 vs = *(const uint4*)&g1b[(unsigned)(n << 6) + fo];
    a0 += c0 + bflo(vs.x); a1 += c1 + bfhi(vs.x);
    a2 += c2 + bflo(vs.y); a3 += c3 + bfhi(vs.y);
    a4 += c4 + bflo(vs.z); a5 += c5 + bfhi(vs.z);
    a6 += c6 + bflo(vs.w); a7 += c7 + bfhi(vs.w);

    float dv = dinv[n];
    float4 bb0 = *(const float4*)&b1[fo];
    float4 bb1 = *(const float4*)&b1[fo + 4];
    float4 o0, o1;
    o0.x = dv * a0 + bb0.x; o0.y = dv * a1 + bb0.y;
    o0.z = dv * a2 + bb0.z; o0.w = dv * a3 + bb0.w;
    o1.x = dv * a4 + bb1.x; o1.y = dv * a5 + bb1.y;
    o1.z = dv * a6 + bb1.z; o1.w = dv * a7 + bb1.w;
    o0.x = o0.x > 0.f ? o0.x : 0.f; o0.y = o0.y > 0.f ? o0.y : 0.f;
    o0.z = o0.z > 0.f ? o0.z : 0.f; o0.w = o0.w > 0.f ? o0.w : 0.f;
    o1.x = o1.x > 0.f ? o1.x : 0.f; o1.y = o1.y > 0.f ? o1.y : 0.f;
    o1.z = o1.z > 0.f ? o1.z : 0.f; o1.w = o1.w > 0.f ? o1.w : 0.f;
    *(float4*)&h[(unsigned)(n << 6) + fo] = o0;
    *(float4*)&h[(unsigned)(n << 6) + fo + 4] = o1;
}

// ---------------- layer 2 dense: g2b = bf16((h @ W2) * dinv) ----------------

__global__ __launch_bounds__(256) void gemm2_tiled(const float* __restrict__ h,
                                                   const float* __restrict__ W2,
                                                   const float* __restrict__ dinv,
                                                   unsigned short* __restrict__ g2b) {
    __shared__ float w[HID * OUT_F];      // 8 KB, [k][f]
    __shared__ float hs[64 * HID];        // 16 KB, swizzled
    float4* hs4 = (float4*)hs;            // row stride 16 float4

    int t = threadIdx.x;
    int base = blockIdx.x * 64;

    for (int i = t; i < HID * OUT_F; i += 256) w[i] = W2[i];

#pragma unroll
    for (int j = 0; j < 4; ++j) {         // 64 rows x 64 k = 4096 floats
        int idx = j * 1024 + t * 4;
        int n = idx >> 6;                 // 0..63
        int k = idx & 63;
        float4 v = make_float4(0.f, 0.f, 0.f, 0.f);
        if (base + n < N_NODES) v = *(const float4*)&h[(size_t)(base + n) * HID + k];
        hs4[(n << 4) + ((k >> 2) ^ (n & 7))] = v;
    }
    __syncthreads();

    int m0 = t & 31;
    int f0 = (t >> 5) << 2;
    int sw = m0 & 7;

    float acc[2][4];
#pragma unroll
    for (int u = 0; u < 2; ++u)
#pragma unroll
        for (int j = 0; j < 4; ++j) acc[u][j] = 0.f;

#pragma unroll 2
    for (int k4 = 0; k4 < HID; k4 += 4) {
        int cb = (k4 >> 2) ^ sw;
        float4 xv[2], wv4[4];
        xv[0] = hs4[(m0 << 4) + cb];
        xv[1] = hs4[((m0 + 32) << 4) + cb];
#pragma unroll
        for (int kk = 0; kk < 4; ++kk) wv4[kk] = *(float4*)&w[(k4 + kk) * OUT_F + f0];
#pragma unroll
        for (int u = 0; u < 2; ++u) {
            acc[u][0] += xv[u].x * wv4[0].x + xv[u].y * wv4[1].x + xv[u].z * wv4[2].x + xv[u].w * wv4[3].x;
            acc[u][1] += xv[u].x * wv4[0].y + xv[u].y * wv4[1].y + xv[u].z * wv4[2].y + xv[u].w * wv4[3].y;
            acc[u][2] += xv[u].x * wv4[0].z + xv[u].y * wv4[1].z + xv[u].z * wv4[2].z + xv[u].w * wv4[3].z;
            acc[u][3] += xv[u].x * wv4[0].w + xv[u].y * wv4[1].w + xv[u].z * wv4[2].w + xv[u].w * wv4[3].w;
        }
    }

#pragma unroll
    for (int u = 0; u < 2; ++u) {
        int n = base + m0 + 32 * u;
        if (n < N_NODES) {
            float dv = dinv[n];
            ushort4 o;
            o.x = f2bf(acc[u][0] * dv);
            o.y = f2bf(acc[u][1] * dv);
            o.z = f2bf(acc[u][2] * dv);
            o.w = f2bf(acc[u][3] * dv);
            *(ushort4*)&g2b[(size_t)n * OUT_F + f0] = o;
        }
    }
}

// ---------------- layer 2 gather + finalize2 ----------------
// 8 nodes per wave: 8 lanes/node, lane holds 4 features (uint2 = 4 bf16).

__global__ __launch_bounds__(256) void gather2_kernel(const int* __restrict__ rowptr,
                                                      const int* __restrict__ deg,
                                                      const int* __restrict__ srt,
                                                      const unsigned short* __restrict__ g2b,
                                                      const float* __restrict__ dinv,
                                                      const float* __restrict__ b2,
                                                      float* __restrict__ out) {
    int t = threadIdx.x;
    int n = blockIdx.x * 32 + (t >> 3);   // 32 nodes per block
    int lane8 = t & 7;
    if (n >= N_NODES) return;
    int s = rowptr[n];
    int e = s + deg[n];
    unsigned fo = lane8 << 2;             // feature offset 0..28 (8B)

    float a0 = 0.f, a1 = 0.f, a2 = 0.f, a3 = 0.f;
    float c0 = 0.f, c1 = 0.f, c2 = 0.f, c3 = 0.f;
    int j = s;
    for (; j + 2 <= e; j += 2) {
        int r0 = srt[j], r1 = srt[j + 1];
        uint2 v0 = *(const uint2*)&g2b[(unsigned)(r0 << 5) + fo];
        uint2 v1 = *(const uint2*)&g2b[(unsigned)(r1 << 5) + fo];
        a0 += bflo(v0.x); a1 += bfhi(v0.x); a2 += bflo(v0.y); a3 += bfhi(v0.y);
        c0 += bflo(v1.x); c1 += bfhi(v1.x); c2 += bflo(v1.y); c3 += bfhi(v1.y);
    }
    if (j < e) {
        uint2 v0 = *(const uint2*)&g2b[(unsigned)(srt[j] << 5) + fo];
        a0 += bflo(v0.x); a1 += bfhi(v0.x); a2 += bflo(v0.y); a3 += bfhi(v0.y);
    }
    uint2 vs = *(const uint2*)&g2b[(unsigned)(n << 5) + fo];
    a0 += c0 + bflo(vs.x); a1 += c1 + bfhi(vs.x);
    a2 += c2 + bflo(vs.y); a3 += c3 + bfhi(vs.y);

    float dv = dinv[n];
    float4 bb = *(const float4*)&b2[fo];
    float4 o;
    o.x = dv * a0 + bb.x; o.y = dv * a1 + bb.y;
    o.z = dv * a2 + bb.z; o.w = dv * a3 + bb.w;
    *(float4*)&out[(unsigned)(n << 5) + fo] = o;
}

extern "C" void kernel_launch(void* const* d_in, const int* in_sizes, int n_in,
                              void* d_out, int out_size, void* d_ws, size_t ws_size,
                              hipStream_t stream) {
    const float* x   = (const float*)d_in[0];
    const int*   ei  = (const int*)d_in[1];
    const int*   row = ei;             // edge_index[0] = source
    const int*   col = ei + N_EDGES;   // edge_index[1] = target
    const float* W1  = (const float*)d_in[2];
    const float* b1  = (const float*)d_in[3];
    const float* W2  = (const float*)d_in[4];
    const float* b2  = (const float*)d_in[5];
    float* out = (float*)d_out;

    // workspace layout
    char* p = (char*)d_ws;
    float*          dinv = (float*)p;          p += (size_t)N_NODES * 4;        // 0.4 MB
    unsigned short* g1b  = (unsigned short*)p; p += (size_t)N_NODES * HID * 2;  // 12.8 MB
    float*          h    = (float*)p;          p += (size_t)N_NODES * HID * 4;  // 25.6 MB
    unsigned short* g2b  = (unsigned short*)p; p += (size_t)N_NODES * OUT_F * 2;// 6.4 MB
    int*   deg   = (int*)p;   p += (size_t)N_NODES * 4;          // 0.4 MB
    int*   rowp  = (int*)p;   p += (size_t)(N_NODES + 1) * 4;    // 0.4 MB
    int*   gbcnt = (int*)p;   p += ((NBUCK + 63) & ~63) * 4;
    int*   boff  = (int*)p;   p += ((NBUCK + 64) & ~63) * 4;
    int*   gcur  = (int*)p;   p += ((NBUCK + 63) & ~63) * 4;
    unsigned short* wTg = (unsigned short*)p; p += (size_t)IN_F * HID * 2;   // 16 KB
    int*   srt   = (int*)p;   p += (size_t)N_EDGES * 4;          // 6.4 MB
    int*   tmp   = (int*)p;   p += (size_t)N_EDGES * 4;          // 6.4 MB (packed)

    hipMemsetAsync(gbcnt, 0, NBUCK * sizeof(int), stream);

    wcvt_kernel  <<<(IN_F * HID + 255) / 256, 256, 0, stream>>>(W1, wTg);
    bhist_kernel <<<NBLK_A, 256, 0, stream>>>(col, gbcnt);
    bscan_kernel <<<1, 256, 0, stream>>>(gbcnt, boff, gcur);
    binA_kernel  <<<NBLK_A, 256, 0, stream>>>(row, col, gcur, tmp);
    binB2_kernel <<<NBUCK, 512, 0, stream>>>(boff, tmp, srt, rowp, deg, dinv);

    gemm1_mfma   <<<(N_NODES + 63) / 64, 256, 0, stream>>>(x, wTg, dinv, g1b);
    gather1_kernel<<<(N_NODES + 31) / 32, 256, 0, stream>>>(rowp, deg, srt, g1b, dinv, b1, h);
    gemm2_tiled  <<<(N_NODES + 63) / 64, 256, 0, stream>>>(h, W2, dinv, g2b);
    gather2_kernel<<<(N_NODES + 31) / 32, 256, 0, stream>>>(rowp, deg, srt, g2b, dinv, b2, out);
}

// Round 17
// 166.373 us; speedup vs baseline: 3.7604x; 1.0005x over previous
//
#include <hip/hip_runtime.h>

#define N_NODES 100000
#define N_EDGES 1600000
#define IN_F 128
#define HID 64
#define OUT_F 32

#define BSHIFT 9
#define BUCK_N (1 << BSHIFT)                               // 512 nodes/bucket
#define NBUCK ((N_NODES + BUCK_N - 1) >> BSHIFT)           // 196
#define EPB_H 4096
#define NBLK_H ((N_EDGES + EPB_H - 1) / EPB_H)             // 391
#define EPB_A 2048
#define NBLK_A ((N_EDGES + EPB_A - 1) / EPB_A)             // 782
#define ROW_MASK 0x1FFFF                                   // 17 bits, N < 131072

typedef __attribute__((ext_vector_type(8))) short bf16x8;
typedef __attribute__((ext_vector_type(4))) float f32x4;

// bf16 helpers
__device__ __forceinline__ float bflo(unsigned u) { return __uint_as_float(u << 16); }
__device__ __forceinline__ float bfhi(unsigned u) { return __uint_as_float(u & 0xffff0000u); }
__device__ __forceinline__ unsigned short f2bf(float f) {
    unsigned u = __float_as_uint(f);
    u += 0x7FFF + ((u >> 16) & 1);   // round-to-nearest-even
    return (unsigned short)(u >> 16);
}
__device__ __forceinline__ unsigned pack2(float lo, float hi) {
    return (unsigned)f2bf(lo) | ((unsigned)f2bf(hi) << 16);
}

// ---------------- W1^T -> bf16 + gbcnt zero (one-time, tiny) ----------------

__global__ __launch_bounds__(256) void wcvt_kernel(const float* __restrict__ W1,
                                                   unsigned short* __restrict__ wTg,
                                                   int* __restrict__ gbcnt) {
    int i = blockIdx.x * 256 + threadIdx.x;   // 8192
    if (i < IN_F * HID) {
        int k = i >> 6, c = i & 63;
        wTg[c * IN_F + k] = f2bf(W1[i]);
    }
    if (i < NBUCK) gbcnt[i] = 0;
}

// ---------------- bucket histogram (LDS-privatized) ----------------

__global__ __launch_bounds__(256) void bhist_kernel(const int* __restrict__ col,
                                                    int* __restrict__ gbcnt) {
    __shared__ int cnt[NBUCK];
    int t = threadIdx.x;
    int e0 = blockIdx.x * EPB_H;
    int e1 = e0 + EPB_H < N_EDGES ? e0 + EPB_H : N_EDGES;
    for (int i = t; i < NBUCK; i += 256) cnt[i] = 0;
    __syncthreads();
    for (int e = e0 + t; e < e1; e += 256) atomicAdd(&cnt[col[e] >> BSHIFT], 1);
    __syncthreads();
    for (int i = t; i < NBUCK; i += 256)
        if (cnt[i]) atomicAdd(&gbcnt[i], cnt[i]);
}

// ---------------- bucket scan: boff (exclusive) + gcur seed ----------------

__global__ __launch_bounds__(256) void bscan_kernel(const int* __restrict__ gbcnt,
                                                    int* __restrict__ boff,
                                                    int* __restrict__ gcur) {
    __shared__ int s[256];
    int t = threadIdx.x;
    int v = (t < NBUCK) ? gbcnt[t] : 0;
    s[t] = v; __syncthreads();
    for (int off = 1; off < 256; off <<= 1) {
        int x = (t >= off) ? s[t - off] : 0; __syncthreads();
        s[t] += x; __syncthreads();
    }
    if (t < NBUCK) {
        int o = s[t] - v;
        boff[t] = o;
        gcur[t] = o;
    }
    if (t == 0) boff[NBUCK] = N_EDGES;
}

// ---------------- binA: group edges by bucket into tmp (packed) ----------------

__global__ __launch_bounds__(256) void binA_kernel(const int* __restrict__ row,
                                                   const int* __restrict__ col,
                                                   int* __restrict__ gcur,
                                                   int* __restrict__ tmp) {
    __shared__ int cnt[NBUCK], base[NBUCK], lcur[NBUCK];
    int t = threadIdx.x;
    int e0 = blockIdx.x * EPB_A;
    int e1 = e0 + EPB_A < N_EDGES ? e0 + EPB_A : N_EDGES;
    for (int i = t; i < NBUCK; i += 256) cnt[i] = 0;
    __syncthreads();
    for (int e = e0 + t; e < e1; e += 256) atomicAdd(&cnt[col[e] >> BSHIFT], 1);
    __syncthreads();
    for (int i = t; i < NBUCK; i += 256) {
        int c = cnt[i];
        base[i] = c ? atomicAdd(&gcur[i], c) : 0;
        lcur[i] = 0;
    }
    __syncthreads();
    for (int e = e0 + t; e < e1; e += 256) {
        int c = col[e];
        int b = c >> BSHIFT;
        int rk = atomicAdd(&lcur[b], 1);
        tmp[base[b] + rk] = ((c & (BUCK_N - 1)) << 17) | row[e];
    }
}

// ---------------- binB2: per-bucket hist + scan + rowp/deg/dinv + sort -------

__global__ __launch_bounds__(512) void binB2_kernel(const int* __restrict__ boff,
                                                    const int* __restrict__ tmp,
                                                    int* __restrict__ srt,
                                                    int* __restrict__ rowp,
                                                    int* __restrict__ deg,
                                                    float* __restrict__ dinv) {
    __shared__ int cnt[BUCK_N];   // 2 KB: hist -> inclusive scan -> cursors
    int b = blockIdx.x, t = threadIdx.x;
    int nbase = b << BSHIFT;
    int s  = boff[b];
    int e1 = boff[b + 1];

    cnt[t] = 0;
    __syncthreads();
    for (int e = s + t; e < e1; e += 512) atomicAdd(&cnt[tmp[e] >> 17], 1);
    __syncthreads();

    int v = cnt[t];               // this node's degree
    for (int off = 1; off < 512; off <<= 1) {
        int x = (t >= off) ? cnt[t - off] : 0; __syncthreads();
        cnt[t] += x; __syncthreads();
    }
    int rowpos = s + cnt[t] - v;  // global exclusive position
    int n = nbase + t;
    if (n < N_NODES) {
        rowp[n] = rowpos;
        deg[n]  = v;
        dinv[n] = rsqrtf((float)v + 1.0f);  // +1 = self-loop
    }
    __syncthreads();
    cnt[t] = rowpos;              // now cursors
    __syncthreads();
    for (int e = s + t; e < e1; e += 512) {
        int rc = tmp[e];
        int pos = atomicAdd(&cnt[rc >> 17], 1);
        srt[pos] = rc & ROW_MASK;
    }
}

// ---------------- layer 1 dense via MFMA: g1b = bf16((x @ W1) * dinv) -------
// Block = 64 nodes, 256 thr (4 waves). LDS: x-tile bf16 [64][128] + W1^T bf16
// [64][128], both XOR-swizzled in 16B chunks (chunk ^ (row&7)).

__global__ __launch_bounds__(256) void gemm1_mfma(const float* __restrict__ x,
                                                  const unsigned short* __restrict__ wTg,
                                                  const float* __restrict__ dinv,
                                                  unsigned short* __restrict__ g1b) {
    __shared__ unsigned short xs[64 * IN_F];   // 16 KB
    __shared__ unsigned short wT[64 * IN_F];   // 16 KB

    int t = threadIdx.x;
    int base = blockIdx.x * 64;

    // stage W1^T (bf16, pre-converted): 1024 16B chunks
    {
        const int4* src = (const int4*)wTg;
        int4* dst = (int4*)wT;
#pragma unroll
        for (int j = 0; j < 4; ++j) {
            int c = j * 256 + t;          // chunk id
            int colr = c >> 4, kc = c & 15;
            dst[colr * 16 + (kc ^ (colr & 7))] = src[c];
        }
    }
    // stage x tile -> bf16 swizzled
#pragma unroll
    for (int j = 0; j < 4; ++j) {
        int fidx = j * 2048 + t * 8;
        int r = fidx >> 7;                // 0..63
        int k = fidx & 127;
        float4 v0 = make_float4(0.f, 0.f, 0.f, 0.f), v1 = v0;
        if (base + r < N_NODES) {
            const float* xp = &x[(size_t)(base + r) * IN_F + k];
            v0 = *(const float4*)xp;
            v1 = *(const float4*)(xp + 4);
        }
        int4 pk;
        pk.x = pack2(v0.x, v0.y); pk.y = pack2(v0.z, v0.w);
        pk.z = pack2(v1.x, v1.y); pk.w = pack2(v1.z, v1.w);
        ((int4*)xs)[r * 16 + ((k >> 3) ^ (r & 7))] = pk;
    }
    __syncthreads();

    int l = t & 63;
    int w = t >> 6;
    int lr = l & 15;          // A-row / B-col / D-col component
    int lg = l >> 4;          // k-subgroup

    f32x4 acc[4];
#pragma unroll
    for (int ct = 0; ct < 4; ++ct) acc[ct] = (f32x4){0.f, 0.f, 0.f, 0.f};

#pragma unroll
    for (int kk = 0; kk < 4; ++kk) {
        int chunk = kk * 4 + lg;
        int arow = w * 16 + lr;
        bf16x8 a = *(bf16x8*)&xs[arow * IN_F + ((chunk ^ (arow & 7)) << 3)];
#pragma unroll
        for (int ct = 0; ct < 4; ++ct) {
            int bcol = ct * 16 + lr;
            bf16x8 b = *(bf16x8*)&wT[bcol * IN_F + ((chunk ^ (bcol & 7)) << 3)];
            acc[ct] = __builtin_amdgcn_mfma_f32_16x16x32_bf16(a, b, acc[ct], 0, 0, 0);
        }
    }

    // epilogue: D row = w*16 + lg*4 + i, col = ct*16 + lr
    float dv[4];
    int rbase = base + w * 16 + lg * 4;
#pragma unroll
    for (int i = 0; i < 4; ++i)
        dv[i] = (rbase + i < N_NODES) ? dinv[rbase + i] : 0.f;
#pragma unroll
    for (int i = 0; i < 4; ++i) {
        int n = rbase + i;
        if (n < N_NODES) {
#pragma unroll
            for (int ct = 0; ct < 4; ++ct)
                g1b[(unsigned)(n << 6) + ct * 16 + lr] = f2bf(acc[ct][i] * dv[i]);
        }
    }
}

// ---------------- layer 1 gather + finalize1 ----------------
// 8 nodes per wave: 8 lanes/node, lane holds 8 features (uint4 = 8 bf16).

__global__ __launch_bounds__(256) void gather1_kernel(const int* __restrict__ rowptr,
                                                      const int* __restrict__ deg,
                                                      const int* __restrict__ srt,
                                                      const unsigned short* __restrict__ g1b,
                                                      const float* __restrict__ dinv,
                                                      const float* __restrict__ b1,
                                                      float* __restrict__ h) {
    int t = threadIdx.x;
    int n = blockIdx.x * 32 + (t >> 3);   // 32 nodes per block
    int lane8 = t & 7;
    if (n >= N_NODES) return;
    int s = rowptr[n];
    int e = s + deg[n];
    unsigned fo = lane8 << 3;             // feature offset 0..56 (16B)

    float a0 = 0.f, a1 = 0.f, a2 = 0.f, a3 = 0.f;
    float a4 = 0.f, a5 = 0.f, a6 = 0.f, a7 = 0.f;
    float c0 = 0.f, c1 = 0.f, c2 = 0.f, c3 = 0.f;
    float c4 = 0.f, c5 = 0.f, c6 = 0.f, c7 = 0.f;
    int j = s;
    for (; j + 2 <= e; j += 2) {
        int r0 = srt[j], r1 = srt[j + 1];
        uint4 v0 = *(const uint4*)&g1b[(unsigned)(r0 << 6) + fo];
        uint4 v1 = *(const uint4*)&g1b[(unsigned)(r1 << 6) + fo];
        a0 += bflo(v0.x); a1 += bfhi(v0.x); a2 += bflo(v0.y); a3 += bfhi(v0.y);
        a4 += bflo(v0.z); a5 += bfhi(v0.z); a6 += bflo(v0.w); a7 += bfhi(v0.w);
        c0 += bflo(v1.x); c1 += bfhi(v1.x); c2 += bflo(v1.y); c3 += bfhi(v1.y);
        c4 += bflo(v1.z); c5 += bfhi(v1.z); c6 += bflo(v1.w); c7 += bfhi(v1.w);
    }
    if (j < e) {
        int r0 = srt[j];
        uint4 v0 = *(const uint4*)&g1b[(unsigned)(r0 << 6) + fo];
        a0 += bflo(v0.x); a1 += bfhi(v0.x); a2 += bflo(v0.y); a3 += bfhi(v0.y);
        a4 += bflo(v0.z); a5 += bfhi(v0.z); a6 += bflo(v0.w); a7 += bfhi(v0.w);
    }
    // self-loop
    uint4 vs = *(const uint4*)&g1b[(unsigned)(n << 6) + fo];
    a0 += c0 + bflo(vs.x); a1 += c1 + bfhi(vs.x);
    a2 += c2 + bflo(vs.y); a3 += c3 + bfhi(vs.y);
    a4 += c4 + bflo(vs.z); a5 += c5 + bfhi(vs.z);
    a6 += c6 + bflo(vs.w); a7 += c7 + bfhi(vs.w);

    float dv = dinv[n];
    float4 bb0 = *(const float4*)&b1[fo];
    float4 bb1 = *(const float4*)&b1[fo + 4];
    float4 o0, o1;
    o0.x = dv * a0 + bb0.x; o0.y = dv * a1 + bb0.y;
    o0.z = dv * a2 + bb0.z; o0.w = dv * a3 + bb0.w;
    o1.x = dv * a4 + bb1.x; o1.y = dv * a5 + bb1.y;
    o1.z = dv * a6 + bb1.z; o1.w = dv * a7 + bb1.w;
    o0.x = o0.x > 0.f ? o0.x : 0.f; o0.y = o0.y > 0.f ? o0.y : 0.f;
    o0.z = o0.z > 0.f ? o0.z : 0.f; o0.w = o0.w > 0.f ? o0.w : 0.f;
    o1.x = o1.x > 0.f ? o1.x : 0.f; o1.y = o1.y > 0.f ? o1.y : 0.f;
    o1.z = o1.z > 0.f ? o1.z : 0.f; o1.w = o1.w > 0.f ? o1.w : 0.f;
    *(float4*)&h[(unsigned)(n << 6) + fo] = o0;
    *(float4*)&h[(unsigned)(n << 6) + fo + 4] = o1;
}

// ---------------- layer 2 dense: g2b = bf16((h @ W2) * dinv) ----------------

__global__ __launch_bounds__(256) void gemm2_tiled(const float* __restrict__ h,
                                                   const float* __restrict__ W2,
                                                   const float* __restrict__ dinv,
                                                   unsigned short* __restrict__ g2b) {
    __shared__ float w[HID * OUT_F];      // 8 KB, [k][f]
    __shared__ float hs[64 * HID];        // 16 KB, swizzled
    float4* hs4 = (float4*)hs;            // row stride 16 float4

    int t = threadIdx.x;
    int base = blockIdx.x * 64;

    for (int i = t; i < HID * OUT_F; i += 256) w[i] = W2[i];

#pragma unroll
    for (int j = 0; j < 4; ++j) {         // 64 rows x 64 k = 4096 floats
        int idx = j * 1024 + t * 4;
        int n = idx >> 6;                 // 0..63
        int k = idx & 63;
        float4 v = make_float4(0.f, 0.f, 0.f, 0.f);
        if (base + n < N_NODES) v = *(const float4*)&h[(size_t)(base + n) * HID + k];
        hs4[(n << 4) + ((k >> 2) ^ (n & 7))] = v;
    }
    __syncthreads();

    int m0 = t & 31;
    int f0 = (t >> 5) << 2;
    int sw = m0 & 7;

    float acc[2][4];
#pragma unroll
    for (int u = 0; u < 2; ++u)
#pragma unroll
        for (int j = 0; j < 4; ++j) acc[u][j] = 0.f;

#pragma unroll 2
    for (int k4 = 0; k4 < HID; k4 += 4) {
        int cb = (k4 >> 2) ^ sw;
        float4 xv[2], wv4[4];
        xv[0] = hs4[(m0 << 4) + cb];
        xv[1] = hs4[((m0 + 32) << 4) + cb];
#pragma unroll
        for (int kk = 0; kk < 4; ++kk) wv4[kk] = *(float4*)&w[(k4 + kk) * OUT_F + f0];
#pragma unroll
        for (int u = 0; u < 2; ++u) {
            acc[u][0] += xv[u].x * wv4[0].x + xv[u].y * wv4[1].x + xv[u].z * wv4[2].x + xv[u].w * wv4[3].x;
            acc[u][1] += xv[u].x * wv4[0].y + xv[u].y * wv4[1].y + xv[u].z * wv4[2].y + xv[u].w * wv4[3].y;
            acc[u][2] += xv[u].x * wv4[0].z + xv[u].y * wv4[1].z + xv[u].z * wv4[2].z + xv[u].w * wv4[3].z;
            acc[u][3] += xv[u].x * wv4[0].w + xv[u].y * wv4[1].w + xv[u].z * wv4[2].w + xv[u].w * wv4[3].w;
        }
    }

#pragma unroll
    for (int u = 0; u < 2; ++u) {
        int n = base + m0 + 32 * u;
        if (n < N_NODES) {
            float dv = dinv[n];
            ushort4 o;
            o.x = f2bf(acc[u][0] * dv);
            o.y = f2bf(acc[u][1] * dv);
            o.z = f2bf(acc[u][2] * dv);
            o.w = f2bf(acc[u][3] * dv);
            *(ushort4*)&g2b[(size_t)n * OUT_F + f0] = o;
        }
    }
}

// ---------------- layer 2 gather + finalize2 ----------------
// 8 nodes per wave: 8 lanes/node, lane holds 4 features (uint2 = 4 bf16).

__global__ __launch_bounds__(256) void gather2_kernel(const int* __restrict__ rowptr,
                                                      const int* __restrict__ deg,
                                                      const int* __restrict__ srt,
                                                      const unsigned short* __restrict__ g2b,
                                                      const float* __restrict__ dinv,
                                                      const float* __restrict__ b2,
                                                      float* __restrict__ out) {
    int t = threadIdx.x;
    int n = blockIdx.x * 32 + (t >> 3);   // 32 nodes per block
    int lane8 = t & 7;
    if (n >= N_NODES) return;
    int s = rowptr[n];
    int e = s + deg[n];
    unsigned fo = lane8 << 2;             // feature offset 0..28 (8B)

    float a0 = 0.f, a1 = 0.f, a2 = 0.f, a3 = 0.f;
    float c0 = 0.f, c1 = 0.f, c2 = 0.f, c3 = 0.f;
    int j = s;
    for (; j + 2 <= e; j += 2) {
        int r0 = srt[j], r1 = srt[j + 1];
        uint2 v0 = *(const uint2*)&g2b[(unsigned)(r0 << 5) + fo];
        uint2 v1 = *(const uint2*)&g2b[(unsigned)(r1 << 5) + fo];
        a0 += bflo(v0.x); a1 += bfhi(v0.x); a2 += bflo(v0.y); a3 += bfhi(v0.y);
        c0 += bflo(v1.x); c1 += bfhi(v1.x); c2 += bflo(v1.y); c3 += bfhi(v1.y);
    }
    if (j < e) {
        uint2 v0 = *(const uint2*)&g2b[(unsigned)(srt[j] << 5) + fo];
        a0 += bflo(v0.x); a1 += bfhi(v0.x); a2 += bflo(v0.y); a3 += bfhi(v0.y);
    }
    uint2 vs = *(const uint2*)&g2b[(unsigned)(n << 5) + fo];
    a0 += c0 + bflo(vs.x); a1 += c1 + bfhi(vs.x);
    a2 += c2 + bflo(vs.y); a3 += c3 + bfhi(vs.y);

    float dv = dinv[n];
    float4 bb = *(const float4*)&b2[fo];
    float4 o;
    o.x = dv * a0 + bb.x; o.y = dv * a1 + bb.y;
    o.z = dv * a2 + bb.z; o.w = dv * a3 + bb.w;
    *(float4*)&out[(unsigned)(n << 5) + fo] = o;
}

extern "C" void kernel_launch(void* const* d_in, const int* in_sizes, int n_in,
                              void* d_out, int out_size, void* d_ws, size_t ws_size,
                              hipStream_t stream) {
    const float* x   = (const float*)d_in[0];
    const int*   ei  = (const int*)d_in[1];
    const int*   row = ei;             // edge_index[0] = source
    const int*   col = ei + N_EDGES;   // edge_index[1] = target
    const float* W1  = (const float*)d_in[2];
    const float* b1  = (const float*)d_in[3];
    const float* W2  = (const float*)d_in[4];
    const float* b2  = (const float*)d_in[5];
    float* out = (float*)d_out;

    // workspace layout
    char* p = (char*)d_ws;
    float*          dinv = (float*)p;          p += (size_t)N_NODES * 4;        // 0.4 MB
    unsigned short* g1b  = (unsigned short*)p; p += (size_t)N_NODES * HID * 2;  // 12.8 MB
    float*          h    = (float*)p;          p += (size_t)N_NODES * HID * 4;  // 25.6 MB
    unsigned short* g2b  = (unsigned short*)p; p += (size_t)N_NODES * OUT_F * 2;// 6.4 MB
    int*   deg   = (int*)p;   p += (size_t)N_NODES * 4;          // 0.4 MB
    int*   rowp  = (int*)p;   p += (size_t)(N_NODES + 1) * 4;    // 0.4 MB
    int*   gbcnt = (int*)p;   p += ((NBUCK + 63) & ~63) * 4;
    int*   boff  = (int*)p;   p += ((NBUCK + 64) & ~63) * 4;
    int*   gcur  = (int*)p;   p += ((NBUCK + 63) & ~63) * 4;
    unsigned short* wTg = (unsigned short*)p; p += (size_t)IN_F * HID * 2;   // 16 KB
    int*   srt   = (int*)p;   p += (size_t)N_EDGES * 4;          // 6.4 MB
    int*   tmp   = (int*)p;   p += (size_t)N_EDGES * 4;          // 6.4 MB (packed)

    wcvt_kernel  <<<(IN_F * HID + 255) / 256, 256, 0, stream>>>(W1, wTg, gbcnt);
    bhist_kernel <<<NBLK_H, 256, 0, stream>>>(col, gbcnt);
    bscan_kernel <<<1, 256, 0, stream>>>(gbcnt, boff, gcur);
    binA_kernel  <<<NBLK_A, 256, 0, stream>>>(row, col, gcur, tmp);
    binB2_kernel <<<NBUCK, 512, 0, stream>>>(boff, tmp, srt, rowp, deg, dinv);

    gemm1_mfma   <<<(N_NODES + 63) / 64, 256, 0, stream>>>(x, wTg, dinv, g1b);
    gather1_kernel<<<(N_NODES + 31) / 32, 256, 0, stream>>>(rowp, deg, srt, g1b, dinv, b1, h);
    gemm2_tiled  <<<(N_NODES + 63) / 64, 256, 0, stream>>>(h, W2, dinv, g2b);
    gather2_kernel<<<(N_NODES + 31) / 32, 256, 0, stream>>>(rowp, deg, srt, g2b, dinv, b2, out);
}

// Round 18
// 140.397 us; speedup vs baseline: 4.4562x; 1.1850x over previous
//
#include <hip/hip_runtime.h>

#define N_NODES 100000
#define N_EDGES 1600000
#define IN_F 128
#define HID 64
#define OUT_F 32

#define BSHIFT 9
#define BUCK_N (1 << BSHIFT)                               // 512 nodes/bucket
#define NBUCK ((N_NODES + BUCK_N - 1) >> BSHIFT)           // 196
#define EPB_A 2048
#define NBLK_A ((N_EDGES + EPB_A - 1) / EPB_A)             // 782
#define ROW_MASK 0x1FFFF                                   // 17 bits, N < 131072

typedef __attribute__((ext_vector_type(8))) short bf16x8;
typedef __attribute__((ext_vector_type(4))) float f32x4;

// bf16 helpers
__device__ __forceinline__ float bflo(unsigned u) { return __uint_as_float(u << 16); }
__device__ __forceinline__ float bfhi(unsigned u) { return __uint_as_float(u & 0xffff0000u); }
__device__ __forceinline__ unsigned short f2bf(float f) {
    unsigned u = __float_as_uint(f);
    u += 0x7FFF + ((u >> 16) & 1);   // round-to-nearest-even
    return (unsigned short)(u >> 16);
}
__device__ __forceinline__ unsigned pack2(float lo, float hi) {
    return (unsigned)f2bf(lo) | ((unsigned)f2bf(hi) << 16);
}

// ---------------- W1^T -> bf16 (one-time, tiny) ----------------

__global__ __launch_bounds__(256) void wcvt_kernel(const float* __restrict__ W1,
                                                   unsigned short* __restrict__ wTg) {
    int i = blockIdx.x * 256 + threadIdx.x;   // 8192
    if (i < IN_F * HID) {
        int k = i >> 6, c = i & 63;
        wTg[c * IN_F + k] = f2bf(W1[i]);
    }
}

// ---------------- A1: per-block bucket hist -> M[bucket][blk] (no atomics) --

__global__ __launch_bounds__(256) void histA_kernel(const int* __restrict__ col,
                                                    int* __restrict__ M) {
    __shared__ int cnt[NBUCK];
    int t = threadIdx.x;
    int e0 = blockIdx.x * EPB_A;
    int e1 = e0 + EPB_A < N_EDGES ? e0 + EPB_A : N_EDGES;
    for (int i = t; i < NBUCK; i += 256) cnt[i] = 0;
    __syncthreads();
    for (int e = e0 + t; e < e1; e += 256) atomicAdd(&cnt[col[e] >> BSHIFT], 1);
    __syncthreads();
    for (int i = t; i < NBUCK; i += 256) M[i * NBLK_A + blockIdx.x] = cnt[i];
}

// ---------------- A2a: in-place exclusive scan of each bucket row ----------
// 196 blocks x 256 threads; each thread handles 4 consecutive entries.

__global__ __launch_bounds__(256) void scanA_kernel(int* __restrict__ M,
                                                    int* __restrict__ tot) {
    __shared__ int s[256];
    int b = blockIdx.x, t = threadIdx.x;
    int* rowM = M + (size_t)b * NBLK_A;
    int v[4]; int sum = 0;
#pragma unroll
    for (int j = 0; j < 4; ++j) {
        int idx = t * 4 + j;
        v[j] = (idx < NBLK_A) ? rowM[idx] : 0;
        sum += v[j];
    }
    s[t] = sum; __syncthreads();
    for (int off = 1; off < 256; off <<= 1) {
        int x = (t >= off) ? s[t - off] : 0; __syncthreads();
        s[t] += x; __syncthreads();
    }
    int run = s[t] - sum;   // exclusive prefix for this thread's chunk
#pragma unroll
    for (int j = 0; j < 4; ++j) {
        int idx = t * 4 + j;
        if (idx < NBLK_A) { int c = v[j]; rowM[idx] = run; run += c; }
    }
    if (t == 255) tot[b] = run;   // bucket total
}

// ---------------- A2b: scan bucket totals -> boff ----------------

__global__ __launch_bounds__(256) void bscan_kernel(const int* __restrict__ tot,
                                                    int* __restrict__ boff) {
    __shared__ int s[256];
    int t = threadIdx.x;
    int v = (t < NBUCK) ? tot[t] : 0;
    s[t] = v; __syncthreads();
    for (int off = 1; off < 256; off <<= 1) {
        int x = (t >= off) ? s[t - off] : 0; __syncthreads();
        s[t] += x; __syncthreads();
    }
    if (t < NBUCK) boff[t] = s[t] - v;
    if (t == 0) boff[NBUCK] = N_EDGES;
}

// ---------------- A3: scatter with precomputed bases (no global atomics) ----

__global__ __launch_bounds__(256) void scatA_kernel(const int* __restrict__ row,
                                                    const int* __restrict__ col,
                                                    const int* __restrict__ M,
                                                    const int* __restrict__ boff,
                                                    int* __restrict__ tmp) {
    __shared__ int base[NBUCK], lcur[NBUCK];
    int t = threadIdx.x;
    int e0 = blockIdx.x * EPB_A;
    int e1 = e0 + EPB_A < N_EDGES ? e0 + EPB_A : N_EDGES;
    for (int i = t; i < NBUCK; i += 256) {
        base[i] = boff[i] + M[i * NBLK_A + blockIdx.x];
        lcur[i] = 0;
    }
    __syncthreads();
    for (int e = e0 + t; e < e1; e += 256) {
        int c = col[e];
        int b = c >> BSHIFT;
        int rk = atomicAdd(&lcur[b], 1);
        tmp[base[b] + rk] = ((c & (BUCK_N - 1)) << 17) | row[e];
    }
}

// ---------------- binB2: per-bucket hist + scan + rowp/deg/dinv + sort -------

__global__ __launch_bounds__(512) void binB2_kernel(const int* __restrict__ boff,
                                                    const int* __restrict__ tmp,
                                                    int* __restrict__ srt,
                                                    int* __restrict__ rowp,
                                                    int* __restrict__ deg,
                                                    float* __restrict__ dinv) {
    __shared__ int cnt[BUCK_N];   // 2 KB: hist -> inclusive scan -> cursors
    int b = blockIdx.x, t = threadIdx.x;
    int nbase = b << BSHIFT;
    int s  = boff[b];
    int e1 = boff[b + 1];

    cnt[t] = 0;
    __syncthreads();
    for (int e = s + t; e < e1; e += 512) atomicAdd(&cnt[tmp[e] >> 17], 1);
    __syncthreads();

    int v = cnt[t];               // this node's degree
    for (int off = 1; off < 512; off <<= 1) {
        int x = (t >= off) ? cnt[t - off] : 0; __syncthreads();
        cnt[t] += x; __syncthreads();
    }
    int rowpos = s + cnt[t] - v;  // global exclusive position
    int n = nbase + t;
    if (n < N_NODES) {
        rowp[n] = rowpos;
        deg[n]  = v;
        dinv[n] = rsqrtf((float)v + 1.0f);  // +1 = self-loop
    }
    __syncthreads();
    cnt[t] = rowpos;              // now cursors
    __syncthreads();
    for (int e = s + t; e < e1; e += 512) {
        int rc = tmp[e];
        int pos = atomicAdd(&cnt[rc >> 17], 1);
        srt[pos] = rc & ROW_MASK;
    }
}

// ---------------- layer 1 dense via MFMA: g1b = bf16((x @ W1) * dinv) -------

__global__ __launch_bounds__(256) void gemm1_mfma(const float* __restrict__ x,
                                                  const unsigned short* __restrict__ wTg,
                                                  const float* __restrict__ dinv,
                                                  unsigned short* __restrict__ g1b) {
    __shared__ unsigned short xs[64 * IN_F];   // 16 KB
    __shared__ unsigned short wT[64 * IN_F];   // 16 KB

    int t = threadIdx.x;
    int base = blockIdx.x * 64;

    // stage W1^T (bf16, pre-converted): 1024 16B chunks
    {
        const int4* src = (const int4*)wTg;
        int4* dst = (int4*)wT;
#pragma unroll
        for (int j = 0; j < 4; ++j) {
            int c = j * 256 + t;          // chunk id
            int colr = c >> 4, kc = c & 15;
            dst[colr * 16 + (kc ^ (colr & 7))] = src[c];
        }
    }
    // stage x tile -> bf16 swizzled
#pragma unroll
    for (int j = 0; j < 4; ++j) {
        int fidx = j * 2048 + t * 8;
        int r = fidx >> 7;                // 0..63
        int k = fidx & 127;
        float4 v0 = make_float4(0.f, 0.f, 0.f, 0.f), v1 = v0;
        if (base + r < N_NODES) {
            const float* xp = &x[(size_t)(base + r) * IN_F + k];
            v0 = *(const float4*)xp;
            v1 = *(const float4*)(xp + 4);
        }
        int4 pk;
        pk.x = pack2(v0.x, v0.y); pk.y = pack2(v0.z, v0.w);
        pk.z = pack2(v1.x, v1.y); pk.w = pack2(v1.z, v1.w);
        ((int4*)xs)[r * 16 + ((k >> 3) ^ (r & 7))] = pk;
    }
    __syncthreads();

    int l = t & 63;
    int w = t >> 6;
    int lr = l & 15;          // A-row / B-col / D-col component
    int lg = l >> 4;          // k-subgroup

    f32x4 acc[4];
#pragma unroll
    for (int ct = 0; ct < 4; ++ct) acc[ct] = (f32x4){0.f, 0.f, 0.f, 0.f};

#pragma unroll
    for (int kk = 0; kk < 4; ++kk) {
        int chunk = kk * 4 + lg;
        int arow = w * 16 + lr;
        bf16x8 a = *(bf16x8*)&xs[arow * IN_F + ((chunk ^ (arow & 7)) << 3)];
#pragma unroll
        for (int ct = 0; ct < 4; ++ct) {
            int bcol = ct * 16 + lr;
            bf16x8 b = *(bf16x8*)&wT[bcol * IN_F + ((chunk ^ (bcol & 7)) << 3)];
            acc[ct] = __builtin_amdgcn_mfma_f32_16x16x32_bf16(a, b, acc[ct], 0, 0, 0);
        }
    }

    // epilogue: D row = w*16 + lg*4 + i, col = ct*16 + lr
    float dv[4];
    int rbase = base + w * 16 + lg * 4;
#pragma unroll
    for (int i = 0; i < 4; ++i)
        dv[i] = (rbase + i < N_NODES) ? dinv[rbase + i] : 0.f;
#pragma unroll
    for (int i = 0; i < 4; ++i) {
        int n = rbase + i;
        if (n < N_NODES) {
#pragma unroll
            for (int ct = 0; ct < 4; ++ct)
                g1b[(unsigned)(n << 6) + ct * 16 + lr] = f2bf(acc[ct][i] * dv[i]);
        }
    }
}

// ---------------- layer 1 gather + finalize1 ----------------
// 8 nodes per wave: 8 lanes/node, lane holds 8 features (uint4 = 8 bf16).

__global__ __launch_bounds__(256) void gather1_kernel(const int* __restrict__ rowptr,
                                                      const int* __restrict__ deg,
                                                      const int* __restrict__ srt,
                                                      const unsigned short* __restrict__ g1b,
                                                      const float* __restrict__ dinv,
                                                      const float* __restrict__ b1,
                                                      float* __restrict__ h) {
    int t = threadIdx.x;
    int n = blockIdx.x * 32 + (t >> 3);   // 32 nodes per block
    int lane8 = t & 7;
    if (n >= N_NODES) return;
    int s = rowptr[n];
    int e = s + deg[n];
    unsigned fo = lane8 << 3;             // feature offset 0..56 (16B)

    float a0 = 0.f, a1 = 0.f, a2 = 0.f, a3 = 0.f;
    float a4 = 0.f, a5 = 0.f, a6 = 0.f, a7 = 0.f;
    float c0 = 0.f, c1 = 0.f, c2 = 0.f, c3 = 0.f;
    float c4 = 0.f, c5 = 0.f, c6 = 0.f, c7 = 0.f;
    int j = s;
    for (; j + 2 <= e; j += 2) {
        int r0 = srt[j], r1 = srt[j + 1];
        uint4 v0 = *(const uint4*)&g1b[(unsigned)(r0 << 6) + fo];
        uint4 v1 = *(const uint4*)&g1b[(unsigned)(r1 << 6) + fo];
        a0 += bflo(v0.x); a1 += bfhi(v0.x); a2 += bflo(v0.y); a3 += bfhi(v0.y);
        a4 += bflo(v0.z); a5 += bfhi(v0.z); a6 += bflo(v0.w); a7 += bfhi(v0.w);
        c0 += bflo(v1.x); c1 += bfhi(v1.x); c2 += bflo(v1.y); c3 += bfhi(v1.y);
        c4 += bflo(v1.z); c5 += bfhi(v1.z); c6 += bflo(v1.w); c7 += bfhi(v1.w);
    }
    if (j < e) {
        int r0 = srt[j];
        uint4 v0 = *(const uint4*)&g1b[(unsigned)(r0 << 6) + fo];
        a0 += bflo(v0.x); a1 += bfhi(v0.x); a2 += bflo(v0.y); a3 += bfhi(v0.y);
        a4 += bflo(v0.z); a5 += bfhi(v0.z); a6 += bflo(v0.w); a7 += bfhi(v0.w);
    }
    // self-loop
    uint4 vs = *(const uint4*)&g1b[(unsigned)(n << 6) + fo];
    a0 += c0 + bflo(vs.x); a1 += c1 + bfhi(vs.x);
    a2 += c2 + bflo(vs.y); a3 += c3 + bfhi(vs.y);
    a4 += c4 + bflo(vs.z); a5 += c5 + bfhi(vs.z);
    a6 += c6 + bflo(vs.w); a7 += c7 + bfhi(vs.w);

    float dv = dinv[n];
    float4 bb0 = *(const float4*)&b1[fo];
    float4 bb1 = *(const float4*)&b1[fo + 4];
    float4 o0, o1;
    o0.x = dv * a0 + bb0.x; o0.y = dv * a1 + bb0.y;
    o0.z = dv * a2 + bb0.z; o0.w = dv * a3 + bb0.w;
    o1.x = dv * a4 + bb1.x; o1.y = dv * a5 + bb1.y;
    o1.z = dv * a6 + bb1.z; o1.w = dv * a7 + bb1.w;
    o0.x = o0.x > 0.f ? o0.x : 0.f; o0.y = o0.y > 0.f ? o0.y : 0.f;
    o0.z = o0.z > 0.f ? o0.z : 0.f; o0.w = o0.w > 0.f ? o0.w : 0.f;
    o1.x = o1.x > 0.f ? o1.x : 0.f; o1.y = o1.y > 0.f ? o1.y : 0.f;
    o1.z = o1.z > 0.f ? o1.z : 0.f; o1.w = o1.w > 0.f ? o1.w : 0.f;
    *(float4*)&h[(unsigned)(n << 6) + fo] = o0;
    *(float4*)&h[(unsigned)(n << 6) + fo + 4] = o1;
}

// ---------------- layer 2 dense: g2b = bf16((h @ W2) * dinv) ----------------

__global__ __launch_bounds__(256) void gemm2_tiled(const float* __restrict__ h,
                                                   const float* __restrict__ W2,
                                                   const float* __restrict__ dinv,
                                                   unsigned short* __restrict__ g2b) {
    __shared__ float w[HID * OUT_F];      // 8 KB, [k][f]
    __shared__ float hs[64 * HID];        // 16 KB, swizzled
    float4* hs4 = (float4*)hs;            // row stride 16 float4

    int t = threadIdx.x;
    int base = blockIdx.x * 64;

    for (int i = t; i < HID * OUT_F; i += 256) w[i] = W2[i];

#pragma unroll
    for (int j = 0; j < 4; ++j) {         // 64 rows x 64 k = 4096 floats
        int idx = j * 1024 + t * 4;
        int n = idx >> 6;                 // 0..63
        int k = idx & 63;
        float4 v = make_float4(0.f, 0.f, 0.f, 0.f);
        if (base + n < N_NODES) v = *(const float4*)&h[(size_t)(base + n) * HID + k];
        hs4[(n << 4) + ((k >> 2) ^ (n & 7))] = v;
    }
    __syncthreads();

    int m0 = t & 31;
    int f0 = (t >> 5) << 2;
    int sw = m0 & 7;

    float acc[2][4];
#pragma unroll
    for (int u = 0; u < 2; ++u)
#pragma unroll
        for (int j = 0; j < 4; ++j) acc[u][j] = 0.f;

#pragma unroll 2
    for (int k4 = 0; k4 < HID; k4 += 4) {
        int cb = (k4 >> 2) ^ sw;
        float4 xv[2], wv4[4];
        xv[0] = hs4[(m0 << 4) + cb];
        xv[1] = hs4[((m0 + 32) << 4) + cb];
#pragma unroll
        for (int kk = 0; kk < 4; ++kk) wv4[kk] = *(float4*)&w[(k4 + kk) * OUT_F + f0];
#pragma unroll
        for (int u = 0; u < 2; ++u) {
            acc[u][0] += xv[u].x * wv4[0].x + xv[u].y * wv4[1].x + xv[u].z * wv4[2].x + xv[u].w * wv4[3].x;
            acc[u][1] += xv[u].x * wv4[0].y + xv[u].y * wv4[1].y + xv[u].z * wv4[2].y + xv[u].w * wv4[3].y;
            acc[u][2] += xv[u].x * wv4[0].z + xv[u].y * wv4[1].z + xv[u].z * wv4[2].z + xv[u].w * wv4[3].z;
            acc[u][3] += xv[u].x * wv4[0].w + xv[u].y * wv4[1].w + xv[u].z * wv4[2].w + xv[u].w * wv4[3].w;
        }
    }

#pragma unroll
    for (int u = 0; u < 2; ++u) {
        int n = base + m0 + 32 * u;
        if (n < N_NODES) {
            float dv = dinv[n];
            ushort4 o;
            o.x = f2bf(acc[u][0] * dv);
            o.y = f2bf(acc[u][1] * dv);
            o.z = f2bf(acc[u][2] * dv);
            o.w = f2bf(acc[u][3] * dv);
            *(ushort4*)&g2b[(size_t)n * OUT_F + f0] = o;
        }
    }
}

// ---------------- layer 2 gather + finalize2 ----------------
// 8 nodes per wave: 8 lanes/node, lane holds 4 features (uint2 = 4 bf16).

__global__ __launch_bounds__(256) void gather2_kernel(const int* __restrict__ rowptr,
                                                      const int* __restrict__ deg,
                                                      const int* __restrict__ srt,
                                                      const unsigned short* __restrict__ g2b,
                                                      const float* __restrict__ dinv,
                                                      const float* __restrict__ b2,
                                                      float* __restrict__ out) {
    int t = threadIdx.x;
    int n = blockIdx.x * 32 + (t >> 3);   // 32 nodes per block
    int lane8 = t & 7;
    if (n >= N_NODES) return;
    int s = rowptr[n];
    int e = s + deg[n];
    unsigned fo = lane8 << 2;             // feature offset 0..28 (8B)

    float a0 = 0.f, a1 = 0.f, a2 = 0.f, a3 = 0.f;
    float c0 = 0.f, c1 = 0.f, c2 = 0.f, c3 = 0.f;
    int j = s;
    for (; j + 2 <= e; j += 2) {
        int r0 = srt[j], r1 = srt[j + 1];
        uint2 v0 = *(const uint2*)&g2b[(unsigned)(r0 << 5) + fo];
        uint2 v1 = *(const uint2*)&g2b[(unsigned)(r1 << 5) + fo];
        a0 += bflo(v0.x); a1 += bfhi(v0.x); a2 += bflo(v0.y); a3 += bfhi(v0.y);
        c0 += bflo(v1.x); c1 += bfhi(v1.x); c2 += bflo(v1.y); c3 += bfhi(v1.y);
    }
    if (j < e) {
        uint2 v0 = *(const uint2*)&g2b[(unsigned)(srt[j] << 5) + fo];
        a0 += bflo(v0.x); a1 += bfhi(v0.x); a2 += bflo(v0.y); a3 += bfhi(v0.y);
    }
    uint2 vs = *(const uint2*)&g2b[(unsigned)(n << 5) + fo];
    a0 += c0 + bflo(vs.x); a1 += c1 + bfhi(vs.x);
    a2 += c2 + bflo(vs.y); a3 += c3 + bfhi(vs.y);

    float dv = dinv[n];
    float4 bb = *(const float4*)&b2[fo];
    float4 o;
    o.x = dv * a0 + bb.x; o.y = dv * a1 + bb.y;
    o.z = dv * a2 + bb.z; o.w = dv * a3 + bb.w;
    *(float4*)&out[(unsigned)(n << 5) + fo] = o;
}

extern "C" void kernel_launch(void* const* d_in, const int* in_sizes, int n_in,
                              void* d_out, int out_size, void* d_ws, size_t ws_size,
                              hipStream_t stream) {
    const float* x   = (const float*)d_in[0];
    const int*   ei  = (const int*)d_in[1];
    const int*   row = ei;             // edge_index[0] = source
    const int*   col = ei + N_EDGES;   // edge_index[1] = target
    const float* W1  = (const float*)d_in[2];
    const float* b1  = (const float*)d_in[3];
    const float* W2  = (const float*)d_in[4];
    const float* b2  = (const float*)d_in[5];
    float* out = (float*)d_out;

    // workspace layout
    char* p = (char*)d_ws;
    float*          dinv = (float*)p;          p += (size_t)N_NODES * 4;        // 0.4 MB
    unsigned short* g1b  = (unsigned short*)p; p += (size_t)N_NODES * HID * 2;  // 12.8 MB
    float*          h    = (float*)p;          p += (size_t)N_NODES * HID * 4;  // 25.6 MB
    unsigned short* g2b  = (unsigned short*)p; p += (size_t)N_NODES * OUT_F * 2;// 6.4 MB
    int*   deg   = (int*)p;   p += (size_t)N_NODES * 4;          // 0.4 MB
    int*   rowp  = (int*)p;   p += (size_t)(N_NODES + 1) * 4;    // 0.4 MB
    int*   tot   = (int*)p;   p += ((NBUCK + 63) & ~63) * 4;
    int*   boff  = (int*)p;   p += ((NBUCK + 64) & ~63) * 4;
    unsigned short* wTg = (unsigned short*)p; p += (size_t)IN_F * HID * 2;   // 16 KB
    int*   M     = (int*)p;   p += (size_t)NBUCK * NBLK_A * 4;   // 0.61 MB
    int*   srt   = (int*)p;   p += (size_t)N_EDGES * 4;          // 6.4 MB
    int*   tmp   = (int*)p;   p += (size_t)N_EDGES * 4;          // 6.4 MB (packed)

    wcvt_kernel  <<<(IN_F * HID + 255) / 256, 256, 0, stream>>>(W1, wTg);
    histA_kernel <<<NBLK_A, 256, 0, stream>>>(col, M);
    scanA_kernel <<<NBUCK, 256, 0, stream>>>(M, tot);
    bscan_kernel <<<1, 256, 0, stream>>>(tot, boff);
    scatA_kernel <<<NBLK_A, 256, 0, stream>>>(row, col, M, boff, tmp);
    binB2_kernel <<<NBUCK, 512, 0, stream>>>(boff, tmp, srt, rowp, deg, dinv);

    gemm1_mfma   <<<(N_NODES + 63) / 64, 256, 0, stream>>>(x, wTg, dinv, g1b);
    gather1_kernel<<<(N_NODES + 31) / 32, 256, 0, stream>>>(rowp, deg, srt, g1b, dinv, b1, h);
    gemm2_tiled  <<<(N_NODES + 63) / 64, 256, 0, stream>>>(h, W2, dinv, g2b);
    gather2_kernel<<<(N_NODES + 31) / 32, 256, 0, stream>>>(rowp, deg, srt, g2b, dinv, b2, out);
}

// Round 19
// 128.889 us; speedup vs baseline: 4.8541x; 1.0893x over previous
//
#include <hip/hip_runtime.h>

#define N_NODES 100000
#define N_EDGES 1600000
#define IN_F 128
#define HID 64
#define OUT_F 32

#define BSHIFT 9
#define BUCK_N (1 << BSHIFT)                               // 512 nodes/bucket
#define NBUCK ((N_NODES + BUCK_N - 1) >> BSHIFT)           // 196
#define EPB_A 2048
#define NBLK_A ((N_EDGES + EPB_A - 1) / EPB_A)             // 782
#define ROW_MASK 0x1FFFF                                   // 17 bits, N < 131072

typedef __attribute__((ext_vector_type(8))) short bf16x8;
typedef __attribute__((ext_vector_type(4))) float f32x4;

// bf16 helpers
__device__ __forceinline__ float bflo(unsigned u) { return __uint_as_float(u << 16); }
__device__ __forceinline__ float bfhi(unsigned u) { return __uint_as_float(u & 0xffff0000u); }
__device__ __forceinline__ unsigned short f2bf(float f) {
    unsigned u = __float_as_uint(f);
    u += 0x7FFF + ((u >> 16) & 1);   // round-to-nearest-even
    return (unsigned short)(u >> 16);
}
__device__ __forceinline__ unsigned pack2(float lo, float hi) {
    return (unsigned)f2bf(lo) | ((unsigned)f2bf(hi) << 16);
}

// ---------------- W1^T, W2^T -> bf16 (one-time, tiny) ----------------

__global__ __launch_bounds__(256) void wcvt_kernel(const float* __restrict__ W1,
                                                   const float* __restrict__ W2,
                                                   unsigned short* __restrict__ wTg,
                                                   unsigned short* __restrict__ wTg2) {
    int i = blockIdx.x * 256 + threadIdx.x;   // 8192
    if (i < IN_F * HID) {
        int k = i >> 6, c = i & 63;
        wTg[c * IN_F + k] = f2bf(W1[i]);
    }
    if (i < HID * OUT_F) {
        int k = i >> 5, c = i & 31;
        wTg2[c * HID + k] = f2bf(W2[i]);
    }
}

// ---------------- A1: per-block bucket hist -> M[bucket][blk] (no atomics) --

__global__ __launch_bounds__(256) void histA_kernel(const int* __restrict__ col,
                                                    int* __restrict__ M) {
    __shared__ int cnt[NBUCK];
    int t = threadIdx.x;
    int e0 = blockIdx.x * EPB_A;
    int e1 = e0 + EPB_A < N_EDGES ? e0 + EPB_A : N_EDGES;
    for (int i = t; i < NBUCK; i += 256) cnt[i] = 0;
    __syncthreads();
    for (int e = e0 + t; e < e1; e += 256) atomicAdd(&cnt[col[e] >> BSHIFT], 1);
    __syncthreads();
    for (int i = t; i < NBUCK; i += 256) M[i * NBLK_A + blockIdx.x] = cnt[i];
}

// ---------------- A2a: in-place exclusive scan of each bucket row ----------

__global__ __launch_bounds__(256) void scanA_kernel(int* __restrict__ M,
                                                    int* __restrict__ tot) {
    __shared__ int s[256];
    int b = blockIdx.x, t = threadIdx.x;
    int* rowM = M + (size_t)b * NBLK_A;
    int v[4]; int sum = 0;
#pragma unroll
    for (int j = 0; j < 4; ++j) {
        int idx = t * 4 + j;
        v[j] = (idx < NBLK_A) ? rowM[idx] : 0;
        sum += v[j];
    }
    s[t] = sum; __syncthreads();
    for (int off = 1; off < 256; off <<= 1) {
        int x = (t >= off) ? s[t - off] : 0; __syncthreads();
        s[t] += x; __syncthreads();
    }
    int run = s[t] - sum;   // exclusive prefix for this thread's chunk
#pragma unroll
    for (int j = 0; j < 4; ++j) {
        int idx = t * 4 + j;
        if (idx < NBLK_A) { int c = v[j]; rowM[idx] = run; run += c; }
    }
    if (t == 255) tot[b] = run;   // bucket total
}

// ---------------- A2b: scan bucket totals -> boff ----------------

__global__ __launch_bounds__(256) void bscan_kernel(const int* __restrict__ tot,
                                                    int* __restrict__ boff) {
    __shared__ int s[256];
    int t = threadIdx.x;
    int v = (t < NBUCK) ? tot[t] : 0;
    s[t] = v; __syncthreads();
    for (int off = 1; off < 256; off <<= 1) {
        int x = (t >= off) ? s[t - off] : 0; __syncthreads();
        s[t] += x; __syncthreads();
    }
    if (t < NBUCK) boff[t] = s[t] - v;
    if (t == 0) boff[NBUCK] = N_EDGES;
}

// ---------------- A3: scatter with precomputed bases (no global atomics) ----

__global__ __launch_bounds__(256) void scatA_kernel(const int* __restrict__ row,
                                                    const int* __restrict__ col,
                                                    const int* __restrict__ M,
                                                    const int* __restrict__ boff,
                                                    int* __restrict__ tmp) {
    __shared__ int base[NBUCK], lcur[NBUCK];
    int t = threadIdx.x;
    int e0 = blockIdx.x * EPB_A;
    int e1 = e0 + EPB_A < N_EDGES ? e0 + EPB_A : N_EDGES;
    for (int i = t; i < NBUCK; i += 256) {
        base[i] = boff[i] + M[i * NBLK_A + blockIdx.x];
        lcur[i] = 0;
    }
    __syncthreads();
    for (int e = e0 + t; e < e1; e += 256) {
        int c = col[e];
        int b = c >> BSHIFT;
        int rk = atomicAdd(&lcur[b], 1);
        tmp[base[b] + rk] = ((c & (BUCK_N - 1)) << 17) | row[e];
    }
}

// ---------------- binB2: per-bucket hist + scan + rowp/deg/dinv + sort -------

__global__ __launch_bounds__(512) void binB2_kernel(const int* __restrict__ boff,
                                                    const int* __restrict__ tmp,
                                                    int* __restrict__ srt,
                                                    int* __restrict__ rowp,
                                                    int* __restrict__ deg,
                                                    float* __restrict__ dinv) {
    __shared__ int cnt[BUCK_N];   // 2 KB: hist -> inclusive scan -> cursors
    int b = blockIdx.x, t = threadIdx.x;
    int nbase = b << BSHIFT;
    int s  = boff[b];
    int e1 = boff[b + 1];

    cnt[t] = 0;
    __syncthreads();
    for (int e = s + t; e < e1; e += 512) atomicAdd(&cnt[tmp[e] >> 17], 1);
    __syncthreads();

    int v = cnt[t];               // this node's degree
    for (int off = 1; off < 512; off <<= 1) {
        int x = (t >= off) ? cnt[t - off] : 0; __syncthreads();
        cnt[t] += x; __syncthreads();
    }
    int rowpos = s + cnt[t] - v;  // global exclusive position
    int n = nbase + t;
    if (n < N_NODES) {
        rowp[n] = rowpos;
        deg[n]  = v;
        dinv[n] = rsqrtf((float)v + 1.0f);  // +1 = self-loop
    }
    __syncthreads();
    cnt[t] = rowpos;              // now cursors
    __syncthreads();
    for (int e = s + t; e < e1; e += 512) {
        int rc = tmp[e];
        int pos = atomicAdd(&cnt[rc >> 17], 1);
        srt[pos] = rc & ROW_MASK;
    }
}

// ---------------- layer 1 dense via MFMA: g1b = bf16((x @ W1) * dinv) -------

__global__ __launch_bounds__(256) void gemm1_mfma(const float* __restrict__ x,
                                                  const unsigned short* __restrict__ wTg,
                                                  const float* __restrict__ dinv,
                                                  unsigned short* __restrict__ g1b) {
    __shared__ unsigned short xs[64 * IN_F];   // 16 KB
    __shared__ unsigned short wT[64 * IN_F];   // 16 KB

    int t = threadIdx.x;
    int base = blockIdx.x * 64;

    // stage W1^T (bf16, pre-converted): 1024 16B chunks
    {
        const int4* src = (const int4*)wTg;
        int4* dst = (int4*)wT;
#pragma unroll
        for (int j = 0; j < 4; ++j) {
            int c = j * 256 + t;          // chunk id
            int colr = c >> 4, kc = c & 15;
            dst[colr * 16 + (kc ^ (colr & 7))] = src[c];
        }
    }
    // stage x tile -> bf16 swizzled
#pragma unroll
    for (int j = 0; j < 4; ++j) {
        int fidx = j * 2048 + t * 8;
        int r = fidx >> 7;                // 0..63
        int k = fidx & 127;
        float4 v0 = make_float4(0.f, 0.f, 0.f, 0.f), v1 = v0;
        if (base + r < N_NODES) {
            const float* xp = &x[(size_t)(base + r) * IN_F + k];
            v0 = *(const float4*)xp;
            v1 = *(const float4*)(xp + 4);
        }
        int4 pk;
        pk.x = pack2(v0.x, v0.y); pk.y = pack2(v0.z, v0.w);
        pk.z = pack2(v1.x, v1.y); pk.w = pack2(v1.z, v1.w);
        ((int4*)xs)[r * 16 + ((k >> 3) ^ (r & 7))] = pk;
    }
    __syncthreads();

    int l = t & 63;
    int w = t >> 6;
    int lr = l & 15;          // A-row / B-col / D-col component
    int lg = l >> 4;          // k-subgroup

    f32x4 acc[4];
#pragma unroll
    for (int ct = 0; ct < 4; ++ct) acc[ct] = (f32x4){0.f, 0.f, 0.f, 0.f};

#pragma unroll
    for (int kk = 0; kk < 4; ++kk) {
        int chunk = kk * 4 + lg;
        int arow = w * 16 + lr;
        bf16x8 a = *(bf16x8*)&xs[arow * IN_F + ((chunk ^ (arow & 7)) << 3)];
#pragma unroll
        for (int ct = 0; ct < 4; ++ct) {
            int bcol = ct * 16 + lr;
            bf16x8 b = *(bf16x8*)&wT[bcol * IN_F + ((chunk ^ (bcol & 7)) << 3)];
            acc[ct] = __builtin_amdgcn_mfma_f32_16x16x32_bf16(a, b, acc[ct], 0, 0, 0);
        }
    }

    // epilogue: D row = w*16 + lg*4 + i, col = ct*16 + lr
    float dv[4];
    int rbase = base + w * 16 + lg * 4;
#pragma unroll
    for (int i = 0; i < 4; ++i)
        dv[i] = (rbase + i < N_NODES) ? dinv[rbase + i] : 0.f;
#pragma unroll
    for (int i = 0; i < 4; ++i) {
        int n = rbase + i;
        if (n < N_NODES) {
#pragma unroll
            for (int ct = 0; ct < 4; ++ct)
                g1b[(unsigned)(n << 6) + ct * 16 + lr] = f2bf(acc[ct][i] * dv[i]);
        }
    }
}

// ---------------- layer 1 gather + finalize1 (bf16 out) ----------------
// 8 nodes per wave: 8 lanes/node, lane holds 8 features (uint4 = 8 bf16).

__global__ __launch_bounds__(256) void gather1_kernel(const int* __restrict__ rowptr,
                                                      const int* __restrict__ deg,
                                                      const int* __restrict__ srt,
                                                      const unsigned short* __restrict__ g1b,
                                                      const float* __restrict__ dinv,
                                                      const float* __restrict__ b1,
                                                      unsigned short* __restrict__ hb) {
    int t = threadIdx.x;
    int n = blockIdx.x * 32 + (t >> 3);   // 32 nodes per block
    int lane8 = t & 7;
    if (n >= N_NODES) return;
    int s = rowptr[n];
    int e = s + deg[n];
    unsigned fo = lane8 << 3;             // feature offset 0..56 (16B)

    float a0 = 0.f, a1 = 0.f, a2 = 0.f, a3 = 0.f;
    float a4 = 0.f, a5 = 0.f, a6 = 0.f, a7 = 0.f;
    float c0 = 0.f, c1 = 0.f, c2 = 0.f, c3 = 0.f;
    float c4 = 0.f, c5 = 0.f, c6 = 0.f, c7 = 0.f;
    int j = s;
    for (; j + 2 <= e; j += 2) {
        int r0 = srt[j], r1 = srt[j + 1];
        uint4 v0 = *(const uint4*)&g1b[(unsigned)(r0 << 6) + fo];
        uint4 v1 = *(const uint4*)&g1b[(unsigned)(r1 << 6) + fo];
        a0 += bflo(v0.x); a1 += bfhi(v0.x); a2 += bflo(v0.y); a3 += bfhi(v0.y);
        a4 += bflo(v0.z); a5 += bfhi(v0.z); a6 += bflo(v0.w); a7 += bfhi(v0.w);
        c0 += bflo(v1.x); c1 += bfhi(v1.x); c2 += bflo(v1.y); c3 += bfhi(v1.y);
        c4 += bflo(v1.z); c5 += bfhi(v1.z); c6 += bflo(v1.w); c7 += bfhi(v1.w);
    }
    if (j < e) {
        int r0 = srt[j];
        uint4 v0 = *(const uint4*)&g1b[(unsigned)(r0 << 6) + fo];
        a0 += bflo(v0.x); a1 += bfhi(v0.x); a2 += bflo(v0.y); a3 += bfhi(v0.y);
        a4 += bflo(v0.z); a5 += bfhi(v0.z); a6 += bflo(v0.w); a7 += bfhi(v0.w);
    }
    // self-loop
    uint4 vs = *(const uint4*)&g1b[(unsigned)(n << 6) + fo];
    a0 += c0 + bflo(vs.x); a1 += c1 + bfhi(vs.x);
    a2 += c2 + bflo(vs.y); a3 += c3 + bfhi(vs.y);
    a4 += c4 + bflo(vs.z); a5 += c5 + bfhi(vs.z);
    a6 += c6 + bflo(vs.w); a7 += c7 + bfhi(vs.w);

    float dv = dinv[n];
    float4 bb0 = *(const float4*)&b1[fo];
    float4 bb1 = *(const float4*)&b1[fo + 4];
    float o0 = dv * a0 + bb0.x, o1 = dv * a1 + bb0.y;
    float o2 = dv * a2 + bb0.z, o3 = dv * a3 + bb0.w;
    float o4 = dv * a4 + bb1.x, o5 = dv * a5 + bb1.y;
    float o6 = dv * a6 + bb1.z, o7 = dv * a7 + bb1.w;
    o0 = o0 > 0.f ? o0 : 0.f; o1 = o1 > 0.f ? o1 : 0.f;
    o2 = o2 > 0.f ? o2 : 0.f; o3 = o3 > 0.f ? o3 : 0.f;
    o4 = o4 > 0.f ? o4 : 0.f; o5 = o5 > 0.f ? o5 : 0.f;
    o6 = o6 > 0.f ? o6 : 0.f; o7 = o7 > 0.f ? o7 : 0.f;
    uint4 ob;
    ob.x = pack2(o0, o1); ob.y = pack2(o2, o3);
    ob.z = pack2(o4, o5); ob.w = pack2(o6, o7);
    *(uint4*)&hb[(unsigned)(n << 6) + fo] = ob;
}

// ---------------- layer 2 dense via MFMA: g2b = bf16((h @ W2) * dinv) -------
// Block = 64 nodes; LDS: h-tile bf16 [64][64] (8 KB) + W2^T [32][64] (4 KB).
// Per wave: 2 col-tiles x 2 K-chunks = 4 MFMA.

__global__ __launch_bounds__(256) void gemm2_mfma(const unsigned short* __restrict__ hb,
                                                  const unsigned short* __restrict__ wTg2,
                                                  const float* __restrict__ dinv,
                                                  unsigned short* __restrict__ g2b) {
    __shared__ unsigned short hs[64 * HID];    // 8 KB
    __shared__ unsigned short wT[32 * HID];    // 4 KB

    int t = threadIdx.x;
    int base = blockIdx.x * 64;

    // stage W2^T: 256 16B chunks
    if (t < 256) {
        int colr = t >> 3, kc = t & 7;
        ((int4*)wT)[colr * 8 + (kc ^ (colr & 7))] = ((const int4*)wTg2)[t];
    }
    // stage h tile: 512 16B chunks
    {
        const int4* src = (const int4*)hb;
        int4* dst = (int4*)hs;
#pragma unroll
        for (int j = 0; j < 2; ++j) {
            int c = j * 256 + t;
            int r = c >> 3, kc = c & 7;
            int4 v = make_int4(0, 0, 0, 0);
            if (base + r < N_NODES) v = src[(size_t)(base + r) * 8 + kc];
            dst[r * 8 + (kc ^ (r & 7))] = v;
        }
    }
    __syncthreads();

    int l = t & 63;
    int w = t >> 6;
    int lr = l & 15;
    int lg = l >> 4;

    f32x4 acc[2];
    acc[0] = (f32x4){0.f, 0.f, 0.f, 0.f};
    acc[1] = (f32x4){0.f, 0.f, 0.f, 0.f};

#pragma unroll
    for (int kk = 0; kk < 2; ++kk) {
        int chunk = kk * 4 + lg;
        int arow = w * 16 + lr;
        bf16x8 a = *(bf16x8*)&hs[arow * HID + ((chunk ^ (arow & 7)) << 3)];
#pragma unroll
        for (int ct = 0; ct < 2; ++ct) {
            int bcol = ct * 16 + lr;
            bf16x8 b = *(bf16x8*)&wT[bcol * HID + ((chunk ^ (bcol & 7)) << 3)];
            acc[ct] = __builtin_amdgcn_mfma_f32_16x16x32_bf16(a, b, acc[ct], 0, 0, 0);
        }
    }

    float dv[4];
    int rbase = base + w * 16 + lg * 4;
#pragma unroll
    for (int i = 0; i < 4; ++i)
        dv[i] = (rbase + i < N_NODES) ? dinv[rbase + i] : 0.f;
#pragma unroll
    for (int i = 0; i < 4; ++i) {
        int n = rbase + i;
        if (n < N_NODES) {
#pragma unroll
            for (int ct = 0; ct < 2; ++ct)
                g2b[(unsigned)(n << 5) + ct * 16 + lr] = f2bf(acc[ct][i] * dv[i]);
        }
    }
}

// ---------------- layer 2 gather + finalize2 ----------------
// 8 nodes per wave: 8 lanes/node, lane holds 4 features (uint2 = 4 bf16).

__global__ __launch_bounds__(256) void gather2_kernel(const int* __restrict__ rowptr,
                                                      const int* __restrict__ deg,
                                                      const int* __restrict__ srt,
                                                      const unsigned short* __restrict__ g2b,
                                                      const float* __restrict__ dinv,
                                                      const float* __restrict__ b2,
                                                      float* __restrict__ out) {
    int t = threadIdx.x;
    int n = blockIdx.x * 32 + (t >> 3);   // 32 nodes per block
    int lane8 = t & 7;
    if (n >= N_NODES) return;
    int s = rowptr[n];
    int e = s + deg[n];
    unsigned fo = lane8 << 2;             // feature offset 0..28 (8B)

    float a0 = 0.f, a1 = 0.f, a2 = 0.f, a3 = 0.f;
    float c0 = 0.f, c1 = 0.f, c2 = 0.f, c3 = 0.f;
    int j = s;
    for (; j + 2 <= e; j += 2) {
        int r0 = srt[j], r1 = srt[j + 1];
        uint2 v0 = *(const uint2*)&g2b[(unsigned)(r0 << 5) + fo];
        uint2 v1 = *(const uint2*)&g2b[(unsigned)(r1 << 5) + fo];
        a0 += bflo(v0.x); a1 += bfhi(v0.x); a2 += bflo(v0.y); a3 += bfhi(v0.y);
        c0 += bflo(v1.x); c1 += bfhi(v1.x); c2 += bflo(v1.y); c3 += bfhi(v1.y);
    }
    if (j < e) {
        uint2 v0 = *(const uint2*)&g2b[(unsigned)(srt[j] << 5) + fo];
        a0 += bflo(v0.x); a1 += bfhi(v0.x); a2 += bflo(v0.y); a3 += bfhi(v0.y);
    }
    uint2 vs = *(const uint2*)&g2b[(unsigned)(n << 5) + fo];
    a0 += c0 + bflo(vs.x); a1 += c1 + bfhi(vs.x);
    a2 += c2 + bflo(vs.y); a3 += c3 + bfhi(vs.y);

    float dv = dinv[n];
    float4 bb = *(const float4*)&b2[fo];
    float4 o;
    o.x = dv * a0 + bb.x; o.y = dv * a1 + bb.y;
    o.z = dv * a2 + bb.z; o.w = dv * a3 + bb.w;
    *(float4*)&out[(unsigned)(n << 5) + fo] = o;
}

extern "C" void kernel_launch(void* const* d_in, const int* in_sizes, int n_in,
                              void* d_out, int out_size, void* d_ws, size_t ws_size,
                              hipStream_t stream) {
    const float* x   = (const float*)d_in[0];
    const int*   ei  = (const int*)d_in[1];
    const int*   row = ei;             // edge_index[0] = source
    const int*   col = ei + N_EDGES;   // edge_index[1] = target
    const float* W1  = (const float*)d_in[2];
    const float* b1  = (const float*)d_in[3];
    const float* W2  = (const float*)d_in[4];
    const float* b2  = (const float*)d_in[5];
    float* out = (float*)d_out;

    // workspace layout
    char* p = (char*)d_ws;
    float*          dinv = (float*)p;          p += (size_t)N_NODES * 4;        // 0.4 MB
    unsigned short* g1b  = (unsigned short*)p; p += (size_t)N_NODES * HID * 2;  // 12.8 MB
    unsigned short* hb   = (unsigned short*)p; p += (size_t)N_NODES * HID * 2;  // 12.8 MB
    unsigned short* g2b  = (unsigned short*)p; p += (size_t)N_NODES * OUT_F * 2;// 6.4 MB
    int*   deg   = (int*)p;   p += (size_t)N_NODES * 4;          // 0.4 MB
    int*   rowp  = (int*)p;   p += (size_t)(N_NODES + 1) * 4;    // 0.4 MB
    int*   tot   = (int*)p;   p += ((NBUCK + 63) & ~63) * 4;
    int*   boff  = (int*)p;   p += ((NBUCK + 64) & ~63) * 4;
    unsigned short* wTg  = (unsigned short*)p; p += (size_t)IN_F * HID * 2;   // 16 KB
    unsigned short* wTg2 = (unsigned short*)p; p += (size_t)HID * OUT_F * 2;  // 4 KB
    int*   M     = (int*)p;   p += (size_t)NBUCK * NBLK_A * 4;   // 0.61 MB
    int*   srt   = (int*)p;   p += (size_t)N_EDGES * 4;          // 6.4 MB
    int*   tmp   = (int*)p;   p += (size_t)N_EDGES * 4;          // 6.4 MB (packed)

    wcvt_kernel  <<<(IN_F * HID + 255) / 256, 256, 0, stream>>>(W1, W2, wTg, wTg2);
    histA_kernel <<<NBLK_A, 256, 0, stream>>>(col, M);
    scanA_kernel <<<NBUCK, 256, 0, stream>>>(M, tot);
    bscan_kernel <<<1, 256, 0, stream>>>(tot, boff);
    scatA_kernel <<<NBLK_A, 256, 0, stream>>>(row, col, M, boff, tmp);
    binB2_kernel <<<NBUCK, 512, 0, stream>>>(boff, tmp, srt, rowp, deg, dinv);

    gemm1_mfma   <<<(N_NODES + 63) / 64, 256, 0, stream>>>(x, wTg, dinv, g1b);
    gather1_kernel<<<(N_NODES + 31) / 32, 256, 0, stream>>>(rowp, deg, srt, g1b, dinv, b1, hb);
    gemm2_mfma   <<<(N_NODES + 63) / 64, 256, 0, stream>>>(hb, wTg2, dinv, g2b);
    gather2_kernel<<<(N_NODES + 31) / 32, 256, 0, stream>>>(rowp, deg, srt, g2b, dinv, b2, out);
}

// Round 20
// 128.709 us; speedup vs baseline: 4.8608x; 1.0014x over previous
//
#include <hip/hip_runtime.h>

#define N_NODES 100000
#define N_EDGES 1600000
#define IN_F 128
#define HID 64
#define OUT_F 32

#define BSHIFT 8
#define BUCK_N (1 << BSHIFT)                               // 256 nodes/bucket
#define NBUCK ((N_NODES + BUCK_N - 1) >> BSHIFT)           // 391
#define EPB_A 2048
#define NBLK_A ((N_EDGES + EPB_A - 1) / EPB_A)             // 782
#define ROW_MASK 0x1FFFF                                   // 17 bits, N < 131072

typedef __attribute__((ext_vector_type(8))) short bf16x8;
typedef __attribute__((ext_vector_type(4))) float f32x4;

// bf16 helpers
__device__ __forceinline__ float bflo(unsigned u) { return __uint_as_float(u << 16); }
__device__ __forceinline__ float bfhi(unsigned u) { return __uint_as_float(u & 0xffff0000u); }
__device__ __forceinline__ unsigned short f2bf(float f) {
    unsigned u = __float_as_uint(f);
    u += 0x7FFF + ((u >> 16) & 1);   // round-to-nearest-even
    return (unsigned short)(u >> 16);
}
__device__ __forceinline__ unsigned pack2(float lo, float hi) {
    return (unsigned)f2bf(lo) | ((unsigned)f2bf(hi) << 16);
}

// ---------------- W1^T, W2^T -> bf16 (one-time, tiny) ----------------

__global__ __launch_bounds__(256) void wcvt_kernel(const float* __restrict__ W1,
                                                   const float* __restrict__ W2,
                                                   unsigned short* __restrict__ wTg,
                                                   unsigned short* __restrict__ wTg2) {
    int i = blockIdx.x * 256 + threadIdx.x;   // 8192
    if (i < IN_F * HID) {
        int k = i >> 6, c = i & 63;
        wTg[c * IN_F + k] = f2bf(W1[i]);
    }
    if (i < HID * OUT_F) {
        int k = i >> 5, c = i & 31;
        wTg2[c * HID + k] = f2bf(W2[i]);
    }
}

// ---------------- A1: per-block bucket hist -> M[bucket][blk] (no atomics) --

__global__ __launch_bounds__(256) void histA_kernel(const int* __restrict__ col,
                                                    int* __restrict__ M) {
    __shared__ int cnt[NBUCK];
    int t = threadIdx.x;
    int e0 = blockIdx.x * EPB_A;
    int e1 = e0 + EPB_A < N_EDGES ? e0 + EPB_A : N_EDGES;
    for (int i = t; i < NBUCK; i += 256) cnt[i] = 0;
    __syncthreads();
    for (int e = e0 + t; e < e1; e += 256) atomicAdd(&cnt[col[e] >> BSHIFT], 1);
    __syncthreads();
    for (int i = t; i < NBUCK; i += 256) M[i * NBLK_A + blockIdx.x] = cnt[i];
}

// ---------------- A2a: in-place exclusive scan of each bucket row ----------

__global__ __launch_bounds__(256) void scanA_kernel(int* __restrict__ M,
                                                    int* __restrict__ tot) {
    __shared__ int s[256];
    int b = blockIdx.x, t = threadIdx.x;
    int* rowM = M + (size_t)b * NBLK_A;
    int v[4]; int sum = 0;
#pragma unroll
    for (int j = 0; j < 4; ++j) {
        int idx = t * 4 + j;
        v[j] = (idx < NBLK_A) ? rowM[idx] : 0;
        sum += v[j];
    }
    s[t] = sum; __syncthreads();
    for (int off = 1; off < 256; off <<= 1) {
        int x = (t >= off) ? s[t - off] : 0; __syncthreads();
        s[t] += x; __syncthreads();
    }
    int run = s[t] - sum;   // exclusive prefix for this thread's chunk
#pragma unroll
    for (int j = 0; j < 4; ++j) {
        int idx = t * 4 + j;
        if (idx < NBLK_A) { int c = v[j]; rowM[idx] = run; run += c; }
    }
    if (t == 255) tot[b] = run;   // bucket total
}

// ---------------- A2b: scan bucket totals -> boff (2 entries/thread) -------

__global__ __launch_bounds__(256) void bscan_kernel(const int* __restrict__ tot,
                                                    int* __restrict__ boff) {
    __shared__ int s[256];
    int t = threadIdx.x;
    int i0 = t * 2, i1 = t * 2 + 1;
    int v0 = (i0 < NBUCK) ? tot[i0] : 0;
    int v1 = (i1 < NBUCK) ? tot[i1] : 0;
    int sum = v0 + v1;
    s[t] = sum; __syncthreads();
    for (int off = 1; off < 256; off <<= 1) {
        int x = (t >= off) ? s[t - off] : 0; __syncthreads();
        s[t] += x; __syncthreads();
    }
    int run = s[t] - sum;
    if (i0 < NBUCK) boff[i0] = run;
    if (i1 < NBUCK) boff[i1] = run + v0;
    if (t == 0) boff[NBUCK] = N_EDGES;
}

// ---------------- A3: scatter with precomputed bases (no global atomics) ----

__global__ __launch_bounds__(256) void scatA_kernel(const int* __restrict__ row,
                                                    const int* __restrict__ col,
                                                    const int* __restrict__ M,
                                                    const int* __restrict__ boff,
                                                    int* __restrict__ tmp) {
    __shared__ int base[NBUCK], lcur[NBUCK];
    int t = threadIdx.x;
    int e0 = blockIdx.x * EPB_A;
    int e1 = e0 + EPB_A < N_EDGES ? e0 + EPB_A : N_EDGES;
    for (int i = t; i < NBUCK; i += 256) {
        base[i] = boff[i] + M[i * NBLK_A + blockIdx.x];
        lcur[i] = 0;
    }
    __syncthreads();
    for (int e = e0 + t; e < e1; e += 256) {
        int c = col[e];
        int b = c >> BSHIFT;
        int rk = atomicAdd(&lcur[b], 1);
        tmp[base[b] + rk] = ((c & (BUCK_N - 1)) << 17) | row[e];
    }
}

// ---------------- binB2: per-bucket hist + scan + rowp/deg/dinv + sort -------
// 391 blocks x 512 threads; 256-node buckets (first 256 threads own nodes).

__global__ __launch_bounds__(512) void binB2_kernel(const int* __restrict__ boff,
                                                    const int* __restrict__ tmp,
                                                    int* __restrict__ srt,
                                                    int* __restrict__ rowp,
                                                    int* __restrict__ deg,
                                                    float* __restrict__ dinv) {
    __shared__ int cnt[BUCK_N];   // 1 KB: hist -> inclusive scan -> cursors
    int b = blockIdx.x, t = threadIdx.x;
    int nbase = b << BSHIFT;
    int s  = boff[b];
    int e1 = boff[b + 1];

    if (t < BUCK_N) cnt[t] = 0;
    __syncthreads();
    for (int e = s + t; e < e1; e += 512) atomicAdd(&cnt[tmp[e] >> 17], 1);
    __syncthreads();

    int v = (t < BUCK_N) ? cnt[t] : 0;   // this node's degree
    for (int off = 1; off < BUCK_N; off <<= 1) {
        int x = (t >= off && t < BUCK_N) ? cnt[t - off] : 0;
        __syncthreads();
        if (t < BUCK_N) cnt[t] += x;
        __syncthreads();
    }
    if (t < BUCK_N) {
        int rowpos = s + cnt[t] - v;  // global exclusive position
        int n = nbase + t;
        if (n < N_NODES) {
            rowp[n] = rowpos;
            deg[n]  = v;
            dinv[n] = rsqrtf((float)v + 1.0f);  // +1 = self-loop
        }
        cnt[t] = rowpos;              // will become cursor after barrier
    }
    __syncthreads();
    for (int e = s + t; e < e1; e += 512) {
        int rc = tmp[e];
        int pos = atomicAdd(&cnt[rc >> 17], 1);
        srt[pos] = rc & ROW_MASK;
    }
}

// ---------------- layer 1 dense via MFMA: g1b = bf16((x @ W1) * dinv) -------

__global__ __launch_bounds__(256) void gemm1_mfma(const float* __restrict__ x,
                                                  const unsigned short* __restrict__ wTg,
                                                  const float* __restrict__ dinv,
                                                  unsigned short* __restrict__ g1b) {
    __shared__ unsigned short xs[64 * IN_F];   // 16 KB
    __shared__ unsigned short wT[64 * IN_F];   // 16 KB

    int t = threadIdx.x;
    int base = blockIdx.x * 64;

    // stage W1^T (bf16, pre-converted): 1024 16B chunks
    {
        const int4* src = (const int4*)wTg;
        int4* dst = (int4*)wT;
#pragma unroll
        for (int j = 0; j < 4; ++j) {
            int c = j * 256 + t;          // chunk id
            int colr = c >> 4, kc = c & 15;
            dst[colr * 16 + (kc ^ (colr & 7))] = src[c];
        }
    }
    // stage x tile -> bf16 swizzled
#pragma unroll
    for (int j = 0; j < 4; ++j) {
        int fidx = j * 2048 + t * 8;
        int r = fidx >> 7;                // 0..63
        int k = fidx & 127;
        float4 v0 = make_float4(0.f, 0.f, 0.f, 0.f), v1 = v0;
        if (base + r < N_NODES) {
            const float* xp = &x[(size_t)(base + r) * IN_F + k];
            v0 = *(const float4*)xp;
            v1 = *(const float4*)(xp + 4);
        }
        int4 pk;
        pk.x = pack2(v0.x, v0.y); pk.y = pack2(v0.z, v0.w);
        pk.z = pack2(v1.x, v1.y); pk.w = pack2(v1.z, v1.w);
        ((int4*)xs)[r * 16 + ((k >> 3) ^ (r & 7))] = pk;
    }
    __syncthreads();

    int l = t & 63;
    int w = t >> 6;
    int lr = l & 15;          // A-row / B-col / D-col component
    int lg = l >> 4;          // k-subgroup

    f32x4 acc[4];
#pragma unroll
    for (int ct = 0; ct < 4; ++ct) acc[ct] = (f32x4){0.f, 0.f, 0.f, 0.f};

#pragma unroll
    for (int kk = 0; kk < 4; ++kk) {
        int chunk = kk * 4 + lg;
        int arow = w * 16 + lr;
        bf16x8 a = *(bf16x8*)&xs[arow * IN_F + ((chunk ^ (arow & 7)) << 3)];
#pragma unroll
        for (int ct = 0; ct < 4; ++ct) {
            int bcol = ct * 16 + lr;
            bf16x8 b = *(bf16x8*)&wT[bcol * IN_F + ((chunk ^ (bcol & 7)) << 3)];
            acc[ct] = __builtin_amdgcn_mfma_f32_16x16x32_bf16(a, b, acc[ct], 0, 0, 0);
        }
    }

    // epilogue: D row = w*16 + lg*4 + i, col = ct*16 + lr
    float dv[4];
    int rbase = base + w * 16 + lg * 4;
#pragma unroll
    for (int i = 0; i < 4; ++i)
        dv[i] = (rbase + i < N_NODES) ? dinv[rbase + i] : 0.f;
#pragma unroll
    for (int i = 0; i < 4; ++i) {
        int n = rbase + i;
        if (n < N_NODES) {
#pragma unroll
            for (int ct = 0; ct < 4; ++ct)
                g1b[(unsigned)(n << 6) + ct * 16 + lr] = f2bf(acc[ct][i] * dv[i]);
        }
    }
}

// ---------------- layer 1 gather + finalize1 (bf16 out, 4-edge unroll) ------
// 8 nodes per wave: 8 lanes/node, lane holds 8 features (uint4 = 8 bf16).

__global__ __launch_bounds__(256) void gather1_kernel(const int* __restrict__ rowptr,
                                                      const int* __restrict__ deg,
                                                      const int* __restrict__ srt,
                                                      const unsigned short* __restrict__ g1b,
                                                      const float* __restrict__ dinv,
                                                      const float* __restrict__ b1,
                                                      unsigned short* __restrict__ hb) {
    int t = threadIdx.x;
    int n = blockIdx.x * 32 + (t >> 3);   // 32 nodes per block
    int lane8 = t & 7;
    if (n >= N_NODES) return;
    int s = rowptr[n];
    int e = s + deg[n];
    unsigned fo = lane8 << 3;             // feature offset 0..56 (16B)

    float a0 = 0.f, a1 = 0.f, a2 = 0.f, a3 = 0.f;
    float a4 = 0.f, a5 = 0.f, a6 = 0.f, a7 = 0.f;
    float c0 = 0.f, c1 = 0.f, c2 = 0.f, c3 = 0.f;
    float c4 = 0.f, c5 = 0.f, c6 = 0.f, c7 = 0.f;
    int j = s;
    for (; j + 4 <= e; j += 4) {
        int r0 = srt[j], r1 = srt[j + 1], r2 = srt[j + 2], r3 = srt[j + 3];
        uint4 v0 = *(const uint4*)&g1b[(unsigned)(r0 << 6) + fo];
        uint4 v1 = *(const uint4*)&g1b[(unsigned)(r1 << 6) + fo];
        uint4 v2 = *(const uint4*)&g1b[(unsigned)(r2 << 6) + fo];
        uint4 v3 = *(const uint4*)&g1b[(unsigned)(r3 << 6) + fo];
        a0 += bflo(v0.x); a1 += bfhi(v0.x); a2 += bflo(v0.y); a3 += bfhi(v0.y);
        a4 += bflo(v0.z); a5 += bfhi(v0.z); a6 += bflo(v0.w); a7 += bfhi(v0.w);
        c0 += bflo(v1.x); c1 += bfhi(v1.x); c2 += bflo(v1.y); c3 += bfhi(v1.y);
        c4 += bflo(v1.z); c5 += bfhi(v1.z); c6 += bflo(v1.w); c7 += bfhi(v1.w);
        a0 += bflo(v2.x); a1 += bfhi(v2.x); a2 += bflo(v2.y); a3 += bfhi(v2.y);
        a4 += bflo(v2.z); a5 += bfhi(v2.z); a6 += bflo(v2.w); a7 += bfhi(v2.w);
        c0 += bflo(v3.x); c1 += bfhi(v3.x); c2 += bflo(v3.y); c3 += bfhi(v3.y);
        c4 += bflo(v3.z); c5 += bfhi(v3.z); c6 += bflo(v3.w); c7 += bfhi(v3.w);
    }
    for (; j < e; ++j) {
        int r0 = srt[j];
        uint4 v0 = *(const uint4*)&g1b[(unsigned)(r0 << 6) + fo];
        a0 += bflo(v0.x); a1 += bfhi(v0.x); a2 += bflo(v0.y); a3 += bfhi(v0.y);
        a4 += bflo(v0.z); a5 += bfhi(v0.z); a6 += bflo(v0.w); a7 += bfhi(v0.w);
    }
    // self-loop
    uint4 vs = *(const uint4*)&g1b[(unsigned)(n << 6) + fo];
    a0 += c0 + bflo(vs.x); a1 += c1 + bfhi(vs.x);
    a2 += c2 + bflo(vs.y); a3 += c3 + bfhi(vs.y);
    a4 += c4 + bflo(vs.z); a5 += c5 + bfhi(vs.z);
    a6 += c6 + bflo(vs.w); a7 += c7 + bfhi(vs.w);

    float dv = dinv[n];
    float4 bb0 = *(const float4*)&b1[fo];
    float4 bb1 = *(const float4*)&b1[fo + 4];
    float o0 = dv * a0 + bb0.x, o1 = dv * a1 + bb0.y;
    float o2 = dv * a2 + bb0.z, o3 = dv * a3 + bb0.w;
    float o4 = dv * a4 + bb1.x, o5 = dv * a5 + bb1.y;
    float o6 = dv * a6 + bb1.z, o7 = dv * a7 + bb1.w;
    o0 = o0 > 0.f ? o0 : 0.f; o1 = o1 > 0.f ? o1 : 0.f;
    o2 = o2 > 0.f ? o2 : 0.f; o3 = o3 > 0.f ? o3 : 0.f;
    o4 = o4 > 0.f ? o4 : 0.f; o5 = o5 > 0.f ? o5 : 0.f;
    o6 = o6 > 0.f ? o6 : 0.f; o7 = o7 > 0.f ? o7 : 0.f;
    uint4 ob;
    ob.x = pack2(o0, o1); ob.y = pack2(o2, o3);
    ob.z = pack2(o4, o5); ob.w = pack2(o6, o7);
    *(uint4*)&hb[(unsigned)(n << 6) + fo] = ob;
}

// ---------------- layer 2 dense via MFMA: g2b = bf16((h @ W2) * dinv) -------

__global__ __launch_bounds__(256) void gemm2_mfma(const unsigned short* __restrict__ hb,
                                                  const unsigned short* __restrict__ wTg2,
                                                  const float* __restrict__ dinv,
                                                  unsigned short* __restrict__ g2b) {
    __shared__ unsigned short hs[64 * HID];    // 8 KB
    __shared__ unsigned short wT[32 * HID];    // 4 KB

    int t = threadIdx.x;
    int base = blockIdx.x * 64;

    // stage W2^T: 256 16B chunks
    if (t < 256) {
        int colr = t >> 3, kc = t & 7;
        ((int4*)wT)[colr * 8 + (kc ^ (colr & 7))] = ((const int4*)wTg2)[t];
    }
    // stage h tile: 512 16B chunks
    {
        const int4* src = (const int4*)hb;
        int4* dst = (int4*)hs;
#pragma unroll
        for (int j = 0; j < 2; ++j) {
            int c = j * 256 + t;
            int r = c >> 3, kc = c & 7;
            int4 v = make_int4(0, 0, 0, 0);
            if (base + r < N_NODES) v = src[(size_t)(base + r) * 8 + kc];
            dst[r * 8 + (kc ^ (r & 7))] = v;
        }
    }
    __syncthreads();

    int l = t & 63;
    int w = t >> 6;
    int lr = l & 15;
    int lg = l >> 4;

    f32x4 acc[2];
    acc[0] = (f32x4){0.f, 0.f, 0.f, 0.f};
    acc[1] = (f32x4){0.f, 0.f, 0.f, 0.f};

#pragma unroll
    for (int kk = 0; kk < 2; ++kk) {
        int chunk = kk * 4 + lg;
        int arow = w * 16 + lr;
        bf16x8 a = *(bf16x8*)&hs[arow * HID + ((chunk ^ (arow & 7)) << 3)];
#pragma unroll
        for (int ct = 0; ct < 2; ++ct) {
            int bcol = ct * 16 + lr;
            bf16x8 b = *(bf16x8*)&wT[bcol * HID + ((chunk ^ (bcol & 7)) << 3)];
            acc[ct] = __builtin_amdgcn_mfma_f32_16x16x32_bf16(a, b, acc[ct], 0, 0, 0);
        }
    }

    float dv[4];
    int rbase = base + w * 16 + lg * 4;
#pragma unroll
    for (int i = 0; i < 4; ++i)
        dv[i] = (rbase + i < N_NODES) ? dinv[rbase + i] : 0.f;
#pragma unroll
    for (int i = 0; i < 4; ++i) {
        int n = rbase + i;
        if (n < N_NODES) {
#pragma unroll
            for (int ct = 0; ct < 2; ++ct)
                g2b[(unsigned)(n << 5) + ct * 16 + lr] = f2bf(acc[ct][i] * dv[i]);
        }
    }
}

// ---------------- layer 2 gather + finalize2 (4-edge unroll) ----------------
// 8 nodes per wave: 8 lanes/node, lane holds 4 features (uint2 = 4 bf16).

__global__ __launch_bounds__(256) void gather2_kernel(const int* __restrict__ rowptr,
                                                      const int* __restrict__ deg,
                                                      const int* __restrict__ srt,
                                                      const unsigned short* __restrict__ g2b,
                                                      const float* __restrict__ dinv,
                                                      const float* __restrict__ b2,
                                                      float* __restrict__ out) {
    int t = threadIdx.x;
    int n = blockIdx.x * 32 + (t >> 3);   // 32 nodes per block
    int lane8 = t & 7;
    if (n >= N_NODES) return;
    int s = rowptr[n];
    int e = s + deg[n];
    unsigned fo = lane8 << 2;             // feature offset 0..28 (8B)

    float a0 = 0.f, a1 = 0.f, a2 = 0.f, a3 = 0.f;
    float c0 = 0.f, c1 = 0.f, c2 = 0.f, c3 = 0.f;
    int j = s;
    for (; j + 4 <= e; j += 4) {
        int r0 = srt[j], r1 = srt[j + 1], r2 = srt[j + 2], r3 = srt[j + 3];
        uint2 v0 = *(const uint2*)&g2b[(unsigned)(r0 << 5) + fo];
        uint2 v1 = *(const uint2*)&g2b[(unsigned)(r1 << 5) + fo];
        uint2 v2 = *(const uint2*)&g2b[(unsigned)(r2 << 5) + fo];
        uint2 v3 = *(const uint2*)&g2b[(unsigned)(r3 << 5) + fo];
        a0 += bflo(v0.x); a1 += bfhi(v0.x); a2 += bflo(v0.y); a3 += bfhi(v0.y);
        c0 += bflo(v1.x); c1 += bfhi(v1.x); c2 += bflo(v1.y); c3 += bfhi(v1.y);
        a0 += bflo(v2.x); a1 += bfhi(v2.x); a2 += bflo(v2.y); a3 += bfhi(v2.y);
        c0 += bflo(v3.x); c1 += bfhi(v3.x); c2 += bflo(v3.y); c3 += bfhi(v3.y);
    }
    for (; j < e; ++j) {
        uint2 v0 = *(const uint2*)&g2b[(unsigned)(srt[j] << 5) + fo];
        a0 += bflo(v0.x); a1 += bfhi(v0.x); a2 += bflo(v0.y); a3 += bfhi(v0.y);
    }
    uint2 vs = *(const uint2*)&g2b[(unsigned)(n << 5) + fo];
    a0 += c0 + bflo(vs.x); a1 += c1 + bfhi(vs.x);
    a2 += c2 + bflo(vs.y); a3 += c3 + bfhi(vs.y);

    float dv = dinv[n];
    float4 bb = *(const float4*)&b2[fo];
    float4 o;
    o.x = dv * a0 + bb.x; o.y = dv * a1 + bb.y;
    o.z = dv * a2 + bb.z; o.w = dv * a3 + bb.w;
    *(float4*)&out[(unsigned)(n << 5) + fo] = o;
}

extern "C" void kernel_launch(void* const* d_in, const int* in_sizes, int n_in,
                              void* d_out, int out_size, void* d_ws, size_t ws_size,
                              hipStream_t stream) {
    const float* x   = (const float*)d_in[0];
    const int*   ei  = (const int*)d_in[1];
    const int*   row = ei;             // edge_index[0] = source
    const int*   col = ei + N_EDGES;   // edge_index[1] = target
    const float* W1  = (const float*)d_in[2];
    const float* b1  = (const float*)d_in[3];
    const float* W2  = (const float*)d_in[4];
    const float* b2  = (const float*)d_in[5];
    float* out = (float*)d_out;

    // workspace layout
    char* p = (char*)d_ws;
    float*          dinv = (float*)p;          p += (size_t)N_NODES * 4;        // 0.4 MB
    unsigned short* g1b  = (unsigned short*)p; p += (size_t)N_NODES * HID * 2;  // 12.8 MB
    unsigned short* hb   = (unsigned short*)p; p += (size_t)N_NODES * HID * 2;  // 12.8 MB
    unsigned short* g2b  = (unsigned short*)p; p += (size_t)N_NODES * OUT_F * 2;// 6.4 MB
    int*   deg   = (int*)p;   p += (size_t)N_NODES * 4;          // 0.4 MB
    int*   rowp  = (int*)p;   p += (size_t)(N_NODES + 1) * 4;    // 0.4 MB
    int*   tot   = (int*)p;   p += ((NBUCK + 63) & ~63) * 4;
    int*   boff  = (int*)p;   p += ((NBUCK + 64) & ~63) * 4;
    unsigned short* wTg  = (unsigned short*)p; p += (size_t)IN_F * HID * 2;   // 16 KB
    unsigned short* wTg2 = (unsigned short*)p; p += (size_t)HID * OUT_F * 2;  // 4 KB
    int*   M     = (int*)p;   p += (size_t)NBUCK * NBLK_A * 4;   // 1.22 MB
    int*   srt   = (int*)p;   p += (size_t)N_EDGES * 4;          // 6.4 MB
    int*   tmp   = (int*)p;   p += (size_t)N_EDGES * 4;          // 6.4 MB (packed)

    wcvt_kernel  <<<(IN_F * HID + 255) / 256, 256, 0, stream>>>(W1, W2, wTg, wTg2);
    histA_kernel <<<NBLK_A, 256, 0, stream>>>(col, M);
    scanA_kernel <<<NBUCK, 256, 0, stream>>>(M, tot);
    bscan_kernel <<<1, 256, 0, stream>>>(tot, boff);
    scatA_kernel <<<NBLK_A, 256, 0, stream>>>(row, col, M, boff, tmp);
    binB2_kernel <<<NBUCK, 512, 0, stream>>>(boff, tmp, srt, rowp, deg, dinv);

    gemm1_mfma   <<<(N_NODES + 63) / 64, 256, 0, stream>>>(x, wTg, dinv, g1b);
    gather1_kernel<<<(N_NODES + 31) / 32, 256, 0, stream>>>(rowp, deg, srt, g1b, dinv, b1, hb);
    gemm2_mfma   <<<(N_NODES + 63) / 64, 256, 0, stream>>>(hb, wTg2, dinv, g2b);
    gather2_kernel<<<(N_NODES + 31) / 32, 256, 0, stream>>>(rowp, deg, srt, g2b, dinv, b2, out);
}

// Round 21
// 119.417 us; speedup vs baseline: 5.2391x; 1.0778x over previous
//
#include <hip/hip_runtime.h>

#define N_NODES 100000
#define N_EDGES 1600000
#define IN_F 128
#define HID 64
#define OUT_F 32

#define BSHIFT 9
#define BUCK_N (1 << BSHIFT)                               // 512 nodes/bucket
#define NBUCK ((N_NODES + BUCK_N - 1) >> BSHIFT)           // 196
#define EPB_A 2048
#define NBLK_A ((N_EDGES + EPB_A - 1) / EPB_A)             // 782
#define ROW_MASK 0x1FFFF                                   // 17 bits, N < 131072

typedef __attribute__((ext_vector_type(8))) short bf16x8;
typedef __attribute__((ext_vector_type(4))) float f32x4;

// bf16 helpers
__device__ __forceinline__ float bflo(unsigned u) { return __uint_as_float(u << 16); }
__device__ __forceinline__ float bfhi(unsigned u) { return __uint_as_float(u & 0xffff0000u); }
__device__ __forceinline__ unsigned short f2bf(float f) {
    unsigned u = __float_as_uint(f);
    u += 0x7FFF + ((u >> 16) & 1);   // round-to-nearest-even
    return (unsigned short)(u >> 16);
}
__device__ __forceinline__ unsigned pack2(float lo, float hi) {
    return (unsigned)f2bf(lo) | ((unsigned)f2bf(hi) << 16);
}

// ---------------- A1: per-block bucket hist -> M[bucket][blk] (no atomics) --
// Blocks 0..31 also convert W1^T / W2^T to bf16 (fused wcvt).

__global__ __launch_bounds__(256) void histA_kernel(const int* __restrict__ col,
                                                    int* __restrict__ M,
                                                    const float* __restrict__ W1,
                                                    const float* __restrict__ W2,
                                                    unsigned short* __restrict__ wTg,
                                                    unsigned short* __restrict__ wTg2) {
    __shared__ int cnt[NBUCK];
    int t = threadIdx.x;
    if (blockIdx.x < 32) {
        int i = blockIdx.x * 256 + t;     // 0..8191
        int k = i >> 6, c = i & 63;
        wTg[c * IN_F + k] = f2bf(W1[i]);
        if (i < HID * OUT_F) {
            int k2 = i >> 5, c2 = i & 31;
            wTg2[c2 * HID + k2] = f2bf(W2[i]);
        }
    }
    int e0 = blockIdx.x * EPB_A;
    int e1 = e0 + EPB_A < N_EDGES ? e0 + EPB_A : N_EDGES;
    for (int i = t; i < NBUCK; i += 256) cnt[i] = 0;
    __syncthreads();
    for (int e = e0 + t; e < e1; e += 256) atomicAdd(&cnt[col[e] >> BSHIFT], 1);
    __syncthreads();
    for (int i = t; i < NBUCK; i += 256) M[i * NBLK_A + blockIdx.x] = cnt[i];
}

// ---------------- A2a: in-place exclusive scan of each bucket row ----------

__global__ __launch_bounds__(256) void scanA_kernel(int* __restrict__ M,
                                                    int* __restrict__ tot) {
    __shared__ int s[256];
    int b = blockIdx.x, t = threadIdx.x;
    int* rowM = M + (size_t)b * NBLK_A;
    int v[4]; int sum = 0;
#pragma unroll
    for (int j = 0; j < 4; ++j) {
        int idx = t * 4 + j;
        v[j] = (idx < NBLK_A) ? rowM[idx] : 0;
        sum += v[j];
    }
    s[t] = sum; __syncthreads();
    for (int off = 1; off < 256; off <<= 1) {
        int x = (t >= off) ? s[t - off] : 0; __syncthreads();
        s[t] += x; __syncthreads();
    }
    int run = s[t] - sum;   // exclusive prefix for this thread's chunk
#pragma unroll
    for (int j = 0; j < 4; ++j) {
        int idx = t * 4 + j;
        if (idx < NBLK_A) { int c = v[j]; rowM[idx] = run; run += c; }
    }
    if (t == 255) tot[b] = run;   // bucket total
}

// ---------------- A2b: scan bucket totals -> boff ----------------

__global__ __launch_bounds__(256) void bscan_kernel(const int* __restrict__ tot,
                                                    int* __restrict__ boff) {
    __shared__ int s[256];
    int t = threadIdx.x;
    int v = (t < NBUCK) ? tot[t] : 0;
    s[t] = v; __syncthreads();
    for (int off = 1; off < 256; off <<= 1) {
        int x = (t >= off) ? s[t - off] : 0; __syncthreads();
        s[t] += x; __syncthreads();
    }
    if (t < NBUCK) boff[t] = s[t] - v;
    if (t == 0) boff[NBUCK] = N_EDGES;
}

// ---------------- A3: scatter with precomputed bases (no global atomics) ----

__global__ __launch_bounds__(256) void scatA_kernel(const int* __restrict__ row,
                                                    const int* __restrict__ col,
                                                    const int* __restrict__ M,
                                                    const int* __restrict__ boff,
                                                    int* __restrict__ tmp) {
    __shared__ int base[NBUCK], lcur[NBUCK];
    int t = threadIdx.x;
    int e0 = blockIdx.x * EPB_A;
    int e1 = e0 + EPB_A < N_EDGES ? e0 + EPB_A : N_EDGES;
    for (int i = t; i < NBUCK; i += 256) {
        base[i] = boff[i] + M[i * NBLK_A + blockIdx.x];
        lcur[i] = 0;
    }
    __syncthreads();
    for (int e = e0 + t; e < e1; e += 256) {
        int c = col[e];
        int b = c >> BSHIFT;
        int rk = atomicAdd(&lcur[b], 1);
        tmp[base[b] + rk] = ((c & (BUCK_N - 1)) << 17) | row[e];
    }
}

// ---------------- binB2: per-bucket hist + scan + rowp/deg/dinv + sort -------
// 196 blocks x 512 threads; 512-node buckets.

__global__ __launch_bounds__(512) void binB2_kernel(const int* __restrict__ boff,
                                                    const int* __restrict__ tmp,
                                                    int* __restrict__ srt,
                                                    int* __restrict__ rowp,
                                                    int* __restrict__ deg,
                                                    float* __restrict__ dinv) {
    __shared__ int cnt[BUCK_N];   // 2 KB: hist -> inclusive scan -> cursors
    int b = blockIdx.x, t = threadIdx.x;
    int nbase = b << BSHIFT;
    int s  = boff[b];
    int e1 = boff[b + 1];

    cnt[t] = 0;
    __syncthreads();
    for (int e = s + t; e < e1; e += 512) atomicAdd(&cnt[tmp[e] >> 17], 1);
    __syncthreads();

    int v = cnt[t];               // this node's degree
    for (int off = 1; off < 512; off <<= 1) {
        int x = (t >= off) ? cnt[t - off] : 0; __syncthreads();
        cnt[t] += x; __syncthreads();
    }
    int rowpos = s + cnt[t] - v;  // global exclusive position
    int n = nbase + t;
    if (n < N_NODES) {
        rowp[n] = rowpos;
        deg[n]  = v;
        dinv[n] = rsqrtf((float)v + 1.0f);  // +1 = self-loop
    }
    __syncthreads();
    cnt[t] = rowpos;              // now cursors
    __syncthreads();
    for (int e = s + t; e < e1; e += 512) {
        int rc = tmp[e];
        int pos = atomicAdd(&cnt[rc >> 17], 1);
        srt[pos] = rc & ROW_MASK;
    }
}

// ---------------- layer 1 dense via MFMA: g1b = bf16((x @ W1) * dinv) -------

__global__ __launch_bounds__(256) void gemm1_mfma(const float* __restrict__ x,
                                                  const unsigned short* __restrict__ wTg,
                                                  const float* __restrict__ dinv,
                                                  unsigned short* __restrict__ g1b) {
    __shared__ unsigned short xs[64 * IN_F];   // 16 KB
    __shared__ unsigned short wT[64 * IN_F];   // 16 KB

    int t = threadIdx.x;
    int base = blockIdx.x * 64;

    // stage W1^T (bf16, pre-converted): 1024 16B chunks
    {
        const int4* src = (const int4*)wTg;
        int4* dst = (int4*)wT;
#pragma unroll
        for (int j = 0; j < 4; ++j) {
            int c = j * 256 + t;          // chunk id
            int colr = c >> 4, kc = c & 15;
            dst[colr * 16 + (kc ^ (colr & 7))] = src[c];
        }
    }
    // stage x tile -> bf16 swizzled
#pragma unroll
    for (int j = 0; j < 4; ++j) {
        int fidx = j * 2048 + t * 8;
        int r = fidx >> 7;                // 0..63
        int k = fidx & 127;
        float4 v0 = make_float4(0.f, 0.f, 0.f, 0.f), v1 = v0;
        if (base + r < N_NODES) {
            const float* xp = &x[(size_t)(base + r) * IN_F + k];
            v0 = *(const float4*)xp;
            v1 = *(const float4*)(xp + 4);
        }
        int4 pk;
        pk.x = pack2(v0.x, v0.y); pk.y = pack2(v0.z, v0.w);
        pk.z = pack2(v1.x, v1.y); pk.w = pack2(v1.z, v1.w);
        ((int4*)xs)[r * 16 + ((k >> 3) ^ (r & 7))] = pk;
    }
    __syncthreads();

    int l = t & 63;
    int w = t >> 6;
    int lr = l & 15;          // A-row / B-col / D-col component
    int lg = l >> 4;          // k-subgroup

    f32x4 acc[4];
#pragma unroll
    for (int ct = 0; ct < 4; ++ct) acc[ct] = (f32x4){0.f, 0.f, 0.f, 0.f};

#pragma unroll
    for (int kk = 0; kk < 4; ++kk) {
        int chunk = kk * 4 + lg;
        int arow = w * 16 + lr;
        bf16x8 a = *(bf16x8*)&xs[arow * IN_F + ((chunk ^ (arow & 7)) << 3)];
#pragma unroll
        for (int ct = 0; ct < 4; ++ct) {
            int bcol = ct * 16 + lr;
            bf16x8 b = *(bf16x8*)&wT[bcol * IN_F + ((chunk ^ (bcol & 7)) << 3)];
            acc[ct] = __builtin_amdgcn_mfma_f32_16x16x32_bf16(a, b, acc[ct], 0, 0, 0);
        }
    }

    // epilogue: D row = w*16 + lg*4 + i, col = ct*16 + lr
    float dv[4];
    int rbase = base + w * 16 + lg * 4;
#pragma unroll
    for (int i = 0; i < 4; ++i)
        dv[i] = (rbase + i < N_NODES) ? dinv[rbase + i] : 0.f;
#pragma unroll
    for (int i = 0; i < 4; ++i) {
        int n = rbase + i;
        if (n < N_NODES) {
#pragma unroll
            for (int ct = 0; ct < 4; ++ct)
                g1b[(unsigned)(n << 6) + ct * 16 + lr] = f2bf(acc[ct][i] * dv[i]);
        }
    }
}

// ---------------- layer 1 gather + finalize1 (bf16 out, 4-edge unroll) ------
// 8 nodes per wave: 8 lanes/node, lane holds 8 features (uint4 = 8 bf16).

__global__ __launch_bounds__(256) void gather1_kernel(const int* __restrict__ rowptr,
                                                      const int* __restrict__ deg,
                                                      const int* __restrict__ srt,
                                                      const unsigned short* __restrict__ g1b,
                                                      const float* __restrict__ dinv,
                                                      const float* __restrict__ b1,
                                                      unsigned short* __restrict__ hb) {
    int t = threadIdx.x;
    int n = blockIdx.x * 32 + (t >> 3);   // 32 nodes per block
    int lane8 = t & 7;
    if (n >= N_NODES) return;
    int s = rowptr[n];
    int e = s + deg[n];
    unsigned fo = lane8 << 3;             // feature offset 0..56 (16B)

    float a0 = 0.f, a1 = 0.f, a2 = 0.f, a3 = 0.f;
    float a4 = 0.f, a5 = 0.f, a6 = 0.f, a7 = 0.f;
    float c0 = 0.f, c1 = 0.f, c2 = 0.f, c3 = 0.f;
    float c4 = 0.f, c5 = 0.f, c6 = 0.f, c7 = 0.f;
    int j = s;
    for (; j + 4 <= e; j += 4) {
        int r0 = srt[j], r1 = srt[j + 1], r2 = srt[j + 2], r3 = srt[j + 3];
        uint4 v0 = *(const uint4*)&g1b[(unsigned)(r0 << 6) + fo];
        uint4 v1 = *(const uint4*)&g1b[(unsigned)(r1 << 6) + fo];
        uint4 v2 = *(const uint4*)&g1b[(unsigned)(r2 << 6) + fo];
        uint4 v3 = *(const uint4*)&g1b[(unsigned)(r3 << 6) + fo];
        a0 += bflo(v0.x); a1 += bfhi(v0.x); a2 += bflo(v0.y); a3 += bfhi(v0.y);
        a4 += bflo(v0.z); a5 += bfhi(v0.z); a6 += bflo(v0.w); a7 += bfhi(v0.w);
        c0 += bflo(v1.x); c1 += bfhi(v1.x); c2 += bflo(v1.y); c3 += bfhi(v1.y);
        c4 += bflo(v1.z); c5 += bfhi(v1.z); c6 += bflo(v1.w); c7 += bfhi(v1.w);
        a0 += bflo(v2.x); a1 += bfhi(v2.x); a2 += bflo(v2.y); a3 += bfhi(v2.y);
        a4 += bflo(v2.z); a5 += bfhi(v2.z); a6 += bflo(v2.w); a7 += bfhi(v2.w);
        c0 += bflo(v3.x); c1 += bfhi(v3.x); c2 += bflo(v3.y); c3 += bfhi(v3.y);
        c4 += bflo(v3.z); c5 += bfhi(v3.z); c6 += bflo(v3.w); c7 += bfhi(v3.w);
    }
    for (; j < e; ++j) {
        int r0 = srt[j];
        uint4 v0 = *(const uint4*)&g1b[(unsigned)(r0 << 6) + fo];
        a0 += bflo(v0.x); a1 += bfhi(v0.x); a2 += bflo(v0.y); a3 += bfhi(v0.y);
        a4 += bflo(v0.z); a5 += bfhi(v0.z); a6 += bflo(v0.w); a7 += bfhi(v0.w);
    }
    // self-loop
    uint4 vs = *(const uint4*)&g1b[(unsigned)(n << 6) + fo];
    a0 += c0 + bflo(vs.x); a1 += c1 + bfhi(vs.x);
    a2 += c2 + bflo(vs.y); a3 += c3 + bfhi(vs.y);
    a4 += c4 + bflo(vs.z); a5 += c5 + bfhi(vs.z);
    a6 += c6 + bflo(vs.w); a7 += c7 + bfhi(vs.w);

    float dv = dinv[n];
    float4 bb0 = *(const float4*)&b1[fo];
    float4 bb1 = *(const float4*)&b1[fo + 4];
    float o0 = dv * a0 + bb0.x, o1 = dv * a1 + bb0.y;
    float o2 = dv * a2 + bb0.z, o3 = dv * a3 + bb0.w;
    float o4 = dv * a4 + bb1.x, o5 = dv * a5 + bb1.y;
    float o6 = dv * a6 + bb1.z, o7 = dv * a7 + bb1.w;
    o0 = o0 > 0.f ? o0 : 0.f; o1 = o1 > 0.f ? o1 : 0.f;
    o2 = o2 > 0.f ? o2 : 0.f; o3 = o3 > 0.f ? o3 : 0.f;
    o4 = o4 > 0.f ? o4 : 0.f; o5 = o5 > 0.f ? o5 : 0.f;
    o6 = o6 > 0.f ? o6 : 0.f; o7 = o7 > 0.f ? o7 : 0.f;
    uint4 ob;
    ob.x = pack2(o0, o1); ob.y = pack2(o2, o3);
    ob.z = pack2(o4, o5); ob.w = pack2(o6, o7);
    *(uint4*)&hb[(unsigned)(n << 6) + fo] = ob;
}

// ---------------- layer 2 dense via MFMA: g2b = bf16((h @ W2) * dinv) -------

__global__ __launch_bounds__(256) void gemm2_mfma(const unsigned short* __restrict__ hb,
                                                  const unsigned short* __restrict__ wTg2,
                                                  const float* __restrict__ dinv,
                                                  unsigned short* __restrict__ g2b) {
    __shared__ unsigned short hs[64 * HID];    // 8 KB
    __shared__ unsigned short wT[32 * HID];    // 4 KB

    int t = threadIdx.x;
    int base = blockIdx.x * 64;

    // stage W2^T: 256 16B chunks
    if (t < 256) {
        int colr = t >> 3, kc = t & 7;
        ((int4*)wT)[colr * 8 + (kc ^ (colr & 7))] = ((const int4*)wTg2)[t];
    }
    // stage h tile: 512 16B chunks
    {
        const int4* src = (const int4*)hb;
        int4* dst = (int4*)hs;
#pragma unroll
        for (int j = 0; j < 2; ++j) {
            int c = j * 256 + t;
            int r = c >> 3, kc = c & 7;
            int4 v = make_int4(0, 0, 0, 0);
            if (base + r < N_NODES) v = src[(size_t)(base + r) * 8 + kc];
            dst[r * 8 + (kc ^ (r & 7))] = v;
        }
    }
    __syncthreads();

    int l = t & 63;
    int w = t >> 6;
    int lr = l & 15;
    int lg = l >> 4;

    f32x4 acc[2];
    acc[0] = (f32x4){0.f, 0.f, 0.f, 0.f};
    acc[1] = (f32x4){0.f, 0.f, 0.f, 0.f};

#pragma unroll
    for (int kk = 0; kk < 2; ++kk) {
        int chunk = kk * 4 + lg;
        int arow = w * 16 + lr;
        bf16x8 a = *(bf16x8*)&hs[arow * HID + ((chunk ^ (arow & 7)) << 3)];
#pragma unroll
        for (int ct = 0; ct < 2; ++ct) {
            int bcol = ct * 16 + lr;
            bf16x8 b = *(bf16x8*)&wT[bcol * HID + ((chunk ^ (bcol & 7)) << 3)];
            acc[ct] = __builtin_amdgcn_mfma_f32_16x16x32_bf16(a, b, acc[ct], 0, 0, 0);
        }
    }

    float dv[4];
    int rbase = base + w * 16 + lg * 4;
#pragma unroll
    for (int i = 0; i < 4; ++i)
        dv[i] = (rbase + i < N_NODES) ? dinv[rbase + i] : 0.f;
#pragma unroll
    for (int i = 0; i < 4; ++i) {
        int n = rbase + i;
        if (n < N_NODES) {
#pragma unroll
            for (int ct = 0; ct < 2; ++ct)
                g2b[(unsigned)(n << 5) + ct * 16 + lr] = f2bf(acc[ct][i] * dv[i]);
        }
    }
}

// ---------------- layer 2 gather + finalize2 (4-edge unroll) ----------------
// 8 nodes per wave: 8 lanes/node, lane holds 4 features (uint2 = 4 bf16).

__global__ __launch_bounds__(256) void gather2_kernel(const int* __restrict__ rowptr,
                                                      const int* __restrict__ deg,
                                                      const int* __restrict__ srt,
                                                      const unsigned short* __restrict__ g2b,
                                                      const float* __restrict__ dinv,
                                                      const float* __restrict__ b2,
                                                      float* __restrict__ out) {
    int t = threadIdx.x;
    int n = blockIdx.x * 32 + (t >> 3);   // 32 nodes per block
    int lane8 = t & 7;
    if (n >= N_NODES) return;
    int s = rowptr[n];
    int e = s + deg[n];
    unsigned fo = lane8 << 2;             // feature offset 0..28 (8B)

    float a0 = 0.f, a1 = 0.f, a2 = 0.f, a3 = 0.f;
    float c0 = 0.f, c1 = 0.f, c2 = 0.f, c3 = 0.f;
    int j = s;
    for (; j + 4 <= e; j += 4) {
        int r0 = srt[j], r1 = srt[j + 1], r2 = srt[j + 2], r3 = srt[j + 3];
        uint2 v0 = *(const uint2*)&g2b[(unsigned)(r0 << 5) + fo];
        uint2 v1 = *(const uint2*)&g2b[(unsigned)(r1 << 5) + fo];
        uint2 v2 = *(const uint2*)&g2b[(unsigned)(r2 << 5) + fo];
        uint2 v3 = *(const uint2*)&g2b[(unsigned)(r3 << 5) + fo];
        a0 += bflo(v0.x); a1 += bfhi(v0.x); a2 += bflo(v0.y); a3 += bfhi(v0.y);
        c0 += bflo(v1.x); c1 += bfhi(v1.x); c2 += bflo(v1.y); c3 += bfhi(v1.y);
        a0 += bflo(v2.x); a1 += bfhi(v2.x); a2 += bflo(v2.y); a3 += bfhi(v2.y);
        c0 += bflo(v3.x); c1 += bfhi(v3.x); c2 += bflo(v3.y); c3 += bfhi(v3.y);
    }
    for (; j < e; ++j) {
        uint2 v0 = *(const uint2*)&g2b[(unsigned)(srt[j] << 5) + fo];
        a0 += bflo(v0.x); a1 += bfhi(v0.x); a2 += bflo(v0.y); a3 += bfhi(v0.y);
    }
    uint2 vs = *(const uint2*)&g2b[(unsigned)(n << 5) + fo];
    a0 += c0 + bflo(vs.x); a1 += c1 + bfhi(vs.x);
    a2 += c2 + bflo(vs.y); a3 += c3 + bfhi(vs.y);

    float dv = dinv[n];
    float4 bb = *(const float4*)&b2[fo];
    float4 o;
    o.x = dv * a0 + bb.x; o.y = dv * a1 + bb.y;
    o.z = dv * a2 + bb.z; o.w = dv * a3 + bb.w;
    *(float4*)&out[(unsigned)(n << 5) + fo] = o;
}

extern "C" void kernel_launch(void* const* d_in, const int* in_sizes, int n_in,
                              void* d_out, int out_size, void* d_ws, size_t ws_size,
                              hipStream_t stream) {
    const float* x   = (const float*)d_in[0];
    const int*   ei  = (const int*)d_in[1];
    const int*   row = ei;             // edge_index[0] = source
    const int*   col = ei + N_EDGES;   // edge_index[1] = target
    const float* W1  = (const float*)d_in[2];
    const float* b1  = (const float*)d_in[3];
    const float* W2  = (const float*)d_in[4];
    const float* b2  = (const float*)d_in[5];
    float* out = (float*)d_out;

    // workspace layout
    char* p = (char*)d_ws;
    float*          dinv = (float*)p;          p += (size_t)N_NODES * 4;        // 0.4 MB
    unsigned short* g1b  = (unsigned short*)p; p += (size_t)N_NODES * HID * 2;  // 12.8 MB
    unsigned short* hb   = (unsigned short*)p; p += (size_t)N_NODES * HID * 2;  // 12.8 MB
    unsigned short* g2b  = (unsigned short*)p; p += (size_t)N_NODES * OUT_F * 2;// 6.4 MB
    int*   deg   = (int*)p;   p += (size_t)N_NODES * 4;          // 0.4 MB
    int*   rowp  = (int*)p;   p += (size_t)(N_NODES + 1) * 4;    // 0.4 MB
    int*   tot   = (int*)p;   p += ((NBUCK + 63) & ~63) * 4;
    int*   boff  = (int*)p;   p += ((NBUCK + 64) & ~63) * 4;
    unsigned short* wTg  = (unsigned short*)p; p += (size_t)IN_F * HID * 2;   // 16 KB
    unsigned short* wTg2 = (unsigned short*)p; p += (size_t)HID * OUT_F * 2;  // 4 KB
    int*   M     = (int*)p;   p += (size_t)NBUCK * NBLK_A * 4;   // 0.61 MB
    int*   srt   = (int*)p;   p += (size_t)N_EDGES * 4;          // 6.4 MB
    int*   tmp   = (int*)p;   p += (size_t)N_EDGES * 4;          // 6.4 MB (packed)

    histA_kernel <<<NBLK_A, 256, 0, stream>>>(col, M, W1, W2, wTg, wTg2);
    scanA_kernel <<<NBUCK, 256, 0, stream>>>(M, tot);
    bscan_kernel <<<1, 256, 0, stream>>>(tot, boff);
    scatA_kernel <<<NBLK_A, 256, 0, stream>>>(row, col, M, boff, tmp);
    binB2_kernel <<<NBUCK, 512, 0, stream>>>(boff, tmp, srt, rowp, deg, dinv);

    gemm1_mfma   <<<(N_NODES + 63) / 64, 256, 0, stream>>>(x, wTg, dinv, g1b);
    gather1_kernel<<<(N_NODES + 31) / 32, 256, 0, stream>>>(rowp, deg, srt, g1b, dinv, b1, hb);
    gemm2_mfma   <<<(N_NODES + 63) / 64, 256, 0, stream>>>(hb, wTg2, dinv, g2b);
    gather2_kernel<<<(N_NODES + 31) / 32, 256, 0, stream>>>(rowp, deg, srt, g2b, dinv, b2, out);
}